// Round 2
// baseline (6404.720 us; speedup 1.0000x reference)
//
#include <hip/hip_runtime.h>
#include <stdint.h>

// ---------------------------------------------------------------------------
// SpatioTemporalPerceiverResampler  (D=512, H=8, DH=64, NB=4, DMLP=2048,
// L=32, T=128, B=8, BT=1024, ROPE_DIM=32)
// All GEMMs: bf16 MFMA 16x16x32, fp32 accum. Softmax/RMS in fp32.
// Residual stream (lat) lives in d_out (fp32, 64 MiB). Workspace <= 240 MiB.
// ---------------------------------------------------------------------------

typedef short    bf16x8 __attribute__((ext_vector_type(8)));
typedef float    f32x4  __attribute__((ext_vector_type(4)));
typedef uint16_t u16;

__device__ __forceinline__ float bf2f(uint32_t u) {
  union { uint32_t i; float f; } x; x.i = u << 16; return x.f;
}
__device__ __forceinline__ u16 f2bf(float f) {
  union { float f; uint32_t i; } x; x.f = f;
  return (u16)((x.i + 0x7fffu + ((x.i >> 16) & 1u)) >> 16);  // RNE
}
__device__ __forceinline__ float gelu_t(float x) {  // jax.nn.gelu approximate=True
  float u = 0.7978845608028654f * (x + 0.044715f * x * x * x);
  float t = 1.f - 2.f / (__expf(2.f * u) + 1.f);
  return 0.5f * x * (1.f + t);
}
// r_x = (b*L + l)*T + t  ->  lat row (b*T + t)*L + l     (L=32, T=128)
template<int RMAP>
__device__ __forceinline__ int maprow(int r) {
  if (RMAP == 0) return r;
  int b = r >> 12, rem = r & 4095;
  return ((b << 7) + (rem & 127)) * 32 + (rem >> 7);
}
__device__ __forceinline__ void glds16(const u16* g, u16* l) {
  __builtin_amdgcn_global_load_lds((const __attribute__((address_space(1))) uint32_t*)(g),
                                   (__attribute__((address_space(3))) uint32_t*)(l),
                                   16, 0, 0);
}

// ---------------------------------------------------------------------------
// Weight cast+transpose: src fp32 [R][C] -> dst bf16 [C][R]   (z = block idx)
// ---------------------------------------------------------------------------
__global__ __launch_bounds__(256) void transpose_cast(const float* __restrict__ src,
                                                      u16* __restrict__ dst,
                                                      int R, int C) {
  src += (size_t)blockIdx.z * R * C;
  dst += (size_t)blockIdx.z * R * C;
  __shared__ float t[32][33];
  int c0 = blockIdx.x * 32, r0 = blockIdx.y * 32;
  int tx = threadIdx.x & 31, ty = threadIdx.x >> 5;
#pragma unroll
  for (int i = 0; i < 32; i += 8) t[ty + i][tx] = src[(size_t)(r0 + ty + i) * C + c0 + tx];
  __syncthreads();
#pragma unroll
  for (int i = 0; i < 32; i += 8)
    dst[(size_t)(c0 + ty + i) * R + r0 + tx] = f2bf(t[tx][ty + i]);
}

// w1 (512 x 4096) -> w1t (4096 x 512) with GEGLU column interleave:
// dst row c: tile=c>>7, q=(c>>5)&3 -> orig col tile*64+(q>>1)*32+off+(q&1)*2048
__global__ __launch_bounds__(256) void transpose_w1(const float* __restrict__ src,
                                                    u16* __restrict__ dst) {
  src += (size_t)blockIdx.z * 512 * 4096;
  dst += (size_t)blockIdx.z * 512 * 4096;
  __shared__ float t[32][33];
  int c0 = blockIdx.x * 32, r0 = blockIdx.y * 32;
  int tile = c0 >> 7, q = (c0 >> 5) & 3;
  int m0 = tile * 64 + (q >> 1) * 32 + (q & 1) * 2048;
  int tx = threadIdx.x & 31, ty = threadIdx.x >> 5;
#pragma unroll
  for (int i = 0; i < 32; i += 8) t[ty + i][tx] = src[(size_t)(r0 + ty + i) * 4096 + m0 + tx];
  __syncthreads();
#pragma unroll
  for (int i = 0; i < 32; i += 8)
    dst[(size_t)(c0 + ty + i) * 512 + r0 + tx] = f2bf(t[tx][ty + i]);
}

// ---------------------------------------------------------------------------
__global__ void rope_init(float* cosT, float* sinT) {
  int idx = blockIdx.x * 256 + threadIdx.x;
  if (idx < 128 * 16) {
    int t = idx >> 4, j = idx & 15;
    float inv = __expf(-logf(10000.f) * (float)j / 16.f);
    float a = (float)t * inv;
    cosT[idx] = cosf(a);
    sinT[idx] = sinf(a);
  }
}

// latents init: broadcast query_latents (32,512) over 1024 batches (float4)
__global__ __launch_bounds__(256) void init_lat(const float* __restrict__ ql,
                                                float* __restrict__ lat) {
  size_t i = (size_t)blockIdx.x * 256 + threadIdx.x;  // float4 index, 4,194,304 total
  int r = (int)(i >> 7), cw = (int)(i & 127);
  int l = r & 31;
  ((float4*)lat)[i] = ((const float4*)ql)[l * 128 + cw];
}

// ---------------------------------------------------------------------------
// RMSNorm: one wave per row of 512; out bf16. RMAP=1 -> permuted source row.
// ---------------------------------------------------------------------------
template<int RMAP>
__global__ __launch_bounds__(256) void rms_rows(const float* __restrict__ src,
                                                const float* __restrict__ g,
                                                u16* __restrict__ out) {
  const int wid = threadIdx.x >> 6, lane = threadIdx.x & 63;
  const int row = (blockIdx.x << 2) + wid;
  const int srow = maprow<RMAP>(row);
  const float4* p = (const float4*)(src + (size_t)srow * 512);
  float4 v0 = p[lane * 2], v1 = p[lane * 2 + 1];
  float ss = v0.x * v0.x + v0.y * v0.y + v0.z * v0.z + v0.w * v0.w +
             v1.x * v1.x + v1.y * v1.y + v1.z * v1.z + v1.w * v1.w;
#pragma unroll
  for (int m = 1; m < 64; m <<= 1) ss += __shfl_xor(ss, m);
  const float rs = rsqrtf(ss * (1.f / 512.f) + 1e-6f);
  const float4* gp = (const float4*)g;
  float4 g0 = gp[lane * 2], g1 = gp[lane * 2 + 1];
  u16 rb[8];
  rb[0] = f2bf(v0.x * rs * g0.x); rb[1] = f2bf(v0.y * rs * g0.y);
  rb[2] = f2bf(v0.z * rs * g0.z); rb[3] = f2bf(v0.w * rs * g0.w);
  rb[4] = f2bf(v1.x * rs * g1.x); rb[5] = f2bf(v1.y * rs * g1.y);
  rb[6] = f2bf(v1.z * rs * g1.z); rb[7] = f2bf(v1.w * rs * g1.w);
  *(int4*)(out + (size_t)row * 512 + lane * 8) = *(int4*)rb;
}

// ---------------------------------------------------------------------------
// GEMM: C[M,N] = A[M,K](bf16,row) @ Bt[N,K](bf16,row)^T
// 128x128 tile, BK=64, 4 waves (2x2), 4x4 16x16x32 frags/wave.
// EPI: 0 = bf16 out, 1 = bf16 out + bias, 2 = latF[map(row)] += acc (N==512),
//      3 = GEGLU (interleaved W1 cols) -> bf16 h2 [M][2048]
// AMAP: 0 = A row r -> A + r*K
//       1 = CA kv map: j=r%96, n=nb+r/96: j<64 -> A(shat) row n*64+j
//                                         else  -> A2(xn)  row n*32+j-64  (K==512)
// ---------------------------------------------------------------------------
template<int EPI, int RMAP, int AMAP>
__global__ __launch_bounds__(256) void gemm128(const u16* __restrict__ A,
                                               const u16* __restrict__ A2,
                                               const u16* __restrict__ Bt,
                                               u16* __restrict__ outH,
                                               float* __restrict__ latF,
                                               const float* __restrict__ bias,
                                               int M, int N, int K, int nb) {
  __shared__ __align__(16) u16 As[128 * 64];
  __shared__ __align__(16) u16 Bs[128 * 64];
  const int tid = threadIdx.x;
  const int m0 = blockIdx.y << 7;
  const int n0 = blockIdx.x << 7;
  const int wid = tid >> 6, lane = tid & 63;
  const int wm = wid >> 1, wn = wid & 1;
  const int lr = lane & 15, lg = lane >> 4;

  f32x4 acc[4][4];
#pragma unroll
  for (int i = 0; i < 4; ++i)
#pragma unroll
    for (int j = 0; j < 4; ++j) acc[i][j] = (f32x4){0.f, 0.f, 0.f, 0.f};

  for (int k0 = 0; k0 < K; k0 += 64) {
#pragma unroll
    for (int i = 0; i < 4; ++i) {
      const int e = (i * 256 + tid) * 8;
      const int r = e >> 6, c = e & 63;
      const u16* src;
      if constexpr (AMAP == 0) {
        src = A + (size_t)(m0 + r) * K + (k0 + c);
      } else {
        const int R = m0 + r;
        const int n_ = R / 96;
        const int j = R - n_ * 96;
        src = (j < 64) ? A  + ((size_t)((nb + n_) * 64 + j)) * 512 + (k0 + c)
                       : A2 + ((size_t)((nb + n_) * 32 + (j - 64))) * 512 + (k0 + c);
      }
      glds16(src, &As[e]);
    }
#pragma unroll
    for (int i = 0; i < 4; ++i) {
      const int e = (i * 256 + tid) * 8;
      const int r = e >> 6, c = e & 63;
      glds16(Bt + (size_t)(n0 + r) * K + (k0 + c), &Bs[e]);
    }
    __syncthreads();
#pragma unroll
    for (int ks = 0; ks < 2; ++ks) {
      bf16x8 av[4], bv[4];
#pragma unroll
      for (int im = 0; im < 4; ++im)
        av[im] = *(const bf16x8*)&As[(wm * 64 + im * 16 + lr) * 64 + ks * 32 + lg * 8];
#pragma unroll
      for (int in = 0; in < 4; ++in)
        bv[in] = *(const bf16x8*)&Bs[(wn * 64 + in * 16 + lr) * 64 + ks * 32 + lg * 8];
#pragma unroll
      for (int im = 0; im < 4; ++im)
#pragma unroll
        for (int in = 0; in < 4; ++in)
          acc[im][in] = __builtin_amdgcn_mfma_f32_16x16x32_bf16(av[im], bv[in], acc[im][in], 0, 0, 0);
    }
    __syncthreads();
  }

  if constexpr (EPI == 3) {
#pragma unroll
    for (int im = 0; im < 4; ++im)
#pragma unroll
      for (int in = 0; in < 2; ++in)
#pragma unroll
        for (int j = 0; j < 4; ++j) {
          int row = m0 + wm * 64 + im * 16 + lg * 4 + j;
          int hcol = (n0 >> 1) + wn * 32 + in * 16 + lr;
          float a = acc[im][in][j];
          float g = acc[im][in + 2][j];
          outH[(size_t)row * 2048 + hcol] = f2bf(a * gelu_t(g));
        }
  } else {
#pragma unroll
    for (int im = 0; im < 4; ++im)
#pragma unroll
      for (int in = 0; in < 4; ++in) {
        int col = n0 + wn * 64 + in * 16 + lr;
#pragma unroll
        for (int j = 0; j < 4; ++j) {
          int row = m0 + wm * 64 + im * 16 + lg * 4 + j;
          float v = acc[im][in][j];
          if constexpr (EPI == 0) {
            outH[(size_t)row * N + col] = f2bf(v);
          } else if constexpr (EPI == 1) {
            outH[(size_t)row * N + col] = f2bf(v + bias[col]);
          } else {
            size_t rr = (size_t)maprow<RMAP>(row) * 512 + col;
            latF[rr] += v;
          }
        }
      }
  }
}

// ---------------------------------------------------------------------------
// Cross-attention (chunked over n): one block per (n_local,h), n = nb + n_local.
// Lq=32, Lk=96, DH=64. q/o indexed by global n; k/v by local n. o may alias q.
// ---------------------------------------------------------------------------
__global__ __launch_bounds__(256) void attn_ca(const u16* q,
                                               const u16* __restrict__ k,
                                               const u16* __restrict__ v,
                                               u16* o, int nb) {
  __shared__ __align__(16) u16 Qs[32 * 64];
  __shared__ __align__(16) u16 Ks[96 * 64];
  __shared__ __align__(16) u16 Vt[64 * 96];   // transposed [d][kj]
  __shared__ float S[32 * 96];
  __shared__ __align__(16) u16 Pb[32 * 96];
  const int nl = blockIdx.x, n = nb + nl, h = blockIdx.y, tid = threadIdx.x;
  {
    int r = tid >> 3, c = (tid & 7) * 8;
    *(int4*)&Qs[r * 64 + c] = *(const int4*)&q[((size_t)n * 32 + r) * 512 + h * 64 + c];
  }
#pragma unroll
  for (int i = 0; i < 3; ++i) {
    int r = i * 32 + (tid >> 3), c = (tid & 7) * 8;
    *(int4*)&Ks[r * 64 + c] = *(const int4*)&k[((size_t)nl * 96 + r) * 512 + h * 64 + c];
    int4 pv = *(const int4*)&v[((size_t)nl * 96 + r) * 512 + h * 64 + c];
    const u16* pu = (const u16*)&pv;
#pragma unroll
    for (int e = 0; e < 8; ++e) Vt[(c + e) * 96 + r] = pu[e];
  }
  __syncthreads();
  const int wid = tid >> 6, lane = tid & 63, lr = lane & 15, lg = lane >> 4;
  {  // QK^T: wave -> 16 rows x 48 cols
    const int m0 = (wid & 1) * 16, nbc = (wid >> 1) * 48;
    f32x4 sa[3];
#pragma unroll
    for (int f = 0; f < 3; ++f) sa[f] = (f32x4){0.f, 0.f, 0.f, 0.f};
#pragma unroll
    for (int ks = 0; ks < 2; ++ks) {
      bf16x8 a = *(const bf16x8*)&Qs[(m0 + lr) * 64 + ks * 32 + lg * 8];
#pragma unroll
      for (int f = 0; f < 3; ++f) {
        bf16x8 bb = *(const bf16x8*)&Ks[(nbc + f * 16 + lr) * 64 + ks * 32 + lg * 8];
        sa[f] = __builtin_amdgcn_mfma_f32_16x16x32_bf16(a, bb, sa[f], 0, 0, 0);
      }
    }
#pragma unroll
    for (int f = 0; f < 3; ++f)
#pragma unroll
      for (int j = 0; j < 4; ++j)
        S[(m0 + lg * 4 + j) * 96 + nbc + f * 16 + lr] = sa[f][j] * 0.125f;
  }
  __syncthreads();
  {  // softmax rows of 96: 8 lanes per row
    int row = tid >> 3, sub = tid & 7;
    float m = -1e30f;
    for (int j = sub; j < 96; j += 8) m = fmaxf(m, S[row * 96 + j]);
    m = fmaxf(m, __shfl_xor(m, 1)); m = fmaxf(m, __shfl_xor(m, 2)); m = fmaxf(m, __shfl_xor(m, 4));
    float sum = 0.f;
    for (int j = sub; j < 96; j += 8) { float e = __expf(S[row * 96 + j] - m); S[row * 96 + j] = e; sum += e; }
    sum += __shfl_xor(sum, 1); sum += __shfl_xor(sum, 2); sum += __shfl_xor(sum, 4);
    float inv = 1.f / sum;
    for (int j = sub; j < 96; j += 8) Pb[row * 96 + j] = f2bf(S[row * 96 + j] * inv);
  }
  __syncthreads();
  {  // PV: wave -> 16 rows x 32 d-cols, K=96
    const int m0 = (wid & 1) * 16, n0d = (wid >> 1) * 32;
    f32x4 oa[2];
#pragma unroll
    for (int f = 0; f < 2; ++f) oa[f] = (f32x4){0.f, 0.f, 0.f, 0.f};
#pragma unroll
    for (int ks = 0; ks < 3; ++ks) {
      bf16x8 a = *(const bf16x8*)&Pb[(m0 + lr) * 96 + ks * 32 + lg * 8];
#pragma unroll
      for (int f = 0; f < 2; ++f) {
        bf16x8 bb = *(const bf16x8*)&Vt[(n0d + f * 16 + lr) * 96 + ks * 32 + lg * 8];
        oa[f] = __builtin_amdgcn_mfma_f32_16x16x32_bf16(a, bb, oa[f], 0, 0, 0);
      }
    }
    __syncthreads();
#pragma unroll
    for (int f = 0; f < 2; ++f)
#pragma unroll
      for (int j = 0; j < 4; ++j)
        o[((size_t)n * 32 + m0 + lg * 4 + j) * 512 + h * 64 + n0d + f * 16 + lr] = f2bf(oa[f][j]);
  }
}

// ---------------------------------------------------------------------------
// Temporal attention with RoPE: one block per (n,h), n in [0,256). T=128.
// o may alias q (each block reads/writes only its own (row,col) region).
// ---------------------------------------------------------------------------
__global__ __launch_bounds__(256) void attn_ta(const u16* q,
                                               const u16* __restrict__ k,
                                               const u16* __restrict__ v,
                                               const float* __restrict__ cosT,
                                               const float* __restrict__ sinT,
                                               u16* o) {
  __shared__ __align__(16) u16 Qs[128 * 64];
  __shared__ __align__(16) u16 Ks[128 * 64];
  __shared__ __align__(16) u16 Vt[64 * 128];
  __shared__ float S[128 * 128];
  __shared__ __align__(16) u16 Pb[128 * 128];
  const int n = blockIdx.x, h = blockIdx.y, tid = threadIdx.x;
#pragma unroll
  for (int i = 0; i < 16; ++i) {
    int idx = i * 256 + tid;
    int t = idx >> 5, pr = idx & 31;
    uint32_t uq = *(const uint32_t*)&q[((size_t)n * 128 + t) * 512 + h * 64 + pr * 2];
    uint32_t uk = *(const uint32_t*)&k[((size_t)n * 128 + t) * 512 + h * 64 + pr * 2];
    float q1 = bf2f(uq & 0xffff), q2 = bf2f(uq >> 16);
    float k1 = bf2f(uk & 0xffff), k2 = bf2f(uk >> 16);
    if (pr < 16) {
      float c = cosT[t * 16 + pr], s = sinT[t * 16 + pr];
      float a;
      a = q1 * c - q2 * s; q2 = q1 * s + q2 * c; q1 = a;
      a = k1 * c - k2 * s; k2 = k1 * s + k2 * c; k1 = a;
    }
    Qs[t * 64 + pr * 2] = f2bf(q1); Qs[t * 64 + pr * 2 + 1] = f2bf(q2);
    Ks[t * 64 + pr * 2] = f2bf(k1); Ks[t * 64 + pr * 2 + 1] = f2bf(k2);
  }
#pragma unroll
  for (int i = 0; i < 4; ++i) {  // V transposed
    int idx = i * 256 + tid;
    int r = idx >> 3, c = (idx & 7) * 8;
    int4 pv = *(const int4*)&v[((size_t)n * 128 + r) * 512 + h * 64 + c];
    const u16* pu = (const u16*)&pv;
#pragma unroll
    for (int e = 0; e < 8; ++e) Vt[(c + e) * 128 + r] = pu[e];
  }
  __syncthreads();
  const int wid = tid >> 6, lane = tid & 63, lr = lane & 15, lg = lane >> 4;
  const int wm = wid >> 1, wn = wid & 1;
  {  // QK^T 128x128: wave -> 64x64
    f32x4 sa[4][4];
#pragma unroll
    for (int i = 0; i < 4; ++i)
#pragma unroll
      for (int j = 0; j < 4; ++j) sa[i][j] = (f32x4){0.f, 0.f, 0.f, 0.f};
#pragma unroll
    for (int ks = 0; ks < 2; ++ks) {
      bf16x8 av[4], bv[4];
#pragma unroll
      for (int im = 0; im < 4; ++im)
        av[im] = *(const bf16x8*)&Qs[(wm * 64 + im * 16 + lr) * 64 + ks * 32 + lg * 8];
#pragma unroll
      for (int in = 0; in < 4; ++in)
        bv[in] = *(const bf16x8*)&Ks[(wn * 64 + in * 16 + lr) * 64 + ks * 32 + lg * 8];
#pragma unroll
      for (int im = 0; im < 4; ++im)
#pragma unroll
        for (int in = 0; in < 4; ++in)
          sa[im][in] = __builtin_amdgcn_mfma_f32_16x16x32_bf16(av[im], bv[in], sa[im][in], 0, 0, 0);
    }
#pragma unroll
    for (int im = 0; im < 4; ++im)
#pragma unroll
      for (int in = 0; in < 4; ++in)
#pragma unroll
        for (int j = 0; j < 4; ++j)
          S[(wm * 64 + im * 16 + lg * 4 + j) * 128 + wn * 64 + in * 16 + lr] = sa[im][in][j] * 0.125f;
  }
  __syncthreads();
  {  // softmax rows of 128: 2 lanes per row
    int row = tid >> 1, sub = tid & 1;
    float m = -1e30f;
    for (int j = sub; j < 128; j += 2) m = fmaxf(m, S[row * 128 + j]);
    m = fmaxf(m, __shfl_xor(m, 1));
    float sum = 0.f;
    for (int j = sub; j < 128; j += 2) { float e = __expf(S[row * 128 + j] - m); S[row * 128 + j] = e; sum += e; }
    sum += __shfl_xor(sum, 1);
    float inv = 1.f / sum;
    for (int j = sub; j < 128; j += 2) Pb[row * 128 + j] = f2bf(S[row * 128 + j] * inv);
  }
  __syncthreads();
  {  // PV: wave -> 32 rows x 64 d, K=128
    f32x4 oa[2][4];
#pragma unroll
    for (int i = 0; i < 2; ++i)
#pragma unroll
      for (int j = 0; j < 4; ++j) oa[i][j] = (f32x4){0.f, 0.f, 0.f, 0.f};
#pragma unroll
    for (int ks = 0; ks < 4; ++ks) {
      bf16x8 av[2], bv[4];
#pragma unroll
      for (int im = 0; im < 2; ++im)
        av[im] = *(const bf16x8*)&Pb[(wid * 32 + im * 16 + lr) * 128 + ks * 32 + lg * 8];
#pragma unroll
      for (int in = 0; in < 4; ++in)
        bv[in] = *(const bf16x8*)&Vt[(in * 16 + lr) * 128 + ks * 32 + lg * 8];
#pragma unroll
      for (int im = 0; im < 2; ++im)
#pragma unroll
        for (int in = 0; in < 4; ++in)
          oa[im][in] = __builtin_amdgcn_mfma_f32_16x16x32_bf16(av[im], bv[in], oa[im][in], 0, 0, 0);
    }
    __syncthreads();
#pragma unroll
    for (int im = 0; im < 2; ++im)
#pragma unroll
      for (int in = 0; in < 4; ++in)
#pragma unroll
        for (int j = 0; j < 4; ++j) {
          int qi = wid * 32 + im * 16 + lg * 4 + j;
          o[((size_t)n * 128 + qi) * 512 + h * 64 + in * 16 + lr] = f2bf(oa[im][in][j]);
        }
  }
}

// ---------------------------------------------------------------------------
extern "C" void kernel_launch(void* const* d_in, const int* in_sizes, int n_in,
                              void* d_out, int out_size, void* d_ws, size_t ws_size,
                              hipStream_t stream) {
  const float* source = (const float*)d_in[0];
  const float* qlat   = (const float*)d_in[1];
  const float* ca_ln  = (const float*)d_in[2];
  const float* ca_wq  = (const float*)d_in[3];
  const float* ca_wk  = (const float*)d_in[4];
  const float* ca_bk  = (const float*)d_in[5];
  const float* ca_wv  = (const float*)d_in[6];
  const float* ca_wo  = (const float*)d_in[7];
  const float* ca_w1  = (const float*)d_in[8];
  const float* ca_w2  = (const float*)d_in[9];
  const float* ta_ln  = (const float*)d_in[10];
  const float* ta_wq  = (const float*)d_in[11];
  const float* ta_wk  = (const float*)d_in[12];
  const float* ta_bk  = (const float*)d_in[13];
  const float* ta_wv  = (const float*)d_in[14];
  const float* ta_wo  = (const float*)d_in[15];
  const float* ta_w1  = (const float*)d_in[16];
  const float* ta_w2  = (const float*)d_in[17];
  float* lat = (float*)d_out;  // residual stream lives in d_out (identical layout)
  char* ws = (char*)d_ws;
  (void)in_sizes; (void)n_in; (void)out_size;

  // required workspace: 251,674,624 B (~240 MiB). If short, bail (output stays
  // poison -> diagnosable as ws-size failure, not a fault).
  if (ws_size < 251674624ull) return;

  // weight sub-offsets (bf16 elems)
  const size_t WQ = 512 * 512, W1SZ = (size_t)512 * 4096, W2SZ = (size_t)2048 * 512;
  const size_t O_CA_WQ = 0,               O_CA_WK = 4 * WQ,  O_CA_WV = 8 * WQ,
               O_CA_WO = 12 * WQ,         O_CA_W1 = 16 * WQ, O_CA_W2 = O_CA_W1 + 4 * W1SZ,
               O_TA_WQ = O_CA_W2 + 4 * W2SZ,
               O_TA_WK = O_TA_WQ + 4 * WQ, O_TA_WV = O_TA_WK + 4 * WQ,
               O_TA_WO = O_TA_WV + 4 * WQ, O_TA_W1 = O_TA_WO + 4 * WQ,
               O_TA_W2 = O_TA_W1 + 4 * W1SZ;

  // ws layout (bytes):
  u16*   W    = (u16*)ws;                    // [0, 67,108,864)       weights bf16
  u16*   xn   = (u16*)(ws + 67108864);       // [.., 100,663,296)     32 MiB
  u16*   shat = (u16*)(ws + 100663296);      // [.., 167,772,160)     64 MiB  (CA s_n)
  u16*   qb   = (u16*)(ws + 167772160);      // [.., 201,326,592)     32 MiB  (q / attn out)
  u16*   kb   = (u16*)(ws + 201326592);      // [.., 226,492,416)     24 MiB  (CA K chunk)
  u16*   vb   = (u16*)(ws + 226492416);      // [.., 251,658,240)     24 MiB  (CA V chunk)
  u16*   h2   = shat;                        // MLP hidden, 128 MiB over shat+qb+kb+vb[:8MiB]
  u16*   tak  = shat;                        // TA K, 32 MiB  (shat region)
  u16*   tav  = (u16*)(ws + 134217728);      // TA V, 32 MiB  (shat region)
  float* cosT = (float*)(ws + 251658240);
  float* sinT = (float*)(ws + 251666432);

  // --- weight conversion (per launch; deterministic) ---
  transpose_cast<<<dim3(16, 16, 4), 256, 0, stream>>>(ca_wq, W + O_CA_WQ, 512, 512);
  transpose_cast<<<dim3(16, 16, 4), 256, 0, stream>>>(ca_wk, W + O_CA_WK, 512, 512);
  transpose_cast<<<dim3(16, 16, 4), 256, 0, stream>>>(ca_wv, W + O_CA_WV, 512, 512);
  transpose_cast<<<dim3(16, 16, 4), 256, 0, stream>>>(ca_wo, W + O_CA_WO, 512, 512);
  transpose_w1 <<<dim3(128, 16, 4), 256, 0, stream>>>(ca_w1, W + O_CA_W1);
  transpose_cast<<<dim3(16, 64, 4), 256, 0, stream>>>(ca_w2, W + O_CA_W2, 2048, 512);
  transpose_cast<<<dim3(16, 16, 4), 256, 0, stream>>>(ta_wq, W + O_TA_WQ, 512, 512);
  transpose_cast<<<dim3(16, 16, 4), 256, 0, stream>>>(ta_wk, W + O_TA_WK, 512, 512);
  transpose_cast<<<dim3(16, 16, 4), 256, 0, stream>>>(ta_wv, W + O_TA_WV, 512, 512);
  transpose_cast<<<dim3(16, 16, 4), 256, 0, stream>>>(ta_wo, W + O_TA_WO, 512, 512);
  transpose_w1 <<<dim3(128, 16, 4), 256, 0, stream>>>(ta_w1, W + O_TA_W1);
  transpose_cast<<<dim3(16, 64, 4), 256, 0, stream>>>(ta_w2, W + O_TA_W2, 2048, 512);
  rope_init<<<8, 256, 0, stream>>>(cosT, sinT);
  init_lat<<<16384, 256, 0, stream>>>(qlat, lat);

  for (int b = 0; b < 4; ++b) {
    const u16* wqt  = W + O_CA_WQ + (size_t)b * WQ;
    const u16* wkt  = W + O_CA_WK + (size_t)b * WQ;
    const u16* wvt  = W + O_CA_WV + (size_t)b * WQ;
    const u16* wot  = W + O_CA_WO + (size_t)b * WQ;
    const u16* w1t  = W + O_CA_W1 + (size_t)b * W1SZ;
    const u16* w2t  = W + O_CA_W2 + (size_t)b * W2SZ;
    const u16* twqt = W + O_TA_WQ + (size_t)b * WQ;
    const u16* twkt = W + O_TA_WK + (size_t)b * WQ;
    const u16* twvt = W + O_TA_WV + (size_t)b * WQ;
    const u16* twot = W + O_TA_WO + (size_t)b * WQ;
    const u16* tw1t = W + O_TA_W1 + (size_t)b * W1SZ;
    const u16* tw2t = W + O_TA_W2 + (size_t)b * W2SZ;

    // ---- cross attention ----
    rms_rows<0><<<8192, 256, 0, stream>>>(lat, ca_ln + b * 1536, xn);           // l_n
    rms_rows<0><<<16384, 256, 0, stream>>>(source, ca_ln + b * 1536 + 512, shat); // s_n
    gemm128<0, 0, 0><<<dim3(4, 256), 256, 0, stream>>>(xn, nullptr, wqt, qb, nullptr, nullptr, 32768, 512, 512, 0);
    for (int c = 0; c < 4; ++c) {  // K/V + attention per 256-batch chunk
      gemm128<1, 0, 1><<<dim3(4, 192), 256, 0, stream>>>(shat, xn, wkt, kb, nullptr, ca_bk + b * 512, 24576, 512, 512, c * 256);
      gemm128<0, 0, 1><<<dim3(4, 192), 256, 0, stream>>>(shat, xn, wvt, vb, nullptr, nullptr, 24576, 512, 512, c * 256);
      attn_ca<<<dim3(256, 8), 256, 0, stream>>>(qb, kb, vb, qb, c * 256);
    }
    gemm128<2, 0, 0><<<dim3(4, 256), 256, 0, stream>>>(qb, nullptr, wot, nullptr, lat, nullptr, 32768, 512, 512, 0);
    rms_rows<0><<<8192, 256, 0, stream>>>(lat, ca_ln + b * 1536 + 1024, xn);
    gemm128<3, 0, 0><<<dim3(32, 256), 256, 0, stream>>>(xn, nullptr, w1t, h2, nullptr, nullptr, 32768, 4096, 512, 0);
    gemm128<2, 0, 0><<<dim3(4, 256), 256, 0, stream>>>(h2, nullptr, w2t, nullptr, lat, nullptr, 32768, 512, 2048, 0);

    // ---- temporal attention ----
    rms_rows<1><<<8192, 256, 0, stream>>>(lat, ta_ln + b * 1024, xn);
    gemm128<0, 0, 0><<<dim3(4, 256), 256, 0, stream>>>(xn, nullptr, twqt, qb, nullptr, nullptr, 32768, 512, 512, 0);
    gemm128<1, 0, 0><<<dim3(4, 256), 256, 0, stream>>>(xn, nullptr, twkt, tak, nullptr, ta_bk + b * 512, 32768, 512, 512, 0);
    gemm128<0, 0, 0><<<dim3(4, 256), 256, 0, stream>>>(xn, nullptr, twvt, tav, nullptr, nullptr, 32768, 512, 512, 0);
    attn_ta<<<dim3(256, 8), 256, 0, stream>>>(qb, tak, tav, cosT, sinT, qb);
    gemm128<2, 1, 0><<<dim3(4, 256), 256, 0, stream>>>(qb, nullptr, twot, nullptr, lat, nullptr, 32768, 512, 512, 0);
    rms_rows<1><<<8192, 256, 0, stream>>>(lat, ta_ln + b * 1024 + 512, xn);
    gemm128<3, 0, 0><<<dim3(32, 256), 256, 0, stream>>>(xn, nullptr, tw1t, h2, nullptr, nullptr, 32768, 4096, 512, 0);
    gemm128<2, 1, 0><<<dim3(4, 256), 256, 0, stream>>>(h2, nullptr, tw2t, nullptr, lat, nullptr, 32768, 512, 2048, 0);
  }
}

// Round 4
// 6311.539 us; speedup vs baseline: 1.0148x; 1.0148x over previous
//
#include <hip/hip_runtime.h>
#include <stdint.h>

// ---------------------------------------------------------------------------
// SpatioTemporalPerceiverResampler  (D=512, H=8, DH=64, NB=4, DMLP=2048,
// L=32, T=128, B=8, BT=1024, ROPE_DIM=32)
// bf16 MFMA 16x16x32, fp32 accum; softmax/RMS fp32. lat lives in d_out.
// R4: R3 (LDS epilogues, fused KV) with ws-layout fix: no table/weight overlap.
// Weights occupy [0, 67,108,864) exactly; cosT/sinT in the tail gap after kvb.
// ---------------------------------------------------------------------------

typedef short    bf16x8 __attribute__((ext_vector_type(8)));
typedef float    f32x4  __attribute__((ext_vector_type(4)));
typedef uint16_t u16;

__device__ __forceinline__ float bf2f(uint32_t u) {
  union { uint32_t i; float f; } x; x.i = u << 16; return x.f;
}
__device__ __forceinline__ u16 f2bf(float f) {
  union { float f; uint32_t i; } x; x.f = f;
  return (u16)((x.i + 0x7fffu + ((x.i >> 16) & 1u)) >> 16);  // RNE
}
__device__ __forceinline__ float gelu_t(float x) {  // jax.nn.gelu approximate=True
  float u = 0.7978845608028654f * (x + 0.044715f * x * x * x);
  float t = 1.f - 2.f / (__expf(2.f * u) + 1.f);
  return 0.5f * x * (1.f + t);
}
// r_x = (b*L + l)*T + t  ->  lat row (b*T + t)*L + l     (L=32, T=128)
template<int RMAP>
__device__ __forceinline__ int maprow(int r) {
  if (RMAP == 0) return r;
  int b = r >> 12, rem = r & 4095;
  return ((b << 7) + (rem & 127)) * 32 + (rem >> 7);
}
__device__ __forceinline__ void glds16(const u16* g, u16* l) {
  __builtin_amdgcn_global_load_lds((const __attribute__((address_space(1))) uint32_t*)(g),
                                   (__attribute__((address_space(3))) uint32_t*)(l),
                                   16, 0, 0);
}

// ---------------------------------------------------------------------------
// Weight cast+transpose: src fp32 [R][C] -> dst bf16 [C][R]; z strides:
// src by R*C, dst by zsD (allows interleaving wk/wv per block).
// ---------------------------------------------------------------------------
__global__ __launch_bounds__(256) void transpose_cast(const float* __restrict__ src,
                                                      u16* __restrict__ dst,
                                                      int R, int C, size_t zsD) {
  src += (size_t)blockIdx.z * R * C;
  dst += (size_t)blockIdx.z * zsD;
  __shared__ float t[32][33];
  int c0 = blockIdx.x * 32, r0 = blockIdx.y * 32;
  int tx = threadIdx.x & 31, ty = threadIdx.x >> 5;
#pragma unroll
  for (int i = 0; i < 32; i += 8) t[ty + i][tx] = src[(size_t)(r0 + ty + i) * C + c0 + tx];
  __syncthreads();
#pragma unroll
  for (int i = 0; i < 32; i += 8)
    dst[(size_t)(c0 + ty + i) * R + r0 + tx] = f2bf(t[tx][ty + i]);
}

// w1 (512 x 4096) -> w1t (4096 x 512) with GEGLU column interleave:
// dst row c: tile=c>>7, q=(c>>5)&3 -> orig col tile*64+(q>>1)*32+off+(q&1)*2048
__global__ __launch_bounds__(256) void transpose_w1(const float* __restrict__ src,
                                                    u16* __restrict__ dst) {
  src += (size_t)blockIdx.z * 512 * 4096;
  dst += (size_t)blockIdx.z * 512 * 4096;
  __shared__ float t[32][33];
  int c0 = blockIdx.x * 32, r0 = blockIdx.y * 32;
  int tile = c0 >> 7, q = (c0 >> 5) & 3;
  int m0 = tile * 64 + (q >> 1) * 32 + (q & 1) * 2048;
  int tx = threadIdx.x & 31, ty = threadIdx.x >> 5;
#pragma unroll
  for (int i = 0; i < 32; i += 8) t[ty + i][tx] = src[(size_t)(r0 + ty + i) * 4096 + m0 + tx];
  __syncthreads();
#pragma unroll
  for (int i = 0; i < 32; i += 8)
    dst[(size_t)(c0 + ty + i) * 512 + r0 + tx] = f2bf(t[tx][ty + i]);
}

// ---------------------------------------------------------------------------
__global__ void rope_init(float* cosT, float* sinT) {
  int idx = blockIdx.x * 256 + threadIdx.x;
  if (idx < 128 * 16) {
    int t = idx >> 4, j = idx & 15;
    float inv = __expf(-logf(10000.f) * (float)j / 16.f);
    float a = (float)t * inv;
    cosT[idx] = cosf(a);
    sinT[idx] = sinf(a);
  }
}

// latents init: broadcast query_latents (32,512) over 1024 batches (float4)
__global__ __launch_bounds__(256) void init_lat(const float* __restrict__ ql,
                                                float* __restrict__ lat) {
  size_t i = (size_t)blockIdx.x * 256 + threadIdx.x;  // float4 index
  int r = (int)(i >> 7), cw = (int)(i & 127);
  int l = r & 31;
  ((float4*)lat)[i] = ((const float4*)ql)[l * 128 + cw];
}

// ---------------------------------------------------------------------------
// RMSNorm: one wave per row of 512; out bf16. RMAP=1 -> permuted source row.
// ---------------------------------------------------------------------------
template<int RMAP>
__global__ __launch_bounds__(256) void rms_rows(const float* __restrict__ src,
                                                const float* __restrict__ g,
                                                u16* __restrict__ out) {
  const int wid = threadIdx.x >> 6, lane = threadIdx.x & 63;
  const int row = (blockIdx.x << 2) + wid;
  const int srow = maprow<RMAP>(row);
  const float4* p = (const float4*)(src + (size_t)srow * 512);
  float4 v0 = p[lane * 2], v1 = p[lane * 2 + 1];
  float ss = v0.x * v0.x + v0.y * v0.y + v0.z * v0.z + v0.w * v0.w +
             v1.x * v1.x + v1.y * v1.y + v1.z * v1.z + v1.w * v1.w;
#pragma unroll
  for (int m = 1; m < 64; m <<= 1) ss += __shfl_xor(ss, m);
  const float rs = rsqrtf(ss * (1.f / 512.f) + 1e-6f);
  const float4* gp = (const float4*)g;
  float4 g0 = gp[lane * 2], g1 = gp[lane * 2 + 1];
  u16 rb[8];
  rb[0] = f2bf(v0.x * rs * g0.x); rb[1] = f2bf(v0.y * rs * g0.y);
  rb[2] = f2bf(v0.z * rs * g0.z); rb[3] = f2bf(v0.w * rs * g0.w);
  rb[4] = f2bf(v1.x * rs * g1.x); rb[5] = f2bf(v1.y * rs * g1.y);
  rb[6] = f2bf(v1.z * rs * g1.z); rb[7] = f2bf(v1.w * rs * g1.w);
  *(int4*)(out + (size_t)row * 512 + lane * 8) = *(int4*)rb;
}

// ---------------------------------------------------------------------------
// GEMM: C[M,N] = A[M,K](bf16,row) @ Bt[N,K](bf16,row)^T
// 128x128 tile, BK=64, 4 waves (2x2), 4x4 16x16x32 frags/wave.
// EPI: 0 = bf16 out, 1 = bf16 out + bias (bias has 512 entries, applied only
//          to cols < 512 -- block-uniform since 512 % 128 == 0),
//      2 = latF[map(row)] += acc, 3 = GEGLU (interleaved W1) -> h2 [M][2048]
// AMAP: 1 = CA kv row map, else direct.
// All epilogues stage C through LDS and store vectorized (16B).
// ---------------------------------------------------------------------------
template<int EPI, int RMAP, int AMAP>
__global__ __launch_bounds__(256) void gemm128(const u16* __restrict__ A,
                                               const u16* __restrict__ A2,
                                               const u16* __restrict__ Bt,
                                               u16* __restrict__ outH,
                                               float* __restrict__ latF,
                                               const float* __restrict__ bias,
                                               int M, int N, int K, int nb) {
  union __align__(16) SM {
    struct { u16 As[128 * 64]; u16 Bs[128 * 64]; } st;  // 32 KiB staging
    u16   c01[2][128][72];                              // EPI 0/1 C-stage
    u16   c3[128][72];                                  // EPI 3 C-stage
    float c2[64][132];                                  // EPI 2 C-stage
  };
  __shared__ SM sm;
  const int tid = threadIdx.x;
  const int m0 = blockIdx.y << 7;
  const int n0 = blockIdx.x << 7;
  const int wid = tid >> 6, lane = tid & 63;
  const int wm = wid >> 1, wn = wid & 1;
  const int lr = lane & 15, lg = lane >> 4;

  f32x4 acc[4][4];
#pragma unroll
  for (int i = 0; i < 4; ++i)
#pragma unroll
    for (int j = 0; j < 4; ++j) acc[i][j] = (f32x4){0.f, 0.f, 0.f, 0.f};

  for (int k0 = 0; k0 < K; k0 += 64) {
#pragma unroll
    for (int i = 0; i < 4; ++i) {
      const int e = (i * 256 + tid) * 8;
      const int r = e >> 6, c = e & 63;
      const u16* src;
      if constexpr (AMAP == 0) {
        src = A + (size_t)(m0 + r) * K + (k0 + c);
      } else {
        const int R = m0 + r;
        const int n_ = R / 96;
        const int j = R - n_ * 96;
        src = (j < 64) ? A  + ((size_t)((nb + n_) * 64 + j)) * 512 + (k0 + c)
                       : A2 + ((size_t)((nb + n_) * 32 + (j - 64))) * 512 + (k0 + c);
      }
      glds16(src, &sm.st.As[e]);
    }
#pragma unroll
    for (int i = 0; i < 4; ++i) {
      const int e = (i * 256 + tid) * 8;
      const int r = e >> 6, c = e & 63;
      glds16(Bt + (size_t)(n0 + r) * K + (k0 + c), &sm.st.Bs[e]);
    }
    __syncthreads();
#pragma unroll
    for (int ks = 0; ks < 2; ++ks) {
      bf16x8 av[4], bv[4];
#pragma unroll
      for (int im = 0; im < 4; ++im)
        av[im] = *(const bf16x8*)&sm.st.As[(wm * 64 + im * 16 + lr) * 64 + ks * 32 + lg * 8];
#pragma unroll
      for (int in = 0; in < 4; ++in)
        bv[in] = *(const bf16x8*)&sm.st.Bs[(wn * 64 + in * 16 + lr) * 64 + ks * 32 + lg * 8];
#pragma unroll
      for (int im = 0; im < 4; ++im)
#pragma unroll
        for (int in = 0; in < 4; ++in)
          acc[im][in] = __builtin_amdgcn_mfma_f32_16x16x32_bf16(av[im], bv[in], acc[im][in], 0, 0, 0);
    }
    __syncthreads();
  }

  if constexpr (EPI == 3) {
#pragma unroll
    for (int im = 0; im < 4; ++im)
#pragma unroll
      for (int in = 0; in < 2; ++in)
#pragma unroll
        for (int j = 0; j < 4; ++j) {
          int row = wm * 64 + im * 16 + lg * 4 + j;
          int hl = wn * 32 + in * 16 + lr;
          sm.c3[row][hl] = f2bf(acc[im][in][j] * gelu_t(acc[im][in + 2][j]));
        }
    __syncthreads();
#pragma unroll
    for (int s = 0; s < 4; ++s) {
      int idx = s * 2048 + tid * 8;  // 8192 u16 = 128 x 64
      int row = idx >> 6, hl = idx & 63;
      *(int4*)&outH[(size_t)(m0 + row) * 2048 + (n0 >> 1) + hl] = *(int4*)&sm.c3[row][hl];
    }
  } else if constexpr (EPI == 2) {
#pragma unroll
    for (int p = 0; p < 2; ++p) {
      if (wm == p) {
#pragma unroll
        for (int im = 0; im < 4; ++im)
#pragma unroll
          for (int in = 0; in < 4; ++in)
#pragma unroll
            for (int j = 0; j < 4; ++j)
              sm.c2[im * 16 + lg * 4 + j][wn * 64 + in * 16 + lr] = acc[im][in][j];
      }
      __syncthreads();
#pragma unroll
      for (int s = 0; s < 8; ++s) {
        int idx = s * 1024 + tid * 4;  // 8192 floats = 64 x 128
        int row = idx >> 7, col = idx & 127;
        size_t rr = (size_t)maprow<RMAP>(m0 + p * 64 + row) * 512 + n0 + col;
        float4 cur = *(float4*)&latF[rr];
        float4 ad = *(float4*)&sm.c2[row][col];
        cur.x += ad.x; cur.y += ad.y; cur.z += ad.z; cur.w += ad.w;
        *(float4*)&latF[rr] = cur;
      }
      if (p == 0) __syncthreads();
    }
  } else {
    float bv4[4];
    if constexpr (EPI == 1) {
      // bias covers cols [0,512) only (fused K|V: V half unbiased)
#pragma unroll
      for (int in = 0; in < 4; ++in)
        bv4[in] = (n0 < 512) ? bias[n0 + wn * 64 + in * 16 + lr] : 0.f;
    }
#pragma unroll
    for (int im = 0; im < 4; ++im)
#pragma unroll
      for (int in = 0; in < 4; ++in)
#pragma unroll
        for (int j = 0; j < 4; ++j) {
          int row = wm * 64 + im * 16 + lg * 4 + j;
          int col = in * 16 + lr;
          float v = acc[im][in][j];
          if constexpr (EPI == 1) v += bv4[in];
          sm.c01[wn][row][col] = f2bf(v);
        }
    __syncthreads();
#pragma unroll
    for (int s = 0; s < 8; ++s) {
      int idx = s * 2048 + tid * 8;  // 16384 u16 = 128 x 128
      int row = idx >> 7, col = idx & 127;
      *(int4*)&outH[(size_t)(m0 + row) * N + n0 + col] = *(int4*)&sm.c01[col >> 6][row][col & 63];
    }
  }
}

// ---------------------------------------------------------------------------
// Cross-attention (chunked over n): block per (n_local,h), n = nb + n_local.
// Lq=32, Lk=96, DH=64. kv fused rows [1024]: k cols 0-511, v cols 512-1023.
// ---------------------------------------------------------------------------
__global__ __launch_bounds__(256) void attn_ca(const u16* q,
                                               const u16* __restrict__ kv,
                                               u16* o, int nb) {
  __shared__ __align__(16) u16 Qs[32 * 64];
  __shared__ __align__(16) u16 Ks[96 * 64];
  __shared__ __align__(16) u16 Vt[64 * 96];   // transposed [d][kj]
  __shared__ float S[32 * 96];
  __shared__ __align__(16) u16 Pb[32 * 96];
  const int nl = blockIdx.x, n = nb + nl, h = blockIdx.y, tid = threadIdx.x;
  {
    int r = tid >> 3, c = (tid & 7) * 8;
    *(int4*)&Qs[r * 64 + c] = *(const int4*)&q[((size_t)n * 32 + r) * 512 + h * 64 + c];
  }
#pragma unroll
  for (int i = 0; i < 3; ++i) {
    int r = i * 32 + (tid >> 3), c = (tid & 7) * 8;
    *(int4*)&Ks[r * 64 + c] = *(const int4*)&kv[((size_t)nl * 96 + r) * 1024 + h * 64 + c];
    int4 pv = *(const int4*)&kv[((size_t)nl * 96 + r) * 1024 + 512 + h * 64 + c];
    const u16* pu = (const u16*)&pv;
#pragma unroll
    for (int e = 0; e < 8; ++e) Vt[(c + e) * 96 + r] = pu[e];
  }
  __syncthreads();
  const int wid = tid >> 6, lane = tid & 63, lr = lane & 15, lg = lane >> 4;
  {  // QK^T: wave -> 16 rows x 48 cols
    const int m0 = (wid & 1) * 16, nbc = (wid >> 1) * 48;
    f32x4 sa[3];
#pragma unroll
    for (int f = 0; f < 3; ++f) sa[f] = (f32x4){0.f, 0.f, 0.f, 0.f};
#pragma unroll
    for (int ks = 0; ks < 2; ++ks) {
      bf16x8 a = *(const bf16x8*)&Qs[(m0 + lr) * 64 + ks * 32 + lg * 8];
#pragma unroll
      for (int f = 0; f < 3; ++f) {
        bf16x8 bb = *(const bf16x8*)&Ks[(nbc + f * 16 + lr) * 64 + ks * 32 + lg * 8];
        sa[f] = __builtin_amdgcn_mfma_f32_16x16x32_bf16(a, bb, sa[f], 0, 0, 0);
      }
    }
#pragma unroll
    for (int f = 0; f < 3; ++f)
#pragma unroll
      for (int j = 0; j < 4; ++j)
        S[(m0 + lg * 4 + j) * 96 + nbc + f * 16 + lr] = sa[f][j] * 0.125f;
  }
  __syncthreads();
  {  // softmax rows of 96: 8 lanes per row
    int row = tid >> 3, sub = tid & 7;
    float m = -1e30f;
    for (int j = sub; j < 96; j += 8) m = fmaxf(m, S[row * 96 + j]);
    m = fmaxf(m, __shfl_xor(m, 1)); m = fmaxf(m, __shfl_xor(m, 2)); m = fmaxf(m, __shfl_xor(m, 4));
    float sum = 0.f;
    for (int j = sub; j < 96; j += 8) { float e = __expf(S[row * 96 + j] - m); S[row * 96 + j] = e; sum += e; }
    sum += __shfl_xor(sum, 1); sum += __shfl_xor(sum, 2); sum += __shfl_xor(sum, 4);
    float inv = 1.f / sum;
    for (int j = sub; j < 96; j += 8) Pb[row * 96 + j] = f2bf(S[row * 96 + j] * inv);
  }
  __syncthreads();
  {  // PV: wave -> 16 rows x 32 d-cols, K=96
    const int m0 = (wid & 1) * 16, n0d = (wid >> 1) * 32;
    f32x4 oa[2];
#pragma unroll
    for (int f = 0; f < 2; ++f) oa[f] = (f32x4){0.f, 0.f, 0.f, 0.f};
#pragma unroll
    for (int ks = 0; ks < 3; ++ks) {
      bf16x8 a = *(const bf16x8*)&Pb[(m0 + lr) * 96 + ks * 32 + lg * 8];
#pragma unroll
      for (int f = 0; f < 2; ++f) {
        bf16x8 bb = *(const bf16x8*)&Vt[(n0d + f * 16 + lr) * 96 + ks * 32 + lg * 8];
        oa[f] = __builtin_amdgcn_mfma_f32_16x16x32_bf16(a, bb, oa[f], 0, 0, 0);
      }
    }
    __syncthreads();
#pragma unroll
    for (int f = 0; f < 2; ++f)
#pragma unroll
      for (int j = 0; j < 4; ++j)
        o[((size_t)n * 32 + m0 + lg * 4 + j) * 512 + h * 64 + n0d + f * 16 + lr] = f2bf(oa[f][j]);
  }
}

// ---------------------------------------------------------------------------
// Temporal attention with RoPE: block per (n,h), n in [0,256). T=128.
// q stride 512; kv fused stride 1024 (k cols 0-511, v cols 512-1023).
// ---------------------------------------------------------------------------
__global__ __launch_bounds__(256) void attn_ta(const u16* q,
                                               const u16* __restrict__ kv,
                                               const float* __restrict__ cosT,
                                               const float* __restrict__ sinT,
                                               u16* o) {
  __shared__ __align__(16) u16 Qs[128 * 64];
  __shared__ __align__(16) u16 Ks[128 * 64];
  __shared__ __align__(16) u16 Vt[64 * 128];
  __shared__ float S[128 * 128];
  __shared__ __align__(16) u16 Pb[128 * 128];
  const int n = blockIdx.x, h = blockIdx.y, tid = threadIdx.x;
#pragma unroll
  for (int i = 0; i < 16; ++i) {
    int idx = i * 256 + tid;
    int t = idx >> 5, pr = idx & 31;
    uint32_t uq = *(const uint32_t*)&q[((size_t)n * 128 + t) * 512 + h * 64 + pr * 2];
    uint32_t uk = *(const uint32_t*)&kv[((size_t)n * 128 + t) * 1024 + h * 64 + pr * 2];
    float q1 = bf2f(uq & 0xffff), q2 = bf2f(uq >> 16);
    float k1 = bf2f(uk & 0xffff), k2 = bf2f(uk >> 16);
    if (pr < 16) {
      float c = cosT[t * 16 + pr], s = sinT[t * 16 + pr];
      float a;
      a = q1 * c - q2 * s; q2 = q1 * s + q2 * c; q1 = a;
      a = k1 * c - k2 * s; k2 = k1 * s + k2 * c; k1 = a;
    }
    Qs[t * 64 + pr * 2] = f2bf(q1); Qs[t * 64 + pr * 2 + 1] = f2bf(q2);
    Ks[t * 64 + pr * 2] = f2bf(k1); Ks[t * 64 + pr * 2 + 1] = f2bf(k2);
  }
#pragma unroll
  for (int i = 0; i < 4; ++i) {  // V transposed
    int idx = i * 256 + tid;
    int r = idx >> 3, c = (idx & 7) * 8;
    int4 pv = *(const int4*)&kv[((size_t)n * 128 + r) * 1024 + 512 + h * 64 + c];
    const u16* pu = (const u16*)&pv;
#pragma unroll
    for (int e = 0; e < 8; ++e) Vt[(c + e) * 128 + r] = pu[e];
  }
  __syncthreads();
  const int wid = tid >> 6, lane = tid & 63, lr = lane & 15, lg = lane >> 4;
  const int wm = wid >> 1, wn = wid & 1;
  {  // QK^T 128x128: wave -> 64x64
    f32x4 sa[4][4];
#pragma unroll
    for (int i = 0; i < 4; ++i)
#pragma unroll
      for (int j = 0; j < 4; ++j) sa[i][j] = (f32x4){0.f, 0.f, 0.f, 0.f};
#pragma unroll
    for (int ks = 0; ks < 2; ++ks) {
      bf16x8 av[4], bv[4];
#pragma unroll
      for (int im = 0; im < 4; ++im)
        av[im] = *(const bf16x8*)&Qs[(wm * 64 + im * 16 + lr) * 64 + ks * 32 + lg * 8];
#pragma unroll
      for (int in = 0; in < 4; ++in)
        bv[in] = *(const bf16x8*)&Ks[(wn * 64 + in * 16 + lr) * 64 + ks * 32 + lg * 8];
#pragma unroll
      for (int im = 0; im < 4; ++im)
#pragma unroll
        for (int in = 0; in < 4; ++in)
          sa[im][in] = __builtin_amdgcn_mfma_f32_16x16x32_bf16(av[im], bv[in], sa[im][in], 0, 0, 0);
    }
#pragma unroll
    for (int im = 0; im < 4; ++im)
#pragma unroll
      for (int in = 0; in < 4; ++in)
#pragma unroll
        for (int j = 0; j < 4; ++j)
          S[(wm * 64 + im * 16 + lg * 4 + j) * 128 + wn * 64 + in * 16 + lr] = sa[im][in][j] * 0.125f;
  }
  __syncthreads();
  {  // softmax rows of 128: 2 lanes per row
    int row = tid >> 1, sub = tid & 1;
    float m = -1e30f;
    for (int j = sub; j < 128; j += 2) m = fmaxf(m, S[row * 128 + j]);
    m = fmaxf(m, __shfl_xor(m, 1));
    float sum = 0.f;
    for (int j = sub; j < 128; j += 2) { float e = __expf(S[row * 128 + j] - m); S[row * 128 + j] = e; sum += e; }
    sum += __shfl_xor(sum, 1);
    float inv = 1.f / sum;
    for (int j = sub; j < 128; j += 2) Pb[row * 128 + j] = f2bf(S[row * 128 + j] * inv);
  }
  __syncthreads();
  {  // PV: wave -> 32 rows x 64 d, K=128
    f32x4 oa[2][4];
#pragma unroll
    for (int i = 0; i < 2; ++i)
#pragma unroll
      for (int j = 0; j < 4; ++j) oa[i][j] = (f32x4){0.f, 0.f, 0.f, 0.f};
#pragma unroll
    for (int ks = 0; ks < 4; ++ks) {
      bf16x8 av[2], bv[4];
#pragma unroll
      for (int im = 0; im < 2; ++im)
        av[im] = *(const bf16x8*)&Pb[(wid * 32 + im * 16 + lr) * 128 + ks * 32 + lg * 8];
#pragma unroll
      for (int in = 0; in < 4; ++in)
        bv[in] = *(const bf16x8*)&Vt[(in * 16 + lr) * 128 + ks * 32 + lg * 8];
#pragma unroll
      for (int im = 0; im < 2; ++im)
#pragma unroll
        for (int in = 0; in < 4; ++in)
          oa[im][in] = __builtin_amdgcn_mfma_f32_16x16x32_bf16(av[im], bv[in], oa[im][in], 0, 0, 0);
    }
    __syncthreads();
#pragma unroll
    for (int im = 0; im < 2; ++im)
#pragma unroll
      for (int in = 0; in < 4; ++in)
#pragma unroll
        for (int j = 0; j < 4; ++j) {
          int qi = wid * 32 + im * 16 + lg * 4 + j;
          o[((size_t)n * 128 + qi) * 512 + h * 64 + in * 16 + lr] = f2bf(oa[im][in][j]);
        }
  }
}

// ---------------------------------------------------------------------------
extern "C" void kernel_launch(void* const* d_in, const int* in_sizes, int n_in,
                              void* d_out, int out_size, void* d_ws, size_t ws_size,
                              hipStream_t stream) {
  const float* source = (const float*)d_in[0];
  const float* qlat   = (const float*)d_in[1];
  const float* ca_ln  = (const float*)d_in[2];
  const float* ca_wq  = (const float*)d_in[3];
  const float* ca_wk  = (const float*)d_in[4];
  const float* ca_bk  = (const float*)d_in[5];
  const float* ca_wv  = (const float*)d_in[6];
  const float* ca_wo  = (const float*)d_in[7];
  const float* ca_w1  = (const float*)d_in[8];
  const float* ca_w2  = (const float*)d_in[9];
  const float* ta_ln  = (const float*)d_in[10];
  const float* ta_wq  = (const float*)d_in[11];
  const float* ta_wk  = (const float*)d_in[12];
  const float* ta_bk  = (const float*)d_in[13];
  const float* ta_wv  = (const float*)d_in[14];
  const float* ta_wo  = (const float*)d_in[15];
  const float* ta_w1  = (const float*)d_in[16];
  const float* ta_w2  = (const float*)d_in[17];
  float* lat = (float*)d_out;  // residual stream lives in d_out
  char* ws = (char*)d_ws;
  (void)in_sizes; (void)n_in; (void)out_size;

  if (ws_size < 251674624ull) return;  // known-good guard from R2

  // weight sub-offsets (bf16 elems). KV weights interleaved per block:
  // O_CA_KV + b*2WQ = [wk_b^T ; wv_b^T] -> fused Bt N=1024.
  // Weight pool total = 128*WQ elems = 67,108,864 B exactly.
  const size_t WQ = 512 * 512, W1SZ = (size_t)512 * 4096, W2SZ = (size_t)2048 * 512;
  const size_t O_CA_WQ = 0,
               O_CA_KV = 4 * WQ,
               O_CA_WO = 12 * WQ,
               O_CA_W1 = 16 * WQ,                  // +32 WQ
               O_CA_W2 = O_CA_W1 + 4 * W1SZ,       // 48 WQ, +16 WQ
               O_TA_WQ = O_CA_W2 + 4 * W2SZ,       // 64 WQ
               O_TA_KV = O_TA_WQ + 4 * WQ,         // 68 WQ
               O_TA_WO = O_TA_KV + 8 * WQ,         // 76 WQ
               O_TA_W1 = O_TA_WO + 4 * WQ,         // 80 WQ
               O_TA_W2 = O_TA_W1 + 4 * W1SZ;       // 112 WQ, ends at 128 WQ

  // ws layout (bytes):
  u16*   W    = (u16*)ws;                    // [0, 67,108,864)  weights (exact)
  u16*   xn   = (u16*)(ws + 67108864);       // 32 MiB
  u16*   shat = (u16*)(ws + 100663296);      // 64 MiB (CA s_n; TA fused KV; h2 head)
  u16*   qb   = (u16*)(ws + 167772160);      // 32 MiB (q / attn out)
  u16*   kvb  = (u16*)(ws + 201326592);      // 48 MiB (CA fused K|V chunk)
  u16*   h2   = shat;                        // MLP hidden 128 MiB (shat+qb+kvb head)
  u16*   takv = shat;                        // TA fused KV 64 MiB
  float* cosT = (float*)(ws + 251658240);    // 8 KiB  (tail gap, within guard)
  float* sinT = (float*)(ws + 251666432);    // 8 KiB

  // --- weight conversion ---
  transpose_cast<<<dim3(16, 16, 4), 256, 0, stream>>>(ca_wq, W + O_CA_WQ, 512, 512, WQ);
  transpose_cast<<<dim3(16, 16, 4), 256, 0, stream>>>(ca_wk, W + O_CA_KV, 512, 512, 2 * WQ);
  transpose_cast<<<dim3(16, 16, 4), 256, 0, stream>>>(ca_wv, W + O_CA_KV + WQ, 512, 512, 2 * WQ);
  transpose_cast<<<dim3(16, 16, 4), 256, 0, stream>>>(ca_wo, W + O_CA_WO, 512, 512, WQ);
  transpose_w1 <<<dim3(128, 16, 4), 256, 0, stream>>>(ca_w1, W + O_CA_W1);
  transpose_cast<<<dim3(16, 64, 4), 256, 0, stream>>>(ca_w2, W + O_CA_W2, 2048, 512, W2SZ);
  transpose_cast<<<dim3(16, 16, 4), 256, 0, stream>>>(ta_wq, W + O_TA_WQ, 512, 512, WQ);
  transpose_cast<<<dim3(16, 16, 4), 256, 0, stream>>>(ta_wk, W + O_TA_KV, 512, 512, 2 * WQ);
  transpose_cast<<<dim3(16, 16, 4), 256, 0, stream>>>(ta_wv, W + O_TA_KV + WQ, 512, 512, 2 * WQ);
  transpose_cast<<<dim3(16, 16, 4), 256, 0, stream>>>(ta_wo, W + O_TA_WO, 512, 512, WQ);
  transpose_w1 <<<dim3(128, 16, 4), 256, 0, stream>>>(ta_w1, W + O_TA_W1);
  transpose_cast<<<dim3(16, 64, 4), 256, 0, stream>>>(ta_w2, W + O_TA_W2, 2048, 512, W2SZ);
  rope_init<<<8, 256, 0, stream>>>(cosT, sinT);
  init_lat<<<16384, 256, 0, stream>>>(qlat, lat);

  for (int b = 0; b < 4; ++b) {
    const u16* wqt   = W + O_CA_WQ + (size_t)b * WQ;
    const u16* wkvt  = W + O_CA_KV + (size_t)b * 2 * WQ;
    const u16* wot   = W + O_CA_WO + (size_t)b * WQ;
    const u16* w1t   = W + O_CA_W1 + (size_t)b * W1SZ;
    const u16* w2t   = W + O_CA_W2 + (size_t)b * W2SZ;
    const u16* twqt  = W + O_TA_WQ + (size_t)b * WQ;
    const u16* twkvt = W + O_TA_KV + (size_t)b * 2 * WQ;
    const u16* twot  = W + O_TA_WO + (size_t)b * WQ;
    const u16* tw1t  = W + O_TA_W1 + (size_t)b * W1SZ;
    const u16* tw2t  = W + O_TA_W2 + (size_t)b * W2SZ;

    // ---- cross attention ----
    rms_rows<0><<<8192, 256, 0, stream>>>(lat, ca_ln + b * 1536, xn);              // l_n
    rms_rows<0><<<16384, 256, 0, stream>>>(source, ca_ln + b * 1536 + 512, shat);  // s_n
    gemm128<0, 0, 0><<<dim3(4, 256), 256, 0, stream>>>(xn, nullptr, wqt, qb, nullptr, nullptr, 32768, 512, 512, 0);
    for (int c = 0; c < 4; ++c) {  // fused K|V + attention per 256-batch chunk
      gemm128<1, 0, 1><<<dim3(8, 192), 256, 0, stream>>>(shat, xn, wkvt, kvb, nullptr, ca_bk + b * 512, 24576, 1024, 512, c * 256);
      attn_ca<<<dim3(256, 8), 256, 0, stream>>>(qb, kvb, qb, c * 256);
    }
    gemm128<2, 0, 0><<<dim3(4, 256), 256, 0, stream>>>(qb, nullptr, wot, nullptr, lat, nullptr, 32768, 512, 512, 0);
    rms_rows<0><<<8192, 256, 0, stream>>>(lat, ca_ln + b * 1536 + 1024, xn);
    gemm128<3, 0, 0><<<dim3(32, 256), 256, 0, stream>>>(xn, nullptr, w1t, h2, nullptr, nullptr, 32768, 4096, 512, 0);
    gemm128<2, 0, 0><<<dim3(4, 256), 256, 0, stream>>>(h2, nullptr, w2t, nullptr, lat, nullptr, 32768, 512, 2048, 0);

    // ---- temporal attention ----
    rms_rows<1><<<8192, 256, 0, stream>>>(lat, ta_ln + b * 1024, xn);
    gemm128<0, 0, 0><<<dim3(4, 256), 256, 0, stream>>>(xn, nullptr, twqt, qb, nullptr, nullptr, 32768, 512, 512, 0);
    gemm128<1, 0, 0><<<dim3(8, 256), 256, 0, stream>>>(xn, nullptr, twkvt, takv, nullptr, ta_bk + b * 512, 32768, 1024, 512, 0);
    attn_ta<<<dim3(256, 8), 256, 0, stream>>>(qb, takv, cosT, sinT, qb);
    gemm128<2, 1, 0><<<dim3(4, 256), 256, 0, stream>>>(qb, nullptr, twot, nullptr, lat, nullptr, 32768, 512, 512, 0);
    rms_rows<1><<<8192, 256, 0, stream>>>(lat, ta_ln + b * 1024 + 512, xn);
    gemm128<3, 0, 0><<<dim3(32, 256), 256, 0, stream>>>(xn, nullptr, tw1t, h2, nullptr, nullptr, 32768, 4096, 512, 0);
    gemm128<2, 1, 0><<<dim3(4, 256), 256, 0, stream>>>(h2, nullptr, tw2t, nullptr, lat, nullptr, 32768, 512, 2048, 0);
  }
}

// Round 5
// 6027.155 us; speedup vs baseline: 1.0626x; 1.0472x over previous
//
#include <hip/hip_runtime.h>
#include <stdint.h>

// ---------------------------------------------------------------------------
// SpatioTemporalPerceiverResampler  (D=512, H=8, DH=64, NB=4, DMLP=2048,
// L=32, T=128, B=8, BT=1024, ROPE_DIM=32)
// R5: all GEMMs -> 256x256 8-phase-style pipeline (T3+T4 counted vmcnt,
// T2 LDS XOR-swizzle both-sides, T5 setprio). bf16 MFMA 16x16x32, fp32 accum.
// lat lives in d_out. Attn/RMS kernels unchanged from R4 (proven).
// ---------------------------------------------------------------------------

typedef short    bf16x8 __attribute__((ext_vector_type(8)));
typedef float    f32x4  __attribute__((ext_vector_type(4)));
typedef uint16_t u16;

__device__ __forceinline__ float bf2f(uint32_t u) {
  union { uint32_t i; float f; } x; x.i = u << 16; return x.f;
}
__device__ __forceinline__ u16 f2bf(float f) {
  union { float f; uint32_t i; } x; x.f = f;
  return (u16)((x.i + 0x7fffu + ((x.i >> 16) & 1u)) >> 16);  // RNE
}
__device__ __forceinline__ float gelu_t(float x) {  // jax.nn.gelu approximate=True
  float u = 0.7978845608028654f * (x + 0.044715f * x * x * x);
  float t = 1.f - 2.f / (__expf(2.f * u) + 1.f);
  return 0.5f * x * (1.f + t);
}
// r_x = (b*L + l)*T + t  ->  lat row (b*T + t)*L + l     (L=32, T=128)
template<int RMAP>
__device__ __forceinline__ int maprow(int r) {
  if (RMAP == 0) return r;
  int b = r >> 12, rem = r & 4095;
  return ((b << 7) + (rem & 127)) * 32 + (rem >> 7);
}
__device__ __forceinline__ void glds16(const u16* g, u16* l) {
  __builtin_amdgcn_global_load_lds((const __attribute__((address_space(1))) uint32_t*)(g),
                                   (__attribute__((address_space(3))) uint32_t*)(l),
                                   16, 0, 0);
}
// K-tile boundary gate: drain this wave's staging loads, sync, fence compiler.
__device__ __forceinline__ void kt_gate() {
  asm volatile("s_waitcnt vmcnt(0)" ::: "memory");
  __builtin_amdgcn_s_barrier();
  asm volatile("" ::: "memory");
}

// ---------------------------------------------------------------------------
// Weight cast+transpose: src fp32 [R][C] -> dst bf16 [C][R]; z strides:
// src by R*C, dst by zsD (allows interleaving wk/wv per block).
// ---------------------------------------------------------------------------
__global__ __launch_bounds__(256) void transpose_cast(const float* __restrict__ src,
                                                      u16* __restrict__ dst,
                                                      int R, int C, size_t zsD) {
  src += (size_t)blockIdx.z * R * C;
  dst += (size_t)blockIdx.z * zsD;
  __shared__ float t[32][33];
  int c0 = blockIdx.x * 32, r0 = blockIdx.y * 32;
  int tx = threadIdx.x & 31, ty = threadIdx.x >> 5;
#pragma unroll
  for (int i = 0; i < 32; i += 8) t[ty + i][tx] = src[(size_t)(r0 + ty + i) * C + c0 + tx];
  __syncthreads();
#pragma unroll
  for (int i = 0; i < 32; i += 8)
    dst[(size_t)(c0 + ty + i) * R + r0 + tx] = f2bf(t[tx][ty + i]);
}

// w1 (512 x 4096) -> w1t (4096 x 512), GEGLU interleave for the 256-tile GEMM:
// dst row c: t=c>>8, w=(c>>6)&3, p=c&63 -> src col t*128 + w*32 + (p&31) + (p&32?2048:0)
__global__ __launch_bounds__(256) void transpose_w1(const float* __restrict__ src,
                                                    u16* __restrict__ dst) {
  src += (size_t)blockIdx.z * 512 * 4096;
  dst += (size_t)blockIdx.z * 512 * 4096;
  __shared__ float t[32][33];
  int c0 = blockIdx.x * 32, r0 = blockIdx.y * 32;
  int m0 = (c0 >> 8) * 128 + ((c0 >> 6) & 3) * 32 + ((c0 & 32) ? 2048 : 0);
  int tx = threadIdx.x & 31, ty = threadIdx.x >> 5;
#pragma unroll
  for (int i = 0; i < 32; i += 8) t[ty + i][tx] = src[(size_t)(r0 + ty + i) * 4096 + m0 + tx];
  __syncthreads();
#pragma unroll
  for (int i = 0; i < 32; i += 8)
    dst[(size_t)(c0 + ty + i) * 512 + r0 + tx] = f2bf(t[tx][ty + i]);
}

// ---------------------------------------------------------------------------
__global__ void rope_init(float* cosT, float* sinT) {
  int idx = blockIdx.x * 256 + threadIdx.x;
  if (idx < 128 * 16) {
    int t = idx >> 4, j = idx & 15;
    float inv = __expf(-logf(10000.f) * (float)j / 16.f);
    float a = (float)t * inv;
    cosT[idx] = cosf(a);
    sinT[idx] = sinf(a);
  }
}

// latents init: broadcast query_latents (32,512) over 1024 batches (float4)
__global__ __launch_bounds__(256) void init_lat(const float* __restrict__ ql,
                                                float* __restrict__ lat) {
  size_t i = (size_t)blockIdx.x * 256 + threadIdx.x;  // float4 index
  int r = (int)(i >> 7), cw = (int)(i & 127);
  int l = r & 31;
  ((float4*)lat)[i] = ((const float4*)ql)[l * 128 + cw];
}

// ---------------------------------------------------------------------------
// RMSNorm: one wave per row of 512; out bf16. RMAP=1 -> permuted source row.
// ---------------------------------------------------------------------------
template<int RMAP>
__global__ __launch_bounds__(256) void rms_rows(const float* __restrict__ src,
                                                const float* __restrict__ g,
                                                u16* __restrict__ out) {
  const int wid = threadIdx.x >> 6, lane = threadIdx.x & 63;
  const int row = (blockIdx.x << 2) + wid;
  const int srow = maprow<RMAP>(row);
  const float4* p = (const float4*)(src + (size_t)srow * 512);
  float4 v0 = p[lane * 2], v1 = p[lane * 2 + 1];
  float ss = v0.x * v0.x + v0.y * v0.y + v0.z * v0.z + v0.w * v0.w +
             v1.x * v1.x + v1.y * v1.y + v1.z * v1.z + v1.w * v1.w;
#pragma unroll
  for (int m = 1; m < 64; m <<= 1) ss += __shfl_xor(ss, m);
  const float rs = rsqrtf(ss * (1.f / 512.f) + 1e-6f);
  const float4* gp = (const float4*)g;
  float4 g0 = gp[lane * 2], g1 = gp[lane * 2 + 1];
  u16 rb[8];
  rb[0] = f2bf(v0.x * rs * g0.x); rb[1] = f2bf(v0.y * rs * g0.y);
  rb[2] = f2bf(v0.z * rs * g0.z); rb[3] = f2bf(v0.w * rs * g0.w);
  rb[4] = f2bf(v1.x * rs * g1.x); rb[5] = f2bf(v1.y * rs * g1.y);
  rb[6] = f2bf(v1.z * rs * g1.z); rb[7] = f2bf(v1.w * rs * g1.w);
  *(int4*)(out + (size_t)row * 512 + lane * 8) = *(int4*)rb;
}

// ---------------------------------------------------------------------------
// gemm256: C[M,N] = A[M,K](bf16,row) @ Bt[N,K](bf16,row)^T
// 256x256 tile, BK=64, 512 thr = 8 waves (2M x 4N), per-wave C 128x64.
// Pipeline: double-buffered LDS; per K-tile 4 phases {stage-next || ds_read ||
// 16 MFMA}; one vmcnt(0)+barrier per K-tile (kt_gate), raw s_barrier per phase.
// LDS XOR-swizzle (col ^= (row&7)<<3 elems) on BOTH stage-source and ds_read.
// EPI: 0 bf16 out; 1 +bias on cols<512; 2 latF[maprow(row)]+=acc; 3 GEGLU->h2.
// AMAP: 1 = CA kv row map (rows = concat(s_n 64, l_n 32) per batch).
// ---------------------------------------------------------------------------
template<int EPI, int RMAP, int AMAP>
__global__ __launch_bounds__(512, 2) void gemm256(const u16* __restrict__ A,
                                                  const u16* __restrict__ A2,
                                                  const u16* __restrict__ Bt,
                                                  u16* __restrict__ outH,
                                                  float* __restrict__ latF,
                                                  const float* __restrict__ bias,
                                                  int M, int N, int K, int nb) {
  __shared__ __align__(16) u16 Ab[2][256 * 64];
  __shared__ __align__(16) u16 Bb[2][256 * 64];
  const int tid = threadIdx.x;
  const int m0 = blockIdx.y << 8;
  const int n0 = blockIdx.x << 8;
  const int wid = tid >> 6, lane = tid & 63;
  const int wm = wid >> 2, wn = wid & 3;
  const int lr = lane & 15, lg = lane >> 4;
  const int rx = (lr & 7) << 3;  // read-side col XOR (elems)

  // stage half h (128 rows x 64 cols) of K-tile kt into buffer bf.
  // LDS dest linear (gload_lds requirement); source col pre-swizzled.
  auto stageA = [&](int bf, int kt, int h) {
#pragma unroll
    for (int i = 0; i < 2; ++i) {
      const int e = (i * 512 + tid) * 8;
      const int r = e >> 6;
      const int cs = (e & 63) ^ ((r & 7) << 3);
      const u16* src;
      if constexpr (AMAP == 0) {
        src = A + (size_t)(m0 + h * 128 + r) * K + kt * 64 + cs;
      } else {
        const int R = m0 + h * 128 + r;
        const int n_ = R / 96;
        const int j = R - n_ * 96;
        src = (j < 64) ? A  + ((size_t)((nb + n_) * 64 + j)) * 512 + kt * 64 + cs
                       : A2 + ((size_t)((nb + n_) * 32 + (j - 64))) * 512 + kt * 64 + cs;
      }
      glds16(src, &Ab[bf][h * 8192 + e]);
    }
  };
  auto stageB = [&](int bf, int kt, int h) {
#pragma unroll
    for (int i = 0; i < 2; ++i) {
      const int e = (i * 512 + tid) * 8;
      const int r = e >> 6;
      const int cs = (e & 63) ^ ((r & 7) << 3);
      glds16(Bt + (size_t)(n0 + h * 128 + r) * K + kt * 64 + cs, &Bb[bf][h * 8192 + e]);
    }
  };

  f32x4 acc[8][4];
#pragma unroll
  for (int i = 0; i < 8; ++i)
#pragma unroll
    for (int j = 0; j < 4; ++j) acc[i][j] = (f32x4){0.f, 0.f, 0.f, 0.f};

  // prologue: stage kt0 fully, gate.
  stageA(0, 0, 0); stageA(0, 0, 1);
  stageB(0, 0, 0); stageB(0, 0, 1);
  kt_gate();

  const int nkt = K >> 6;
  for (int kt = 0; kt < nkt; ++kt) {
    const int bf = kt & 1;
    const u16* Abase = &Ab[bf][0];
    const u16* Bbase = &Bb[bf][0];
    const bool pf = (kt + 1 < nkt);
    bf16x8 bfr[2][4];  // [ks][in], whole K-tile
#pragma unroll
    for (int p = 0; p < 4; ++p) {
      if (p == 0 && pf) { stageA(bf ^ 1, kt + 1, 0); stageA(bf ^ 1, kt + 1, 1); }
      if (p == 1 && pf) { stageB(bf ^ 1, kt + 1, 0); stageB(bf ^ 1, kt + 1, 1); }
      if (p == 0) {
#pragma unroll
        for (int ks = 0; ks < 2; ++ks)
#pragma unroll
          for (int in = 0; in < 4; ++in) {
            const int rw = wn * 64 + in * 16 + lr;
            bfr[ks][in] = *(const bf16x8*)&Bbase[rw * 64 + ((ks * 32 + lg * 8) ^ rx)];
          }
      }
      bf16x8 afr[2][2];  // [d][ks]
#pragma unroll
      for (int d = 0; d < 2; ++d)
#pragma unroll
        for (int ks = 0; ks < 2; ++ks) {
          const int rw = wm * 128 + (p * 2 + d) * 16 + lr;
          afr[d][ks] = *(const bf16x8*)&Abase[rw * 64 + ((ks * 32 + lg * 8) ^ rx)];
        }
      __builtin_amdgcn_s_setprio(1);
#pragma unroll
      for (int d = 0; d < 2; ++d)
#pragma unroll
        for (int in = 0; in < 4; ++in)
#pragma unroll
          for (int ks = 0; ks < 2; ++ks)
            acc[p * 2 + d][in] = __builtin_amdgcn_mfma_f32_16x16x32_bf16(
                afr[d][ks], bfr[ks][in], acc[p * 2 + d][in], 0, 0, 0);
      __builtin_amdgcn_s_setprio(0);
      if (p == 3) {
        kt_gate();  // next K-tile's stages (issued p0/p1) complete; buffers swap
      } else {
        __builtin_amdgcn_s_barrier();
      }
    }
  }

  // ---- epilogues (direct stores; cost proven negligible in R4) ----
  if constexpr (EPI == 3) {
    const int t128 = n0 >> 1;
#pragma unroll
    for (int im = 0; im < 8; ++im)
#pragma unroll
      for (int in = 0; in < 2; ++in)
#pragma unroll
        for (int j = 0; j < 4; ++j) {
          const int row = m0 + wm * 128 + im * 16 + lg * 4 + j;
          const int hcol = t128 + wn * 32 + in * 16 + lr;
          outH[(size_t)row * 2048 + hcol] = f2bf(acc[im][in][j] * gelu_t(acc[im][in + 2][j]));
        }
  } else if constexpr (EPI == 2) {
#pragma unroll
    for (int im = 0; im < 8; ++im)
#pragma unroll
      for (int in = 0; in < 4; ++in) {
        const int col = n0 + wn * 64 + in * 16 + lr;
#pragma unroll
        for (int j = 0; j < 4; ++j) {
          const int row = m0 + wm * 128 + im * 16 + lg * 4 + j;
          const size_t rr = (size_t)maprow<RMAP>(row) * 512 + col;
          latF[rr] += acc[im][in][j];
        }
      }
  } else {
    float bv4[4];
    if constexpr (EPI == 1) {
#pragma unroll
      for (int in = 0; in < 4; ++in)
        bv4[in] = (n0 < 512) ? bias[n0 + wn * 64 + in * 16 + lr] : 0.f;
    }
#pragma unroll
    for (int im = 0; im < 8; ++im)
#pragma unroll
      for (int in = 0; in < 4; ++in) {
        const int col = n0 + wn * 64 + in * 16 + lr;
#pragma unroll
        for (int j = 0; j < 4; ++j) {
          const int row = m0 + wm * 128 + im * 16 + lg * 4 + j;
          float v = acc[im][in][j];
          if constexpr (EPI == 1) v += bv4[in];
          outH[(size_t)row * N + col] = f2bf(v);
        }
      }
  }
}

// ---------------------------------------------------------------------------
// Cross-attention (chunked over n): block per (n_local,h), n = nb + n_local.
// Lq=32, Lk=96, DH=64. kv fused rows [1024]: k cols 0-511, v cols 512-1023.
// ---------------------------------------------------------------------------
__global__ __launch_bounds__(256) void attn_ca(const u16* q,
                                               const u16* __restrict__ kv,
                                               u16* o, int nb) {
  __shared__ __align__(16) u16 Qs[32 * 64];
  __shared__ __align__(16) u16 Ks[96 * 64];
  __shared__ __align__(16) u16 Vt[64 * 96];   // transposed [d][kj]
  __shared__ float S[32 * 96];
  __shared__ __align__(16) u16 Pb[32 * 96];
  const int nl = blockIdx.x, n = nb + nl, h = blockIdx.y, tid = threadIdx.x;
  {
    int r = tid >> 3, c = (tid & 7) * 8;
    *(int4*)&Qs[r * 64 + c] = *(const int4*)&q[((size_t)n * 32 + r) * 512 + h * 64 + c];
  }
#pragma unroll
  for (int i = 0; i < 3; ++i) {
    int r = i * 32 + (tid >> 3), c = (tid & 7) * 8;
    *(int4*)&Ks[r * 64 + c] = *(const int4*)&kv[((size_t)nl * 96 + r) * 1024 + h * 64 + c];
    int4 pv = *(const int4*)&kv[((size_t)nl * 96 + r) * 1024 + 512 + h * 64 + c];
    const u16* pu = (const u16*)&pv;
#pragma unroll
    for (int e = 0; e < 8; ++e) Vt[(c + e) * 96 + r] = pu[e];
  }
  __syncthreads();
  const int wid = tid >> 6, lane = tid & 63, lr = lane & 15, lg = lane >> 4;
  {  // QK^T: wave -> 16 rows x 48 cols
    const int m0 = (wid & 1) * 16, nbc = (wid >> 1) * 48;
    f32x4 sa[3];
#pragma unroll
    for (int f = 0; f < 3; ++f) sa[f] = (f32x4){0.f, 0.f, 0.f, 0.f};
#pragma unroll
    for (int ks = 0; ks < 2; ++ks) {
      bf16x8 a = *(const bf16x8*)&Qs[(m0 + lr) * 64 + ks * 32 + lg * 8];
#pragma unroll
      for (int f = 0; f < 3; ++f) {
        bf16x8 bb = *(const bf16x8*)&Ks[(nbc + f * 16 + lr) * 64 + ks * 32 + lg * 8];
        sa[f] = __builtin_amdgcn_mfma_f32_16x16x32_bf16(a, bb, sa[f], 0, 0, 0);
      }
    }
#pragma unroll
    for (int f = 0; f < 3; ++f)
#pragma unroll
      for (int j = 0; j < 4; ++j)
        S[(m0 + lg * 4 + j) * 96 + nbc + f * 16 + lr] = sa[f][j] * 0.125f;
  }
  __syncthreads();
  {  // softmax rows of 96: 8 lanes per row
    int row = tid >> 3, sub = tid & 7;
    float m = -1e30f;
    for (int j = sub; j < 96; j += 8) m = fmaxf(m, S[row * 96 + j]);
    m = fmaxf(m, __shfl_xor(m, 1)); m = fmaxf(m, __shfl_xor(m, 2)); m = fmaxf(m, __shfl_xor(m, 4));
    float sum = 0.f;
    for (int j = sub; j < 96; j += 8) { float e = __expf(S[row * 96 + j] - m); S[row * 96 + j] = e; sum += e; }
    sum += __shfl_xor(sum, 1); sum += __shfl_xor(sum, 2); sum += __shfl_xor(sum, 4);
    float inv = 1.f / sum;
    for (int j = sub; j < 96; j += 8) Pb[row * 96 + j] = f2bf(S[row * 96 + j] * inv);
  }
  __syncthreads();
  {  // PV: wave -> 16 rows x 32 d-cols, K=96
    const int m0 = (wid & 1) * 16, n0d = (wid >> 1) * 32;
    f32x4 oa[2];
#pragma unroll
    for (int f = 0; f < 2; ++f) oa[f] = (f32x4){0.f, 0.f, 0.f, 0.f};
#pragma unroll
    for (int ks = 0; ks < 3; ++ks) {
      bf16x8 a = *(const bf16x8*)&Pb[(m0 + lr) * 96 + ks * 32 + lg * 8];
#pragma unroll
      for (int f = 0; f < 2; ++f) {
        bf16x8 bb = *(const bf16x8*)&Vt[(n0d + f * 16 + lr) * 96 + ks * 32 + lg * 8];
        oa[f] = __builtin_amdgcn_mfma_f32_16x16x32_bf16(a, bb, oa[f], 0, 0, 0);
      }
    }
    __syncthreads();
#pragma unroll
    for (int f = 0; f < 2; ++f)
#pragma unroll
      for (int j = 0; j < 4; ++j)
        o[((size_t)n * 32 + m0 + lg * 4 + j) * 512 + h * 64 + n0d + f * 16 + lr] = f2bf(oa[f][j]);
  }
}

// ---------------------------------------------------------------------------
// Temporal attention with RoPE: block per (n,h), n in [0,256). T=128.
// q stride 512; kv fused stride 1024 (k cols 0-511, v cols 512-1023).
// ---------------------------------------------------------------------------
__global__ __launch_bounds__(256) void attn_ta(const u16* q,
                                               const u16* __restrict__ kv,
                                               const float* __restrict__ cosT,
                                               const float* __restrict__ sinT,
                                               u16* o) {
  __shared__ __align__(16) u16 Qs[128 * 64];
  __shared__ __align__(16) u16 Ks[128 * 64];
  __shared__ __align__(16) u16 Vt[64 * 128];
  __shared__ float S[128 * 128];
  __shared__ __align__(16) u16 Pb[128 * 128];
  const int n = blockIdx.x, h = blockIdx.y, tid = threadIdx.x;
#pragma unroll
  for (int i = 0; i < 16; ++i) {
    int idx = i * 256 + tid;
    int t = idx >> 5, pr = idx & 31;
    uint32_t uq = *(const uint32_t*)&q[((size_t)n * 128 + t) * 512 + h * 64 + pr * 2];
    uint32_t uk = *(const uint32_t*)&kv[((size_t)n * 128 + t) * 1024 + h * 64 + pr * 2];
    float q1 = bf2f(uq & 0xffff), q2 = bf2f(uq >> 16);
    float k1 = bf2f(uk & 0xffff), k2 = bf2f(uk >> 16);
    if (pr < 16) {
      float c = cosT[t * 16 + pr], s = sinT[t * 16 + pr];
      float a;
      a = q1 * c - q2 * s; q2 = q1 * s + q2 * c; q1 = a;
      a = k1 * c - k2 * s; k2 = k1 * s + k2 * c; k1 = a;
    }
    Qs[t * 64 + pr * 2] = f2bf(q1); Qs[t * 64 + pr * 2 + 1] = f2bf(q2);
    Ks[t * 64 + pr * 2] = f2bf(k1); Ks[t * 64 + pr * 2 + 1] = f2bf(k2);
  }
#pragma unroll
  for (int i = 0; i < 4; ++i) {  // V transposed
    int idx = i * 256 + tid;
    int r = idx >> 3, c = (idx & 7) * 8;
    int4 pv = *(const int4*)&kv[((size_t)n * 128 + r) * 1024 + 512 + h * 64 + c];
    const u16* pu = (const u16*)&pv;
#pragma unroll
    for (int e = 0; e < 8; ++e) Vt[(c + e) * 128 + r] = pu[e];
  }
  __syncthreads();
  const int wid = tid >> 6, lane = tid & 63, lr = lane & 15, lg = lane >> 4;
  const int wm = wid >> 1, wn = wid & 1;
  {  // QK^T 128x128: wave -> 64x64
    f32x4 sa[4][4];
#pragma unroll
    for (int i = 0; i < 4; ++i)
#pragma unroll
      for (int j = 0; j < 4; ++j) sa[i][j] = (f32x4){0.f, 0.f, 0.f, 0.f};
#pragma unroll
    for (int ks = 0; ks < 2; ++ks) {
      bf16x8 av[4], bv[4];
#pragma unroll
      for (int im = 0; im < 4; ++im)
        av[im] = *(const bf16x8*)&Qs[(wm * 64 + im * 16 + lr) * 64 + ks * 32 + lg * 8];
#pragma unroll
      for (int in = 0; in < 4; ++in)
        bv[in] = *(const bf16x8*)&Ks[(wn * 64 + in * 16 + lr) * 64 + ks * 32 + lg * 8];
#pragma unroll
      for (int im = 0; im < 4; ++im)
#pragma unroll
        for (int in = 0; in < 4; ++in)
          sa[im][in] = __builtin_amdgcn_mfma_f32_16x16x32_bf16(av[im], bv[in], sa[im][in], 0, 0, 0);
    }
#pragma unroll
    for (int im = 0; im < 4; ++im)
#pragma unroll
      for (int in = 0; in < 4; ++in)
#pragma unroll
        for (int j = 0; j < 4; ++j)
          S[(wm * 64 + im * 16 + lg * 4 + j) * 128 + wn * 64 + in * 16 + lr] = sa[im][in][j] * 0.125f;
  }
  __syncthreads();
  {  // softmax rows of 128: 2 lanes per row
    int row = tid >> 1, sub = tid & 1;
    float m = -1e30f;
    for (int j = sub; j < 128; j += 2) m = fmaxf(m, S[row * 128 + j]);
    m = fmaxf(m, __shfl_xor(m, 1));
    float sum = 0.f;
    for (int j = sub; j < 128; j += 2) { float e = __expf(S[row * 128 + j] - m); S[row * 128 + j] = e; sum += e; }
    sum += __shfl_xor(sum, 1);
    float inv = 1.f / sum;
    for (int j = sub; j < 128; j += 2) Pb[row * 128 + j] = f2bf(S[row * 128 + j] * inv);
  }
  __syncthreads();
  {  // PV: wave -> 32 rows x 64 d, K=128
    f32x4 oa[2][4];
#pragma unroll
    for (int i = 0; i < 2; ++i)
#pragma unroll
      for (int j = 0; j < 4; ++j) oa[i][j] = (f32x4){0.f, 0.f, 0.f, 0.f};
#pragma unroll
    for (int ks = 0; ks < 4; ++ks) {
      bf16x8 av[2], bv[4];
#pragma unroll
      for (int im = 0; im < 2; ++im)
        av[im] = *(const bf16x8*)&Pb[(wid * 32 + im * 16 + lr) * 128 + ks * 32 + lg * 8];
#pragma unroll
      for (int in = 0; in < 4; ++in)
        bv[in] = *(const bf16x8*)&Vt[(in * 16 + lr) * 128 + ks * 32 + lg * 8];
#pragma unroll
      for (int im = 0; im < 2; ++im)
#pragma unroll
        for (int in = 0; in < 4; ++in)
          oa[im][in] = __builtin_amdgcn_mfma_f32_16x16x32_bf16(av[im], bv[in], oa[im][in], 0, 0, 0);
    }
    __syncthreads();
#pragma unroll
    for (int im = 0; im < 2; ++im)
#pragma unroll
      for (int in = 0; in < 4; ++in)
#pragma unroll
        for (int j = 0; j < 4; ++j) {
          int qi = wid * 32 + im * 16 + lg * 4 + j;
          o[((size_t)n * 128 + qi) * 512 + h * 64 + in * 16 + lr] = f2bf(oa[im][in][j]);
        }
  }
}

// ---------------------------------------------------------------------------
extern "C" void kernel_launch(void* const* d_in, const int* in_sizes, int n_in,
                              void* d_out, int out_size, void* d_ws, size_t ws_size,
                              hipStream_t stream) {
  const float* source = (const float*)d_in[0];
  const float* qlat   = (const float*)d_in[1];
  const float* ca_ln  = (const float*)d_in[2];
  const float* ca_wq  = (const float*)d_in[3];
  const float* ca_wk  = (const float*)d_in[4];
  const float* ca_bk  = (const float*)d_in[5];
  const float* ca_wv  = (const float*)d_in[6];
  const float* ca_wo  = (const float*)d_in[7];
  const float* ca_w1  = (const float*)d_in[8];
  const float* ca_w2  = (const float*)d_in[9];
  const float* ta_ln  = (const float*)d_in[10];
  const float* ta_wq  = (const float*)d_in[11];
  const float* ta_wk  = (const float*)d_in[12];
  const float* ta_bk  = (const float*)d_in[13];
  const float* ta_wv  = (const float*)d_in[14];
  const float* ta_wo  = (const float*)d_in[15];
  const float* ta_w1  = (const float*)d_in[16];
  const float* ta_w2  = (const float*)d_in[17];
  float* lat = (float*)d_out;  // residual stream lives in d_out
  char* ws = (char*)d_ws;
  (void)in_sizes; (void)n_in; (void)out_size;

  if (ws_size < 251674624ull) return;  // known-good guard from R2

  // weight sub-offsets (bf16 elems). KV weights interleaved per block:
  // O_CA_KV + b*2WQ = [wk_b^T ; wv_b^T] -> fused Bt N=1024.
  const size_t WQ = 512 * 512, W1SZ = (size_t)512 * 4096, W2SZ = (size_t)2048 * 512;
  const size_t O_CA_WQ = 0,
               O_CA_KV = 4 * WQ,
               O_CA_WO = 12 * WQ,
               O_CA_W1 = 16 * WQ,
               O_CA_W2 = O_CA_W1 + 4 * W1SZ,
               O_TA_WQ = O_CA_W2 + 4 * W2SZ,
               O_TA_KV = O_TA_WQ + 4 * WQ,
               O_TA_WO = O_TA_KV + 8 * WQ,
               O_TA_W1 = O_TA_WO + 4 * WQ,
               O_TA_W2 = O_TA_W1 + 4 * W1SZ;  // ends at 128*WQ = 67,108,864 B

  // ws layout (bytes):
  u16*   W    = (u16*)ws;                    // [0, 67,108,864)  weights (exact)
  u16*   xn   = (u16*)(ws + 67108864);       // 32 MiB
  u16*   shat = (u16*)(ws + 100663296);      // 64 MiB (CA s_n; TA fused KV; h2 head)
  u16*   qb   = (u16*)(ws + 167772160);      // 32 MiB (q / attn out)
  u16*   kvb  = (u16*)(ws + 201326592);      // 48 MiB (CA fused K|V chunk)
  u16*   h2   = shat;                        // MLP hidden 128 MiB
  u16*   takv = shat;                        // TA fused KV 64 MiB
  float* cosT = (float*)(ws + 251658240);    // 8 KiB  (tail gap, within guard)
  float* sinT = (float*)(ws + 251666432);    // 8 KiB

  // --- weight conversion ---
  transpose_cast<<<dim3(16, 16, 4), 256, 0, stream>>>(ca_wq, W + O_CA_WQ, 512, 512, WQ);
  transpose_cast<<<dim3(16, 16, 4), 256, 0, stream>>>(ca_wk, W + O_CA_KV, 512, 512, 2 * WQ);
  transpose_cast<<<dim3(16, 16, 4), 256, 0, stream>>>(ca_wv, W + O_CA_KV + WQ, 512, 512, 2 * WQ);
  transpose_cast<<<dim3(16, 16, 4), 256, 0, stream>>>(ca_wo, W + O_CA_WO, 512, 512, WQ);
  transpose_w1 <<<dim3(128, 16, 4), 256, 0, stream>>>(ca_w1, W + O_CA_W1);
  transpose_cast<<<dim3(16, 64, 4), 256, 0, stream>>>(ca_w2, W + O_CA_W2, 2048, 512, W2SZ);
  transpose_cast<<<dim3(16, 16, 4), 256, 0, stream>>>(ta_wq, W + O_TA_WQ, 512, 512, WQ);
  transpose_cast<<<dim3(16, 16, 4), 256, 0, stream>>>(ta_wk, W + O_TA_KV, 512, 512, 2 * WQ);
  transpose_cast<<<dim3(16, 16, 4), 256, 0, stream>>>(ta_wv, W + O_TA_KV + WQ, 512, 512, 2 * WQ);
  transpose_cast<<<dim3(16, 16, 4), 256, 0, stream>>>(ta_wo, W + O_TA_WO, 512, 512, WQ);
  transpose_w1 <<<dim3(128, 16, 4), 256, 0, stream>>>(ta_w1, W + O_TA_W1);
  transpose_cast<<<dim3(16, 64, 4), 256, 0, stream>>>(ta_w2, W + O_TA_W2, 2048, 512, W2SZ);
  rope_init<<<8, 256, 0, stream>>>(cosT, sinT);
  init_lat<<<16384, 256, 0, stream>>>(qlat, lat);

  for (int b = 0; b < 4; ++b) {
    const u16* wqt   = W + O_CA_WQ + (size_t)b * WQ;
    const u16* wkvt  = W + O_CA_KV + (size_t)b * 2 * WQ;
    const u16* wot   = W + O_CA_WO + (size_t)b * WQ;
    const u16* w1t   = W + O_CA_W1 + (size_t)b * W1SZ;
    const u16* w2t   = W + O_CA_W2 + (size_t)b * W2SZ;
    const u16* twqt  = W + O_TA_WQ + (size_t)b * WQ;
    const u16* twkvt = W + O_TA_KV + (size_t)b * 2 * WQ;
    const u16* twot  = W + O_TA_WO + (size_t)b * WQ;
    const u16* tw1t  = W + O_TA_W1 + (size_t)b * W1SZ;
    const u16* tw2t  = W + O_TA_W2 + (size_t)b * W2SZ;

    // ---- cross attention ----
    rms_rows<0><<<8192, 256, 0, stream>>>(lat, ca_ln + b * 1536, xn);              // l_n
    rms_rows<0><<<16384, 256, 0, stream>>>(source, ca_ln + b * 1536 + 512, shat);  // s_n
    gemm256<0, 0, 0><<<dim3(2, 128), 512, 0, stream>>>(xn, nullptr, wqt, qb, nullptr, nullptr, 32768, 512, 512, 0);
    for (int c = 0; c < 4; ++c) {  // fused K|V + attention per 256-batch chunk
      gemm256<1, 0, 1><<<dim3(4, 96), 512, 0, stream>>>(shat, xn, wkvt, kvb, nullptr, ca_bk + b * 512, 24576, 1024, 512, c * 256);
      attn_ca<<<dim3(256, 8), 256, 0, stream>>>(qb, kvb, qb, c * 256);
    }
    gemm256<2, 0, 0><<<dim3(2, 128), 512, 0, stream>>>(qb, nullptr, wot, nullptr, lat, nullptr, 32768, 512, 512, 0);
    rms_rows<0><<<8192, 256, 0, stream>>>(lat, ca_ln + b * 1536 + 1024, xn);
    gemm256<3, 0, 0><<<dim3(16, 128), 512, 0, stream>>>(xn, nullptr, w1t, h2, nullptr, nullptr, 32768, 4096, 512, 0);
    gemm256<2, 0, 0><<<dim3(2, 128), 512, 0, stream>>>(h2, nullptr, w2t, nullptr, lat, nullptr, 32768, 512, 2048, 0);

    // ---- temporal attention ----
    rms_rows<1><<<8192, 256, 0, stream>>>(lat, ta_ln + b * 1024, xn);
    gemm256<0, 0, 0><<<dim3(2, 128), 512, 0, stream>>>(xn, nullptr, twqt, qb, nullptr, nullptr, 32768, 512, 512, 0);
    gemm256<1, 0, 0><<<dim3(4, 128), 512, 0, stream>>>(xn, nullptr, twkvt, takv, nullptr, ta_bk + b * 512, 32768, 1024, 512, 0);
    attn_ta<<<dim3(256, 8), 256, 0, stream>>>(qb, takv, cosT, sinT, qb);
    gemm256<2, 1, 0><<<dim3(2, 128), 512, 0, stream>>>(qb, nullptr, twot, nullptr, lat, nullptr, 32768, 512, 512, 0);
    rms_rows<1><<<8192, 256, 0, stream>>>(lat, ta_ln + b * 1024 + 512, xn);
    gemm256<3, 0, 0><<<dim3(16, 128), 512, 0, stream>>>(xn, nullptr, tw1t, h2, nullptr, nullptr, 32768, 4096, 512, 0);
    gemm256<2, 1, 0><<<dim3(2, 128), 512, 0, stream>>>(h2, nullptr, tw2t, nullptr, lat, nullptr, 32768, 512, 2048, 0);
  }
}

// Round 6
// 5313.061 us; speedup vs baseline: 1.2055x; 1.1344x over previous
//
#include <hip/hip_runtime.h>
#include <stdint.h>

// ---------------------------------------------------------------------------
// SpatioTemporalPerceiverResampler  (D=512, H=8, DH=64, NB=4, DMLP=2048,
// L=32, T=128, B=8, BT=1024, ROPE_DIM=32)
// R6: attention rewrite -- no S buffer (register softmax, wave-parallel,
// deferred normalization), padded LDS (no bank conflicts), Pb aliases Qs/Ks.
// GEMM path (gemm256 8-phase, T2/T3/T4/T5) unchanged from R5.
// ---------------------------------------------------------------------------

typedef short    bf16x8 __attribute__((ext_vector_type(8)));
typedef float    f32x4  __attribute__((ext_vector_type(4)));
typedef uint16_t u16;

__device__ __forceinline__ float bf2f(uint32_t u) {
  union { uint32_t i; float f; } x; x.i = u << 16; return x.f;
}
__device__ __forceinline__ u16 f2bf(float f) {
  union { float f; uint32_t i; } x; x.f = f;
  return (u16)((x.i + 0x7fffu + ((x.i >> 16) & 1u)) >> 16);  // RNE
}
__device__ __forceinline__ float gelu_t(float x) {  // jax.nn.gelu approximate=True
  float u = 0.7978845608028654f * (x + 0.044715f * x * x * x);
  float t = 1.f - 2.f / (__expf(2.f * u) + 1.f);
  return 0.5f * x * (1.f + t);
}
// r_x = (b*L + l)*T + t  ->  lat row (b*T + t)*L + l     (L=32, T=128)
template<int RMAP>
__device__ __forceinline__ int maprow(int r) {
  if (RMAP == 0) return r;
  int b = r >> 12, rem = r & 4095;
  return ((b << 7) + (rem & 127)) * 32 + (rem >> 7);
}
__device__ __forceinline__ void glds16(const u16* g, u16* l) {
  __builtin_amdgcn_global_load_lds((const __attribute__((address_space(1))) uint32_t*)(g),
                                   (__attribute__((address_space(3))) uint32_t*)(l),
                                   16, 0, 0);
}
// K-tile boundary gate: drain this wave's staging loads, sync, fence compiler.
__device__ __forceinline__ void kt_gate() {
  asm volatile("s_waitcnt vmcnt(0)" ::: "memory");
  __builtin_amdgcn_s_barrier();
  asm volatile("" ::: "memory");
}

// ---------------------------------------------------------------------------
// Weight cast+transpose: src fp32 [R][C] -> dst bf16 [C][R]; z strides:
// src by R*C, dst by zsD (allows interleaving wk/wv per block).
// ---------------------------------------------------------------------------
__global__ __launch_bounds__(256) void transpose_cast(const float* __restrict__ src,
                                                      u16* __restrict__ dst,
                                                      int R, int C, size_t zsD) {
  src += (size_t)blockIdx.z * R * C;
  dst += (size_t)blockIdx.z * zsD;
  __shared__ float t[32][33];
  int c0 = blockIdx.x * 32, r0 = blockIdx.y * 32;
  int tx = threadIdx.x & 31, ty = threadIdx.x >> 5;
#pragma unroll
  for (int i = 0; i < 32; i += 8) t[ty + i][tx] = src[(size_t)(r0 + ty + i) * C + c0 + tx];
  __syncthreads();
#pragma unroll
  for (int i = 0; i < 32; i += 8)
    dst[(size_t)(c0 + ty + i) * R + r0 + tx] = f2bf(t[tx][ty + i]);
}

// w1 (512 x 4096) -> w1t (4096 x 512), GEGLU interleave for the 256-tile GEMM:
// dst row c: src col (c>>8)*128 + ((c>>6)&3)*32 + (c&31) + (c&32 ? 2048 : 0)
__global__ __launch_bounds__(256) void transpose_w1(const float* __restrict__ src,
                                                    u16* __restrict__ dst) {
  src += (size_t)blockIdx.z * 512 * 4096;
  dst += (size_t)blockIdx.z * 512 * 4096;
  __shared__ float t[32][33];
  int c0 = blockIdx.x * 32, r0 = blockIdx.y * 32;
  int m0 = (c0 >> 8) * 128 + ((c0 >> 6) & 3) * 32 + ((c0 & 32) ? 2048 : 0);
  int tx = threadIdx.x & 31, ty = threadIdx.x >> 5;
#pragma unroll
  for (int i = 0; i < 32; i += 8) t[ty + i][tx] = src[(size_t)(r0 + ty + i) * 4096 + m0 + tx];
  __syncthreads();
#pragma unroll
  for (int i = 0; i < 32; i += 8)
    dst[(size_t)(c0 + ty + i) * 512 + r0 + tx] = f2bf(t[tx][ty + i]);
}

// ---------------------------------------------------------------------------
__global__ void rope_init(float* cosT, float* sinT) {
  int idx = blockIdx.x * 256 + threadIdx.x;
  if (idx < 128 * 16) {
    int t = idx >> 4, j = idx & 15;
    float inv = __expf(-logf(10000.f) * (float)j / 16.f);
    float a = (float)t * inv;
    cosT[idx] = cosf(a);
    sinT[idx] = sinf(a);
  }
}

// latents init: broadcast query_latents (32,512) over 1024 batches (float4)
__global__ __launch_bounds__(256) void init_lat(const float* __restrict__ ql,
                                                float* __restrict__ lat) {
  size_t i = (size_t)blockIdx.x * 256 + threadIdx.x;  // float4 index
  int r = (int)(i >> 7), cw = (int)(i & 127);
  int l = r & 31;
  ((float4*)lat)[i] = ((const float4*)ql)[l * 128 + cw];
}

// ---------------------------------------------------------------------------
// RMSNorm: one wave per row of 512; out bf16. RMAP=1 -> permuted source row.
// ---------------------------------------------------------------------------
template<int RMAP>
__global__ __launch_bounds__(256) void rms_rows(const float* __restrict__ src,
                                                const float* __restrict__ g,
                                                u16* __restrict__ out) {
  const int wid = threadIdx.x >> 6, lane = threadIdx.x & 63;
  const int row = (blockIdx.x << 2) + wid;
  const int srow = maprow<RMAP>(row);
  const float4* p = (const float4*)(src + (size_t)srow * 512);
  float4 v0 = p[lane * 2], v1 = p[lane * 2 + 1];
  float ss = v0.x * v0.x + v0.y * v0.y + v0.z * v0.z + v0.w * v0.w +
             v1.x * v1.x + v1.y * v1.y + v1.z * v1.z + v1.w * v1.w;
#pragma unroll
  for (int m = 1; m < 64; m <<= 1) ss += __shfl_xor(ss, m);
  const float rs = rsqrtf(ss * (1.f / 512.f) + 1e-6f);
  const float4* gp = (const float4*)g;
  float4 g0 = gp[lane * 2], g1 = gp[lane * 2 + 1];
  u16 rb[8];
  rb[0] = f2bf(v0.x * rs * g0.x); rb[1] = f2bf(v0.y * rs * g0.y);
  rb[2] = f2bf(v0.z * rs * g0.z); rb[3] = f2bf(v0.w * rs * g0.w);
  rb[4] = f2bf(v1.x * rs * g1.x); rb[5] = f2bf(v1.y * rs * g1.y);
  rb[6] = f2bf(v1.z * rs * g1.z); rb[7] = f2bf(v1.w * rs * g1.w);
  *(int4*)(out + (size_t)row * 512 + lane * 8) = *(int4*)rb;
}

// ---------------------------------------------------------------------------
// gemm256 (unchanged from R5, proven): 256x256 tile, BK=64, 8 waves, 4-phase
// pipelined K-loop, counted gate per K-tile, XOR-swizzled LDS, setprio.
// ---------------------------------------------------------------------------
template<int EPI, int RMAP, int AMAP>
__global__ __launch_bounds__(512, 2) void gemm256(const u16* __restrict__ A,
                                                  const u16* __restrict__ A2,
                                                  const u16* __restrict__ Bt,
                                                  u16* __restrict__ outH,
                                                  float* __restrict__ latF,
                                                  const float* __restrict__ bias,
                                                  int M, int N, int K, int nb) {
  __shared__ __align__(16) u16 Ab[2][256 * 64];
  __shared__ __align__(16) u16 Bb[2][256 * 64];
  const int tid = threadIdx.x;
  const int m0 = blockIdx.y << 8;
  const int n0 = blockIdx.x << 8;
  const int wid = tid >> 6, lane = tid & 63;
  const int wm = wid >> 2, wn = wid & 3;
  const int lr = lane & 15, lg = lane >> 4;
  const int rx = (lr & 7) << 3;  // read-side col XOR (elems)

  auto stageA = [&](int bf, int kt, int h) {
#pragma unroll
    for (int i = 0; i < 2; ++i) {
      const int e = (i * 512 + tid) * 8;
      const int r = e >> 6;
      const int cs = (e & 63) ^ ((r & 7) << 3);
      const u16* src;
      if constexpr (AMAP == 0) {
        src = A + (size_t)(m0 + h * 128 + r) * K + kt * 64 + cs;
      } else {
        const int R = m0 + h * 128 + r;
        const int n_ = R / 96;
        const int j = R - n_ * 96;
        src = (j < 64) ? A  + ((size_t)((nb + n_) * 64 + j)) * 512 + kt * 64 + cs
                       : A2 + ((size_t)((nb + n_) * 32 + (j - 64))) * 512 + kt * 64 + cs;
      }
      glds16(src, &Ab[bf][h * 8192 + e]);
    }
  };
  auto stageB = [&](int bf, int kt, int h) {
#pragma unroll
    for (int i = 0; i < 2; ++i) {
      const int e = (i * 512 + tid) * 8;
      const int r = e >> 6;
      const int cs = (e & 63) ^ ((r & 7) << 3);
      glds16(Bt + (size_t)(n0 + h * 128 + r) * K + kt * 64 + cs, &Bb[bf][h * 8192 + e]);
    }
  };

  f32x4 acc[8][4];
#pragma unroll
  for (int i = 0; i < 8; ++i)
#pragma unroll
    for (int j = 0; j < 4; ++j) acc[i][j] = (f32x4){0.f, 0.f, 0.f, 0.f};

  stageA(0, 0, 0); stageA(0, 0, 1);
  stageB(0, 0, 0); stageB(0, 0, 1);
  kt_gate();

  const int nkt = K >> 6;
  for (int kt = 0; kt < nkt; ++kt) {
    const int bf = kt & 1;
    const u16* Abase = &Ab[bf][0];
    const u16* Bbase = &Bb[bf][0];
    const bool pf = (kt + 1 < nkt);
    bf16x8 bfr[2][4];
#pragma unroll
    for (int p = 0; p < 4; ++p) {
      if (p == 0 && pf) { stageA(bf ^ 1, kt + 1, 0); stageA(bf ^ 1, kt + 1, 1); }
      if (p == 1 && pf) { stageB(bf ^ 1, kt + 1, 0); stageB(bf ^ 1, kt + 1, 1); }
      if (p == 0) {
#pragma unroll
        for (int ks = 0; ks < 2; ++ks)
#pragma unroll
          for (int in = 0; in < 4; ++in) {
            const int rw = wn * 64 + in * 16 + lr;
            bfr[ks][in] = *(const bf16x8*)&Bbase[rw * 64 + ((ks * 32 + lg * 8) ^ rx)];
          }
      }
      bf16x8 afr[2][2];
#pragma unroll
      for (int d = 0; d < 2; ++d)
#pragma unroll
        for (int ks = 0; ks < 2; ++ks) {
          const int rw = wm * 128 + (p * 2 + d) * 16 + lr;
          afr[d][ks] = *(const bf16x8*)&Abase[rw * 64 + ((ks * 32 + lg * 8) ^ rx)];
        }
      __builtin_amdgcn_s_setprio(1);
#pragma unroll
      for (int d = 0; d < 2; ++d)
#pragma unroll
        for (int in = 0; in < 4; ++in)
#pragma unroll
          for (int ks = 0; ks < 2; ++ks)
            acc[p * 2 + d][in] = __builtin_amdgcn_mfma_f32_16x16x32_bf16(
                afr[d][ks], bfr[ks][in], acc[p * 2 + d][in], 0, 0, 0);
      __builtin_amdgcn_s_setprio(0);
      if (p == 3) {
        kt_gate();
      } else {
        __builtin_amdgcn_s_barrier();
      }
    }
  }

  if constexpr (EPI == 3) {
    const int t128 = n0 >> 1;
#pragma unroll
    for (int im = 0; im < 8; ++im)
#pragma unroll
      for (int in = 0; in < 2; ++in)
#pragma unroll
        for (int j = 0; j < 4; ++j) {
          const int row = m0 + wm * 128 + im * 16 + lg * 4 + j;
          const int hcol = t128 + wn * 32 + in * 16 + lr;
          outH[(size_t)row * 2048 + hcol] = f2bf(acc[im][in][j] * gelu_t(acc[im][in + 2][j]));
        }
  } else if constexpr (EPI == 2) {
#pragma unroll
    for (int im = 0; im < 8; ++im)
#pragma unroll
      for (int in = 0; in < 4; ++in) {
        const int col = n0 + wn * 64 + in * 16 + lr;
#pragma unroll
        for (int j = 0; j < 4; ++j) {
          const int row = m0 + wm * 128 + im * 16 + lg * 4 + j;
          const size_t rr = (size_t)maprow<RMAP>(row) * 512 + col;
          latF[rr] += acc[im][in][j];
        }
      }
  } else {
    float bv4[4];
    if constexpr (EPI == 1) {
#pragma unroll
      for (int in = 0; in < 4; ++in)
        bv4[in] = (n0 < 512) ? bias[n0 + wn * 64 + in * 16 + lr] : 0.f;
    }
#pragma unroll
    for (int im = 0; im < 8; ++im)
#pragma unroll
      for (int in = 0; in < 4; ++in) {
        const int col = n0 + wn * 64 + in * 16 + lr;
#pragma unroll
        for (int j = 0; j < 4; ++j) {
          const int row = m0 + wm * 128 + im * 16 + lg * 4 + j;
          float v = acc[im][in][j];
          if constexpr (EPI == 1) v += bv4[in];
          outH[(size_t)row * N + col] = f2bf(v);
        }
      }
  }
}

// ---------------------------------------------------------------------------
// Cross-attention R6: block per (n_local,h), n = nb + n_local. Lq=32, Lk=96.
// Padded LDS (no conflicts), register softmax (wave-parallel), deferred norm.
// kv fused rows [1024]: k cols 0-511, v cols 512-1023. o aliases q (disjoint).
// LDS ~31.5 KiB -> 4 blocks/CU.
// ---------------------------------------------------------------------------
__global__ __launch_bounds__(256) void attn_ca(const u16* q,
                                               const u16* __restrict__ kv,
                                               u16* o, int nb) {
  union __align__(16) SM {
    struct { u16 Qs[32][72]; u16 Ks[96][72]; } qk;  // 18,432 B
    u16 Pb[32][104];                                 //  6,656 B
  };
  __shared__ SM sm;
  __shared__ __align__(16) u16 Vt[64][104];          // 13,312 B
  __shared__ float pmax[2][32];
  __shared__ float psum[2][32];
  const int nl = blockIdx.x, n = nb + nl, h = blockIdx.y, tid = threadIdx.x;

  {  // Q: 32x64
    int r = tid >> 3, c = (tid & 7) * 8;
    *(int4*)&sm.qk.Qs[r][c] = *(const int4*)&q[((size_t)n * 32 + r) * 512 + h * 64 + c];
  }
#pragma unroll
  for (int i = 0; i < 3; ++i) {  // K: 96x64
    int idx = i * 256 + tid;
    int r = idx >> 3, c = (idx & 7) * 8;
    *(int4*)&sm.qk.Ks[r][c] = *(const int4*)&kv[((size_t)nl * 96 + r) * 1024 + h * 64 + c];
  }
#pragma unroll
  for (int i = 0; i < 3; ++i) {  // V transposed: lane owns 8 channels at one t
    int idx = i * 256 + tid;     // 768 = 96 t x 8 d-groups
    int dg = idx / 96, t = idx - dg * 96;
    int4 pv = *(const int4*)&kv[((size_t)nl * 96 + t) * 1024 + 512 + h * 64 + dg * 8];
    const u16* pu = (const u16*)&pv;
#pragma unroll
    for (int e = 0; e < 8; ++e) Vt[dg * 8 + e][t] = pu[e];
  }
  __syncthreads();

  const int wid = tid >> 6, lane = tid & 63, lr = lane & 15, lg = lane >> 4;
  const int m0 = (wid & 1) * 16, wnq = wid >> 1, nbc = wnq * 48;

  // QK^T: wave -> 16 rows x 48 cols
  f32x4 sa[3];
#pragma unroll
  for (int f = 0; f < 3; ++f) sa[f] = (f32x4){0.f, 0.f, 0.f, 0.f};
#pragma unroll
  for (int ks = 0; ks < 2; ++ks) {
    bf16x8 a = *(const bf16x8*)&sm.qk.Qs[m0 + lr][ks * 32 + lg * 8];
#pragma unroll
    for (int f = 0; f < 3; ++f) {
      bf16x8 bb = *(const bf16x8*)&sm.qk.Ks[nbc + f * 16 + lr][ks * 32 + lg * 8];
      sa[f] = __builtin_amdgcn_mfma_f32_16x16x32_bf16(a, bb, sa[f], 0, 0, 0);
    }
  }

  // wave-parallel row max (this wave's 48 cols), exchange across col-halves
#pragma unroll
  for (int j = 0; j < 4; ++j) {
    float m = fmaxf(fmaxf(sa[0][j], sa[1][j]), sa[2][j]);
    m = fmaxf(m, __shfl_xor(m, 1));
    m = fmaxf(m, __shfl_xor(m, 2));
    m = fmaxf(m, __shfl_xor(m, 4));
    m = fmaxf(m, __shfl_xor(m, 8));
    if (lr == 0) pmax[wnq][m0 + lg * 4 + j] = m;
  }
  __syncthreads();
  // exp (unnormalized), partial sums, stage P (Pb overlays Qs/Ks -- all reads done)
#pragma unroll
  for (int j = 0; j < 4; ++j) {
    const int row = m0 + lg * 4 + j;
    const float m = fmaxf(pmax[0][row], pmax[1][row]);
    float s = 0.f;
#pragma unroll
    for (int f = 0; f < 3; ++f) {
      float p = __expf(0.125f * (sa[f][j] - m));
      sa[f][j] = p;
      s += p;
    }
    s += __shfl_xor(s, 1); s += __shfl_xor(s, 2); s += __shfl_xor(s, 4); s += __shfl_xor(s, 8);
    if (lr == 0) psum[wnq][row] = s;
  }
#pragma unroll
  for (int f = 0; f < 3; ++f)
#pragma unroll
    for (int j = 0; j < 4; ++j)
      sm.Pb[m0 + lg * 4 + j][nbc + f * 16 + lr] = f2bf(sa[f][j]);
  __syncthreads();

  // PV: wave -> 16 rows x 32 d-cols, K=96; divide by row sum at the end
  const int n0d = wnq * 32;
  f32x4 oa[2];
#pragma unroll
  for (int f = 0; f < 2; ++f) oa[f] = (f32x4){0.f, 0.f, 0.f, 0.f};
#pragma unroll
  for (int ks = 0; ks < 3; ++ks) {
    bf16x8 a = *(const bf16x8*)&sm.Pb[m0 + lr][ks * 32 + lg * 8];
#pragma unroll
    for (int f = 0; f < 2; ++f) {
      bf16x8 bb = *(const bf16x8*)&Vt[n0d + f * 16 + lr][ks * 32 + lg * 8];
      oa[f] = __builtin_amdgcn_mfma_f32_16x16x32_bf16(a, bb, oa[f], 0, 0, 0);
    }
  }
#pragma unroll
  for (int j = 0; j < 4; ++j) {
    const int row = m0 + lg * 4 + j;
    const float inv = 1.f / (psum[0][row] + psum[1][row]);
#pragma unroll
    for (int f = 0; f < 2; ++f)
      o[((size_t)n * 32 + row) * 512 + h * 64 + n0d + f * 16 + lr] = f2bf(oa[f][j] * inv);
  }
}

// ---------------------------------------------------------------------------
// Temporal attention R6 with RoPE: block per (n,h), n in [0,256). T=128.
// Padded LDS, register softmax, deferred norm, Pb overlays Qs/Ks.
// LDS ~55 KiB -> 2 blocks/CU.
// ---------------------------------------------------------------------------
__global__ __launch_bounds__(256) void attn_ta(const u16* q,
                                               const u16* __restrict__ kv,
                                               const float* __restrict__ cosT,
                                               const float* __restrict__ sinT,
                                               u16* o) {
  union __align__(16) SM {
    struct { u16 Qs[128][72]; u16 Ks[128][72]; } qk;  // 36,864 B
    u16 Pb[128][136];                                  // 34,816 B
  };
  __shared__ SM sm;
  __shared__ __align__(16) u16 Vt[64][136];            // 17,408 B
  __shared__ float pmax[2][128];
  __shared__ float psum[2][128];
  const int n = blockIdx.x, h = blockIdx.y, tid = threadIdx.x;

#pragma unroll
  for (int i = 0; i < 16; ++i) {  // Q,K + RoPE on first 32 dims
    int idx = i * 256 + tid;
    int t = idx >> 5, pr = idx & 31;
    uint32_t uq = *(const uint32_t*)&q[((size_t)n * 128 + t) * 512 + h * 64 + pr * 2];
    uint32_t uk = *(const uint32_t*)&kv[((size_t)n * 128 + t) * 1024 + h * 64 + pr * 2];
    float q1 = bf2f(uq & 0xffff), q2 = bf2f(uq >> 16);
    float k1 = bf2f(uk & 0xffff), k2 = bf2f(uk >> 16);
    if (pr < 16) {
      float c = cosT[t * 16 + pr], s = sinT[t * 16 + pr];
      float a;
      a = q1 * c - q2 * s; q2 = q1 * s + q2 * c; q1 = a;
      a = k1 * c - k2 * s; k2 = k1 * s + k2 * c; k1 = a;
    }
    sm.qk.Qs[t][pr * 2] = f2bf(q1); sm.qk.Qs[t][pr * 2 + 1] = f2bf(q2);
    sm.qk.Ks[t][pr * 2] = f2bf(k1); sm.qk.Ks[t][pr * 2 + 1] = f2bf(k2);
  }
#pragma unroll
  for (int i = 0; i < 4; ++i) {  // V transposed: lane owns 8 channels at one t
    int idx = i * 256 + tid;     // 1024 = 128 t x 8 d-groups
    int t = idx & 127, d0 = (idx >> 7) * 8;
    int4 pv = *(const int4*)&kv[((size_t)n * 128 + t) * 1024 + 512 + h * 64 + d0];
    const u16* pu = (const u16*)&pv;
#pragma unroll
    for (int e = 0; e < 8; ++e) Vt[d0 + e][t] = pu[e];
  }
  __syncthreads();

  const int wid = tid >> 6, lane = tid & 63, lr = lane & 15, lg = lane >> 4;
  const int wm = wid >> 1, wn = wid & 1;
  const int rbase = wm * 64;

  // QK^T 128x128: wave -> 64 rows x 64 cols, all in registers
  f32x4 sa[4][4];
#pragma unroll
  for (int i = 0; i < 4; ++i)
#pragma unroll
    for (int j = 0; j < 4; ++j) sa[i][j] = (f32x4){0.f, 0.f, 0.f, 0.f};
#pragma unroll
  for (int ks = 0; ks < 2; ++ks) {
    bf16x8 av[4], bv[4];
#pragma unroll
    for (int im = 0; im < 4; ++im)
      av[im] = *(const bf16x8*)&sm.qk.Qs[rbase + im * 16 + lr][ks * 32 + lg * 8];
#pragma unroll
    for (int in = 0; in < 4; ++in)
      bv[in] = *(const bf16x8*)&sm.qk.Ks[wn * 64 + in * 16 + lr][ks * 32 + lg * 8];
#pragma unroll
    for (int im = 0; im < 4; ++im)
#pragma unroll
      for (int in = 0; in < 4; ++in)
        sa[im][in] = __builtin_amdgcn_mfma_f32_16x16x32_bf16(av[im], bv[in], sa[im][in], 0, 0, 0);
  }

  // wave-parallel row max over this wave's 64 cols; cross col-half via LDS
#pragma unroll
  for (int im = 0; im < 4; ++im)
#pragma unroll
    for (int j = 0; j < 4; ++j) {
      float m = fmaxf(fmaxf(sa[im][0][j], sa[im][1][j]), fmaxf(sa[im][2][j], sa[im][3][j]));
      m = fmaxf(m, __shfl_xor(m, 1));
      m = fmaxf(m, __shfl_xor(m, 2));
      m = fmaxf(m, __shfl_xor(m, 4));
      m = fmaxf(m, __shfl_xor(m, 8));
      if (lr == 0) pmax[wn][rbase + im * 16 + lg * 4 + j] = m;
    }
  __syncthreads();
  // exp (unnormalized) + partial sums + stage P (Pb overlays Qs/Ks)
#pragma unroll
  for (int im = 0; im < 4; ++im)
#pragma unroll
    for (int j = 0; j < 4; ++j) {
      const int row = rbase + im * 16 + lg * 4 + j;
      const float m = fmaxf(pmax[0][row], pmax[1][row]);
      float s = 0.f;
#pragma unroll
      for (int in = 0; in < 4; ++in) {
        float p = __expf(0.125f * (sa[im][in][j] - m));
        sa[im][in][j] = p;
        s += p;
      }
      s += __shfl_xor(s, 1); s += __shfl_xor(s, 2); s += __shfl_xor(s, 4); s += __shfl_xor(s, 8);
      if (lr == 0) psum[wn][row] = s;
    }
#pragma unroll
  for (int im = 0; im < 4; ++im)
#pragma unroll
    for (int in = 0; in < 4; ++in)
#pragma unroll
      for (int j = 0; j < 4; ++j)
        sm.Pb[rbase + im * 16 + lg * 4 + j][wn * 64 + in * 16 + lr] = f2bf(sa[im][in][j]);
  __syncthreads();

  // PV: wave -> 32 rows x 64 d, K=128; divide by row sum at the end
  f32x4 oa[2][4];
#pragma unroll
  for (int i = 0; i < 2; ++i)
#pragma unroll
    for (int j = 0; j < 4; ++j) oa[i][j] = (f32x4){0.f, 0.f, 0.f, 0.f};
#pragma unroll
  for (int ks = 0; ks < 4; ++ks) {
    bf16x8 av[2], bv[4];
#pragma unroll
    for (int im = 0; im < 2; ++im)
      av[im] = *(const bf16x8*)&sm.Pb[wid * 32 + im * 16 + lr][ks * 32 + lg * 8];
#pragma unroll
    for (int in = 0; in < 4; ++in)
      bv[in] = *(const bf16x8*)&Vt[in * 16 + lr][ks * 32 + lg * 8];
#pragma unroll
    for (int im = 0; im < 2; ++im)
#pragma unroll
      for (int in = 0; in < 4; ++in)
        oa[im][in] = __builtin_amdgcn_mfma_f32_16x16x32_bf16(av[im], bv[in], oa[im][in], 0, 0, 0);
  }
#pragma unroll
  for (int im = 0; im < 2; ++im)
#pragma unroll
    for (int j = 0; j < 4; ++j) {
      const int qi = wid * 32 + im * 16 + lg * 4 + j;
      const float inv = 1.f / (psum[0][qi] + psum[1][qi]);
#pragma unroll
      for (int in = 0; in < 4; ++in)
        o[((size_t)n * 128 + qi) * 512 + h * 64 + in * 16 + lr] = f2bf(oa[im][in][j] * inv);
    }
}

// ---------------------------------------------------------------------------
extern "C" void kernel_launch(void* const* d_in, const int* in_sizes, int n_in,
                              void* d_out, int out_size, void* d_ws, size_t ws_size,
                              hipStream_t stream) {
  const float* source = (const float*)d_in[0];
  const float* qlat   = (const float*)d_in[1];
  const float* ca_ln  = (const float*)d_in[2];
  const float* ca_wq  = (const float*)d_in[3];
  const float* ca_wk  = (const float*)d_in[4];
  const float* ca_bk  = (const float*)d_in[5];
  const float* ca_wv  = (const float*)d_in[6];
  const float* ca_wo  = (const float*)d_in[7];
  const float* ca_w1  = (const float*)d_in[8];
  const float* ca_w2  = (const float*)d_in[9];
  const float* ta_ln  = (const float*)d_in[10];
  const float* ta_wq  = (const float*)d_in[11];
  const float* ta_wk  = (const float*)d_in[12];
  const float* ta_bk  = (const float*)d_in[13];
  const float* ta_wv  = (const float*)d_in[14];
  const float* ta_wo  = (const float*)d_in[15];
  const float* ta_w1  = (const float*)d_in[16];
  const float* ta_w2  = (const float*)d_in[17];
  float* lat = (float*)d_out;  // residual stream lives in d_out
  char* ws = (char*)d_ws;
  (void)in_sizes; (void)n_in; (void)out_size;

  if (ws_size < 251674624ull) return;  // known-good guard from R2

  const size_t WQ = 512 * 512, W1SZ = (size_t)512 * 4096, W2SZ = (size_t)2048 * 512;
  const size_t O_CA_WQ = 0,
               O_CA_KV = 4 * WQ,
               O_CA_WO = 12 * WQ,
               O_CA_W1 = 16 * WQ,
               O_CA_W2 = O_CA_W1 + 4 * W1SZ,
               O_TA_WQ = O_CA_W2 + 4 * W2SZ,
               O_TA_KV = O_TA_WQ + 4 * WQ,
               O_TA_WO = O_TA_KV + 8 * WQ,
               O_TA_W1 = O_TA_WO + 4 * WQ,
               O_TA_W2 = O_TA_W1 + 4 * W1SZ;  // ends at 128*WQ = 67,108,864 B

  u16*   W    = (u16*)ws;                    // [0, 67,108,864)  weights (exact)
  u16*   xn   = (u16*)(ws + 67108864);       // 32 MiB
  u16*   shat = (u16*)(ws + 100663296);      // 64 MiB (CA s_n; TA fused KV; h2 head)
  u16*   qb   = (u16*)(ws + 167772160);      // 32 MiB (q / attn out)
  u16*   kvb  = (u16*)(ws + 201326592);      // 48 MiB (CA fused K|V chunk)
  u16*   h2   = shat;                        // MLP hidden 128 MiB
  u16*   takv = shat;                        // TA fused KV 64 MiB
  float* cosT = (float*)(ws + 251658240);    // 8 KiB  (tail gap, within guard)
  float* sinT = (float*)(ws + 251666432);    // 8 KiB

  transpose_cast<<<dim3(16, 16, 4), 256, 0, stream>>>(ca_wq, W + O_CA_WQ, 512, 512, WQ);
  transpose_cast<<<dim3(16, 16, 4), 256, 0, stream>>>(ca_wk, W + O_CA_KV, 512, 512, 2 * WQ);
  transpose_cast<<<dim3(16, 16, 4), 256, 0, stream>>>(ca_wv, W + O_CA_KV + WQ, 512, 512, 2 * WQ);
  transpose_cast<<<dim3(16, 16, 4), 256, 0, stream>>>(ca_wo, W + O_CA_WO, 512, 512, WQ);
  transpose_w1 <<<dim3(128, 16, 4), 256, 0, stream>>>(ca_w1, W + O_CA_W1);
  transpose_cast<<<dim3(16, 64, 4), 256, 0, stream>>>(ca_w2, W + O_CA_W2, 2048, 512, W2SZ);
  transpose_cast<<<dim3(16, 16, 4), 256, 0, stream>>>(ta_wq, W + O_TA_WQ, 512, 512, WQ);
  transpose_cast<<<dim3(16, 16, 4), 256, 0, stream>>>(ta_wk, W + O_TA_KV, 512, 512, 2 * WQ);
  transpose_cast<<<dim3(16, 16, 4), 256, 0, stream>>>(ta_wv, W + O_TA_KV + WQ, 512, 512, 2 * WQ);
  transpose_cast<<<dim3(16, 16, 4), 256, 0, stream>>>(ta_wo, W + O_TA_WO, 512, 512, WQ);
  transpose_w1 <<<dim3(128, 16, 4), 256, 0, stream>>>(ta_w1, W + O_TA_W1);
  transpose_cast<<<dim3(16, 64, 4), 256, 0, stream>>>(ta_w2, W + O_TA_W2, 2048, 512, W2SZ);
  rope_init<<<8, 256, 0, stream>>>(cosT, sinT);
  init_lat<<<16384, 256, 0, stream>>>(qlat, lat);

  for (int b = 0; b < 4; ++b) {
    const u16* wqt   = W + O_CA_WQ + (size_t)b * WQ;
    const u16* wkvt  = W + O_CA_KV + (size_t)b * 2 * WQ;
    const u16* wot   = W + O_CA_WO + (size_t)b * WQ;
    const u16* w1t   = W + O_CA_W1 + (size_t)b * W1SZ;
    const u16* w2t   = W + O_CA_W2 + (size_t)b * W2SZ;
    const u16* twqt  = W + O_TA_WQ + (size_t)b * WQ;
    const u16* twkvt = W + O_TA_KV + (size_t)b * 2 * WQ;
    const u16* twot  = W + O_TA_WO + (size_t)b * WQ;
    const u16* tw1t  = W + O_TA_W1 + (size_t)b * W1SZ;
    const u16* tw2t  = W + O_TA_W2 + (size_t)b * W2SZ;

    // ---- cross attention ----
    rms_rows<0><<<8192, 256, 0, stream>>>(lat, ca_ln + b * 1536, xn);              // l_n
    rms_rows<0><<<16384, 256, 0, stream>>>(source, ca_ln + b * 1536 + 512, shat);  // s_n
    gemm256<0, 0, 0><<<dim3(2, 128), 512, 0, stream>>>(xn, nullptr, wqt, qb, nullptr, nullptr, 32768, 512, 512, 0);
    for (int c = 0; c < 4; ++c) {  // fused K|V + attention per 256-batch chunk
      gemm256<1, 0, 1><<<dim3(4, 96), 512, 0, stream>>>(shat, xn, wkvt, kvb, nullptr, ca_bk + b * 512, 24576, 1024, 512, c * 256);
      attn_ca<<<dim3(256, 8), 256, 0, stream>>>(qb, kvb, qb, c * 256);
    }
    gemm256<2, 0, 0><<<dim3(2, 128), 512, 0, stream>>>(qb, nullptr, wot, nullptr, lat, nullptr, 32768, 512, 512, 0);
    rms_rows<0><<<8192, 256, 0, stream>>>(lat, ca_ln + b * 1536 + 1024, xn);
    gemm256<3, 0, 0><<<dim3(16, 128), 512, 0, stream>>>(xn, nullptr, w1t, h2, nullptr, nullptr, 32768, 4096, 512, 0);
    gemm256<2, 0, 0><<<dim3(2, 128), 512, 0, stream>>>(h2, nullptr, w2t, nullptr, lat, nullptr, 32768, 512, 2048, 0);

    // ---- temporal attention ----
    rms_rows<1><<<8192, 256, 0, stream>>>(lat, ta_ln + b * 1024, xn);
    gemm256<0, 0, 0><<<dim3(2, 128), 512, 0, stream>>>(xn, nullptr, twqt, qb, nullptr, nullptr, 32768, 512, 512, 0);
    gemm256<1, 0, 0><<<dim3(4, 128), 512, 0, stream>>>(xn, nullptr, twkvt, takv, nullptr, ta_bk + b * 512, 32768, 1024, 512, 0);
    attn_ta<<<dim3(256, 8), 256, 0, stream>>>(qb, takv, cosT, sinT, qb);
    gemm256<2, 1, 0><<<dim3(2, 128), 512, 0, stream>>>(qb, nullptr, twot, nullptr, lat, nullptr, 32768, 512, 512, 0);
    rms_rows<1><<<8192, 256, 0, stream>>>(lat, ta_ln + b * 1024 + 512, xn);
    gemm256<3, 0, 0><<<dim3(16, 128), 512, 0, stream>>>(xn, nullptr, tw1t, h2, nullptr, nullptr, 32768, 4096, 512, 0);
    gemm256<2, 1, 0><<<dim3(2, 128), 512, 0, stream>>>(h2, nullptr, tw2t, nullptr, lat, nullptr, 32768, 512, 2048, 0);
  }
}

// Round 7
// 5045.011 us; speedup vs baseline: 1.2695x; 1.0531x over previous
//
#include <hip/hip_runtime.h>
#include <stdint.h>

// ---------------------------------------------------------------------------
// SpatioTemporalPerceiverResampler  (D=512, H=8, DH=64, NB=4, DMLP=2048,
// L=32, T=128, B=8, BT=1024, ROPE_DIM=32)
// R7: gemm256 -> true counted-vmcnt pipeline: A triple-buffered (staged 2
// tiles ahead), B double-buffered (staged 1 tile ahead), gate = vmcnt(4) not
// vmcnt(0); + XCD-aware block swizzle (T1). LDS = 160 KiB exactly.
// Attention (R6 register-softmax) and everything else unchanged.
// ---------------------------------------------------------------------------

typedef short    bf16x8 __attribute__((ext_vector_type(8)));
typedef float    f32x4  __attribute__((ext_vector_type(4)));
typedef uint16_t u16;

__device__ __forceinline__ float bf2f(uint32_t u) {
  union { uint32_t i; float f; } x; x.i = u << 16; return x.f;
}
__device__ __forceinline__ u16 f2bf(float f) {
  union { float f; uint32_t i; } x; x.f = f;
  return (u16)((x.i + 0x7fffu + ((x.i >> 16) & 1u)) >> 16);  // RNE
}
__device__ __forceinline__ float gelu_t(float x) {  // jax.nn.gelu approximate=True
  float u = 0.7978845608028654f * (x + 0.044715f * x * x * x);
  float t = 1.f - 2.f / (__expf(2.f * u) + 1.f);
  return 0.5f * x * (1.f + t);
}
// r_x = (b*L + l)*T + t  ->  lat row (b*T + t)*L + l     (L=32, T=128)
template<int RMAP>
__device__ __forceinline__ int maprow(int r) {
  if (RMAP == 0) return r;
  int b = r >> 12, rem = r & 4095;
  return ((b << 7) + (rem & 127)) * 32 + (rem >> 7);
}
__device__ __forceinline__ void glds16(const u16* g, u16* l) {
  __builtin_amdgcn_global_load_lds((const __attribute__((address_space(1))) uint32_t*)(g),
                                   (__attribute__((address_space(3))) uint32_t*)(l),
                                   16, 0, 0);
}

// ---------------------------------------------------------------------------
// Weight cast+transpose: src fp32 [R][C] -> dst bf16 [C][R]; z strides:
// src by R*C, dst by zsD (allows interleaving wk/wv per block).
// ---------------------------------------------------------------------------
__global__ __launch_bounds__(256) void transpose_cast(const float* __restrict__ src,
                                                      u16* __restrict__ dst,
                                                      int R, int C, size_t zsD) {
  src += (size_t)blockIdx.z * R * C;
  dst += (size_t)blockIdx.z * zsD;
  __shared__ float t[32][33];
  int c0 = blockIdx.x * 32, r0 = blockIdx.y * 32;
  int tx = threadIdx.x & 31, ty = threadIdx.x >> 5;
#pragma unroll
  for (int i = 0; i < 32; i += 8) t[ty + i][tx] = src[(size_t)(r0 + ty + i) * C + c0 + tx];
  __syncthreads();
#pragma unroll
  for (int i = 0; i < 32; i += 8)
    dst[(size_t)(c0 + ty + i) * R + r0 + tx] = f2bf(t[tx][ty + i]);
}

// w1 (512 x 4096) -> w1t (4096 x 512), GEGLU interleave for the 256-tile GEMM:
// dst row c: src col (c>>8)*128 + ((c>>6)&3)*32 + (c&31) + (c&32 ? 2048 : 0)
__global__ __launch_bounds__(256) void transpose_w1(const float* __restrict__ src,
                                                    u16* __restrict__ dst) {
  src += (size_t)blockIdx.z * 512 * 4096;
  dst += (size_t)blockIdx.z * 512 * 4096;
  __shared__ float t[32][33];
  int c0 = blockIdx.x * 32, r0 = blockIdx.y * 32;
  int m0 = (c0 >> 8) * 128 + ((c0 >> 6) & 3) * 32 + ((c0 & 32) ? 2048 : 0);
  int tx = threadIdx.x & 31, ty = threadIdx.x >> 5;
#pragma unroll
  for (int i = 0; i < 32; i += 8) t[ty + i][tx] = src[(size_t)(r0 + ty + i) * 4096 + m0 + tx];
  __syncthreads();
#pragma unroll
  for (int i = 0; i < 32; i += 8)
    dst[(size_t)(c0 + ty + i) * 512 + r0 + tx] = f2bf(t[tx][ty + i]);
}

// ---------------------------------------------------------------------------
__global__ void rope_init(float* cosT, float* sinT) {
  int idx = blockIdx.x * 256 + threadIdx.x;
  if (idx < 128 * 16) {
    int t = idx >> 4, j = idx & 15;
    float inv = __expf(-logf(10000.f) * (float)j / 16.f);
    float a = (float)t * inv;
    cosT[idx] = cosf(a);
    sinT[idx] = sinf(a);
  }
}

// latents init: broadcast query_latents (32,512) over 1024 batches (float4)
__global__ __launch_bounds__(256) void init_lat(const float* __restrict__ ql,
                                                float* __restrict__ lat) {
  size_t i = (size_t)blockIdx.x * 256 + threadIdx.x;  // float4 index
  int r = (int)(i >> 7), cw = (int)(i & 127);
  int l = r & 31;
  ((float4*)lat)[i] = ((const float4*)ql)[l * 128 + cw];
}

// ---------------------------------------------------------------------------
// RMSNorm: one wave per row of 512; out bf16. RMAP=1 -> permuted source row.
// ---------------------------------------------------------------------------
template<int RMAP>
__global__ __launch_bounds__(256) void rms_rows(const float* __restrict__ src,
                                                const float* __restrict__ g,
                                                u16* __restrict__ out) {
  const int wid = threadIdx.x >> 6, lane = threadIdx.x & 63;
  const int row = (blockIdx.x << 2) + wid;
  const int srow = maprow<RMAP>(row);
  const float4* p = (const float4*)(src + (size_t)srow * 512);
  float4 v0 = p[lane * 2], v1 = p[lane * 2 + 1];
  float ss = v0.x * v0.x + v0.y * v0.y + v0.z * v0.z + v0.w * v0.w +
             v1.x * v1.x + v1.y * v1.y + v1.z * v1.z + v1.w * v1.w;
#pragma unroll
  for (int m = 1; m < 64; m <<= 1) ss += __shfl_xor(ss, m);
  const float rs = rsqrtf(ss * (1.f / 512.f) + 1e-6f);
  const float4* gp = (const float4*)g;
  float4 g0 = gp[lane * 2], g1 = gp[lane * 2 + 1];
  u16 rb[8];
  rb[0] = f2bf(v0.x * rs * g0.x); rb[1] = f2bf(v0.y * rs * g0.y);
  rb[2] = f2bf(v0.z * rs * g0.z); rb[3] = f2bf(v0.w * rs * g0.w);
  rb[4] = f2bf(v1.x * rs * g1.x); rb[5] = f2bf(v1.y * rs * g1.y);
  rb[6] = f2bf(v1.z * rs * g1.z); rb[7] = f2bf(v1.w * rs * g1.w);
  *(int4*)(out + (size_t)row * 512 + lane * 8) = *(int4*)rb;
}

// ---------------------------------------------------------------------------
// gemm256 R7: 256x256 tile, BK=64, 8 waves (2M x 4N), per-wave C 128x64.
// A triple-buffered LDS (staged 2 K-tiles ahead), B double-buffered (staged
// 1 ahead). Per tile: 4 phases {p0: stageB(kt+1) + read B-frags + A-q0 + MFMA;
// p1: stageA(kt+2) + A-q1 + MFMA; p2/p3: A-q + MFMA}. Gate at p3 = vmcnt(4)
// (A(kt+2) loads stay in flight) + barrier. XOR-swizzled LDS, setprio, XCD
// block swizzle. LDS = 3*32K + 2*32K = 160 KiB exactly.
// ---------------------------------------------------------------------------
template<int EPI, int RMAP, int AMAP>
__global__ __launch_bounds__(512, 2) void gemm256(const u16* __restrict__ A,
                                                  const u16* __restrict__ A2,
                                                  const u16* __restrict__ Bt,
                                                  u16* __restrict__ outH,
                                                  float* __restrict__ latF,
                                                  const float* __restrict__ bias,
                                                  int M, int N, int K, int nb) {
  __shared__ __align__(16) u16 Ab[3][256 * 64];   // 96 KiB
  __shared__ __align__(16) u16 Bb[2][256 * 64];   // 64 KiB
  const int tid = threadIdx.x;
  // T1: XCD-aware block swizzle (all grids have nwg % 8 == 0 -> bijective)
  const int nwg = gridDim.x * gridDim.y;
  int bid = blockIdx.y * gridDim.x + blockIdx.x;
  bid = (bid & 7) * (nwg >> 3) + (bid >> 3);
  const int m0 = (bid / gridDim.x) << 8;
  const int n0 = (bid % gridDim.x) << 8;
  const int wid = tid >> 6, lane = tid & 63;
  const int wm = wid >> 2, wn = wid & 3;
  const int lr = lane & 15, lg = lane >> 4;
  const int rx = (lr & 7) << 3;  // read-side col XOR (elems)

  // stage a full 256x64 K-tile (4 x glds16/thread). LDS dest linear; source
  // col pre-swizzled (both-sides involution).
  auto stageA = [&](int slot, int kt) {
#pragma unroll
    for (int i = 0; i < 4; ++i) {
      const int e = (i * 512 + tid) * 8;
      const int r = e >> 6;
      const int cs = (e & 63) ^ ((r & 7) << 3);
      const u16* src;
      if constexpr (AMAP == 0) {
        src = A + (size_t)(m0 + r) * K + kt * 64 + cs;
      } else {
        const int R = m0 + r;
        const int n_ = R / 96;
        const int j = R - n_ * 96;
        src = (j < 64) ? A  + ((size_t)((nb + n_) * 64 + j)) * 512 + kt * 64 + cs
                       : A2 + ((size_t)((nb + n_) * 32 + (j - 64))) * 512 + kt * 64 + cs;
      }
      glds16(src, &Ab[slot][e]);
    }
  };
  auto stageB = [&](int slot, int kt) {
#pragma unroll
    for (int i = 0; i < 4; ++i) {
      const int e = (i * 512 + tid) * 8;
      const int r = e >> 6;
      const int cs = (e & 63) ^ ((r & 7) << 3);
      glds16(Bt + (size_t)(n0 + r) * K + kt * 64 + cs, &Bb[slot][e]);
    }
  };

  f32x4 acc[8][4];
#pragma unroll
  for (int i = 0; i < 8; ++i)
#pragma unroll
    for (int j = 0; j < 4; ++j) acc[i][j] = (f32x4){0.f, 0.f, 0.f, 0.f};

  // prologue: A0, B0, A1 issued (12 loads); wait A0+B0 (A1 stays in flight).
  stageA(0, 0);
  stageB(0, 0);
  stageA(1, 1);
  asm volatile("s_waitcnt vmcnt(4)" ::: "memory");
  __builtin_amdgcn_s_barrier();
  asm volatile("" ::: "memory");

  const int nkt = K >> 6;
  int sl0 = 0;  // LDS A-slot of tile kt
  int sl2 = 2;  // LDS A-slot of tile kt+2
  for (int kt = 0; kt < nkt; ++kt) {
    const u16* Abase = &Ab[sl0][0];
    const u16* Bbase = &Bb[kt & 1][0];
    bf16x8 bfr[2][4];
#pragma unroll
    for (int p = 0; p < 4; ++p) {
      if (p == 0 && kt + 1 < nkt) stageB((kt + 1) & 1, kt + 1);
      if (p == 1 && kt + 2 < nkt) stageA(sl2, kt + 2);
      if (p == 0) {
#pragma unroll
        for (int ks = 0; ks < 2; ++ks)
#pragma unroll
          for (int in = 0; in < 4; ++in) {
            const int rw = wn * 64 + in * 16 + lr;
            bfr[ks][in] = *(const bf16x8*)&Bbase[rw * 64 + ((ks * 32 + lg * 8) ^ rx)];
          }
      }
      bf16x8 afr[2][2];
#pragma unroll
      for (int d = 0; d < 2; ++d)
#pragma unroll
        for (int ks = 0; ks < 2; ++ks) {
          const int rw = wm * 128 + (p * 2 + d) * 16 + lr;
          afr[d][ks] = *(const bf16x8*)&Abase[rw * 64 + ((ks * 32 + lg * 8) ^ rx)];
        }
      __builtin_amdgcn_s_setprio(1);
#pragma unroll
      for (int d = 0; d < 2; ++d)
#pragma unroll
        for (int in = 0; in < 4; ++in)
#pragma unroll
          for (int ks = 0; ks < 2; ++ks)
            acc[p * 2 + d][in] = __builtin_amdgcn_mfma_f32_16x16x32_bf16(
                afr[d][ks], bfr[ks][in], acc[p * 2 + d][in], 0, 0, 0);
      __builtin_amdgcn_s_setprio(0);
      if (p == 3) {
        if (kt + 1 < nkt) {  // gate into tile kt+1 (counted: A(kt+2) in flight)
          if (kt + 2 < nkt) asm volatile("s_waitcnt vmcnt(4)" ::: "memory");
          else              asm volatile("s_waitcnt vmcnt(0)" ::: "memory");
          __builtin_amdgcn_s_barrier();
          asm volatile("" ::: "memory");
        }
      } else {
        __builtin_amdgcn_s_barrier();
      }
    }
    sl0 = (sl0 == 2) ? 0 : sl0 + 1;
    sl2 = (sl2 == 2) ? 0 : sl2 + 1;
  }

  // ---- epilogues (direct stores) ----
  if constexpr (EPI == 3) {
    const int t128 = n0 >> 1;
#pragma unroll
    for (int im = 0; im < 8; ++im)
#pragma unroll
      for (int in = 0; in < 2; ++in)
#pragma unroll
        for (int j = 0; j < 4; ++j) {
          const int row = m0 + wm * 128 + im * 16 + lg * 4 + j;
          const int hcol = t128 + wn * 32 + in * 16 + lr;
          outH[(size_t)row * 2048 + hcol] = f2bf(acc[im][in][j] * gelu_t(acc[im][in + 2][j]));
        }
  } else if constexpr (EPI == 2) {
#pragma unroll
    for (int im = 0; im < 8; ++im)
#pragma unroll
      for (int in = 0; in < 4; ++in) {
        const int col = n0 + wn * 64 + in * 16 + lr;
#pragma unroll
        for (int j = 0; j < 4; ++j) {
          const int row = m0 + wm * 128 + im * 16 + lg * 4 + j;
          const size_t rr = (size_t)maprow<RMAP>(row) * 512 + col;
          latF[rr] += acc[im][in][j];
        }
      }
  } else {
    float bv4[4];
    if constexpr (EPI == 1) {
#pragma unroll
      for (int in = 0; in < 4; ++in)
        bv4[in] = (n0 < 512) ? bias[n0 + wn * 64 + in * 16 + lr] : 0.f;
    }
#pragma unroll
    for (int im = 0; im < 8; ++im)
#pragma unroll
      for (int in = 0; in < 4; ++in) {
        const int col = n0 + wn * 64 + in * 16 + lr;
#pragma unroll
        for (int j = 0; j < 4; ++j) {
          const int row = m0 + wm * 128 + im * 16 + lg * 4 + j;
          float v = acc[im][in][j];
          if constexpr (EPI == 1) v += bv4[in];
          outH[(size_t)row * N + col] = f2bf(v);
        }
      }
  }
}

// ---------------------------------------------------------------------------
// Cross-attention R6: block per (n_local,h), n = nb + n_local. Lq=32, Lk=96.
// Padded LDS (no conflicts), register softmax (wave-parallel), deferred norm.
// ---------------------------------------------------------------------------
__global__ __launch_bounds__(256) void attn_ca(const u16* q,
                                               const u16* __restrict__ kv,
                                               u16* o, int nb) {
  union __align__(16) SM {
    struct { u16 Qs[32][72]; u16 Ks[96][72]; } qk;
    u16 Pb[32][104];
  };
  __shared__ SM sm;
  __shared__ __align__(16) u16 Vt[64][104];
  __shared__ float pmax[2][32];
  __shared__ float psum[2][32];
  const int nl = blockIdx.x, n = nb + nl, h = blockIdx.y, tid = threadIdx.x;

  {
    int r = tid >> 3, c = (tid & 7) * 8;
    *(int4*)&sm.qk.Qs[r][c] = *(const int4*)&q[((size_t)n * 32 + r) * 512 + h * 64 + c];
  }
#pragma unroll
  for (int i = 0; i < 3; ++i) {
    int idx = i * 256 + tid;
    int r = idx >> 3, c = (idx & 7) * 8;
    *(int4*)&sm.qk.Ks[r][c] = *(const int4*)&kv[((size_t)nl * 96 + r) * 1024 + h * 64 + c];
  }
#pragma unroll
  for (int i = 0; i < 3; ++i) {
    int idx = i * 256 + tid;
    int dg = idx / 96, t = idx - dg * 96;
    int4 pv = *(const int4*)&kv[((size_t)nl * 96 + t) * 1024 + 512 + h * 64 + dg * 8];
    const u16* pu = (const u16*)&pv;
#pragma unroll
    for (int e = 0; e < 8; ++e) Vt[dg * 8 + e][t] = pu[e];
  }
  __syncthreads();

  const int wid = tid >> 6, lane = tid & 63, lr = lane & 15, lg = lane >> 4;
  const int m0 = (wid & 1) * 16, wnq = wid >> 1, nbc = wnq * 48;

  f32x4 sa[3];
#pragma unroll
  for (int f = 0; f < 3; ++f) sa[f] = (f32x4){0.f, 0.f, 0.f, 0.f};
#pragma unroll
  for (int ks = 0; ks < 2; ++ks) {
    bf16x8 a = *(const bf16x8*)&sm.qk.Qs[m0 + lr][ks * 32 + lg * 8];
#pragma unroll
    for (int f = 0; f < 3; ++f) {
      bf16x8 bb = *(const bf16x8*)&sm.qk.Ks[nbc + f * 16 + lr][ks * 32 + lg * 8];
      sa[f] = __builtin_amdgcn_mfma_f32_16x16x32_bf16(a, bb, sa[f], 0, 0, 0);
    }
  }

#pragma unroll
  for (int j = 0; j < 4; ++j) {
    float m = fmaxf(fmaxf(sa[0][j], sa[1][j]), sa[2][j]);
    m = fmaxf(m, __shfl_xor(m, 1));
    m = fmaxf(m, __shfl_xor(m, 2));
    m = fmaxf(m, __shfl_xor(m, 4));
    m = fmaxf(m, __shfl_xor(m, 8));
    if (lr == 0) pmax[wnq][m0 + lg * 4 + j] = m;
  }
  __syncthreads();
#pragma unroll
  for (int j = 0; j < 4; ++j) {
    const int row = m0 + lg * 4 + j;
    const float m = fmaxf(pmax[0][row], pmax[1][row]);
    float s = 0.f;
#pragma unroll
    for (int f = 0; f < 3; ++f) {
      float p = __expf(0.125f * (sa[f][j] - m));
      sa[f][j] = p;
      s += p;
    }
    s += __shfl_xor(s, 1); s += __shfl_xor(s, 2); s += __shfl_xor(s, 4); s += __shfl_xor(s, 8);
    if (lr == 0) psum[wnq][row] = s;
  }
#pragma unroll
  for (int f = 0; f < 3; ++f)
#pragma unroll
    for (int j = 0; j < 4; ++j)
      sm.Pb[m0 + lg * 4 + j][nbc + f * 16 + lr] = f2bf(sa[f][j]);
  __syncthreads();

  const int n0d = wnq * 32;
  f32x4 oa[2];
#pragma unroll
  for (int f = 0; f < 2; ++f) oa[f] = (f32x4){0.f, 0.f, 0.f, 0.f};
#pragma unroll
  for (int ks = 0; ks < 3; ++ks) {
    bf16x8 a = *(const bf16x8*)&sm.Pb[m0 + lr][ks * 32 + lg * 8];
#pragma unroll
    for (int f = 0; f < 2; ++f) {
      bf16x8 bb = *(const bf16x8*)&Vt[n0d + f * 16 + lr][ks * 32 + lg * 8];
      oa[f] = __builtin_amdgcn_mfma_f32_16x16x32_bf16(a, bb, oa[f], 0, 0, 0);
    }
  }
#pragma unroll
  for (int j = 0; j < 4; ++j) {
    const int row = m0 + lg * 4 + j;
    const float inv = 1.f / (psum[0][row] + psum[1][row]);
#pragma unroll
    for (int f = 0; f < 2; ++f)
      o[((size_t)n * 32 + row) * 512 + h * 64 + n0d + f * 16 + lr] = f2bf(oa[f][j] * inv);
  }
}

// ---------------------------------------------------------------------------
// Temporal attention R6 with RoPE: block per (n,h), n in [0,256). T=128.
// ---------------------------------------------------------------------------
__global__ __launch_bounds__(256) void attn_ta(const u16* q,
                                               const u16* __restrict__ kv,
                                               const float* __restrict__ cosT,
                                               const float* __restrict__ sinT,
                                               u16* o) {
  union __align__(16) SM {
    struct { u16 Qs[128][72]; u16 Ks[128][72]; } qk;
    u16 Pb[128][136];
  };
  __shared__ SM sm;
  __shared__ __align__(16) u16 Vt[64][136];
  __shared__ float pmax[2][128];
  __shared__ float psum[2][128];
  const int n = blockIdx.x, h = blockIdx.y, tid = threadIdx.x;

#pragma unroll
  for (int i = 0; i < 16; ++i) {
    int idx = i * 256 + tid;
    int t = idx >> 5, pr = idx & 31;
    uint32_t uq = *(const uint32_t*)&q[((size_t)n * 128 + t) * 512 + h * 64 + pr * 2];
    uint32_t uk = *(const uint32_t*)&kv[((size_t)n * 128 + t) * 1024 + h * 64 + pr * 2];
    float q1 = bf2f(uq & 0xffff), q2 = bf2f(uq >> 16);
    float k1 = bf2f(uk & 0xffff), k2 = bf2f(uk >> 16);
    if (pr < 16) {
      float c = cosT[t * 16 + pr], s = sinT[t * 16 + pr];
      float a;
      a = q1 * c - q2 * s; q2 = q1 * s + q2 * c; q1 = a;
      a = k1 * c - k2 * s; k2 = k1 * s + k2 * c; k1 = a;
    }
    sm.qk.Qs[t][pr * 2] = f2bf(q1); sm.qk.Qs[t][pr * 2 + 1] = f2bf(q2);
    sm.qk.Ks[t][pr * 2] = f2bf(k1); sm.qk.Ks[t][pr * 2 + 1] = f2bf(k2);
  }
#pragma unroll
  for (int i = 0; i < 4; ++i) {
    int idx = i * 256 + tid;
    int t = idx & 127, d0 = (idx >> 7) * 8;
    int4 pv = *(const int4*)&kv[((size_t)n * 128 + t) * 1024 + 512 + h * 64 + d0];
    const u16* pu = (const u16*)&pv;
#pragma unroll
    for (int e = 0; e < 8; ++e) Vt[d0 + e][t] = pu[e];
  }
  __syncthreads();

  const int wid = tid >> 6, lane = tid & 63, lr = lane & 15, lg = lane >> 4;
  const int wm = wid >> 1, wn = wid & 1;
  const int rbase = wm * 64;

  f32x4 sa[4][4];
#pragma unroll
  for (int i = 0; i < 4; ++i)
#pragma unroll
    for (int j = 0; j < 4; ++j) sa[i][j] = (f32x4){0.f, 0.f, 0.f, 0.f};
#pragma unroll
  for (int ks = 0; ks < 2; ++ks) {
    bf16x8 av[4], bv[4];
#pragma unroll
    for (int im = 0; im < 4; ++im)
      av[im] = *(const bf16x8*)&sm.qk.Qs[rbase + im * 16 + lr][ks * 32 + lg * 8];
#pragma unroll
    for (int in = 0; in < 4; ++in)
      bv[in] = *(const bf16x8*)&sm.qk.Ks[wn * 64 + in * 16 + lr][ks * 32 + lg * 8];
#pragma unroll
    for (int im = 0; im < 4; ++im)
#pragma unroll
      for (int in = 0; in < 4; ++in)
        sa[im][in] = __builtin_amdgcn_mfma_f32_16x16x32_bf16(av[im], bv[in], sa[im][in], 0, 0, 0);
  }

#pragma unroll
  for (int im = 0; im < 4; ++im)
#pragma unroll
    for (int j = 0; j < 4; ++j) {
      float m = fmaxf(fmaxf(sa[im][0][j], sa[im][1][j]), fmaxf(sa[im][2][j], sa[im][3][j]));
      m = fmaxf(m, __shfl_xor(m, 1));
      m = fmaxf(m, __shfl_xor(m, 2));
      m = fmaxf(m, __shfl_xor(m, 4));
      m = fmaxf(m, __shfl_xor(m, 8));
      if (lr == 0) pmax[wn][rbase + im * 16 + lg * 4 + j] = m;
    }
  __syncthreads();
#pragma unroll
  for (int im = 0; im < 4; ++im)
#pragma unroll
    for (int j = 0; j < 4; ++j) {
      const int row = rbase + im * 16 + lg * 4 + j;
      const float m = fmaxf(pmax[0][row], pmax[1][row]);
      float s = 0.f;
#pragma unroll
      for (int in = 0; in < 4; ++in) {
        float p = __expf(0.125f * (sa[im][in][j] - m));
        sa[im][in][j] = p;
        s += p;
      }
      s += __shfl_xor(s, 1); s += __shfl_xor(s, 2); s += __shfl_xor(s, 4); s += __shfl_xor(s, 8);
      if (lr == 0) psum[wn][row] = s;
    }
#pragma unroll
  for (int im = 0; im < 4; ++im)
#pragma unroll
    for (int in = 0; in < 4; ++in)
#pragma unroll
      for (int j = 0; j < 4; ++j)
        sm.Pb[rbase + im * 16 + lg * 4 + j][wn * 64 + in * 16 + lr] = f2bf(sa[im][in][j]);
  __syncthreads();

  f32x4 oa[2][4];
#pragma unroll
  for (int i = 0; i < 2; ++i)
#pragma unroll
    for (int j = 0; j < 4; ++j) oa[i][j] = (f32x4){0.f, 0.f, 0.f, 0.f};
#pragma unroll
  for (int ks = 0; ks < 4; ++ks) {
    bf16x8 av[2], bv[4];
#pragma unroll
    for (int im = 0; im < 2; ++im)
      av[im] = *(const bf16x8*)&sm.Pb[wid * 32 + im * 16 + lr][ks * 32 + lg * 8];
#pragma unroll
    for (int in = 0; in < 4; ++in)
      bv[in] = *(const bf16x8*)&Vt[in * 16 + lr][ks * 32 + lg * 8];
#pragma unroll
    for (int im = 0; im < 2; ++im)
#pragma unroll
      for (int in = 0; in < 4; ++in)
        oa[im][in] = __builtin_amdgcn_mfma_f32_16x16x32_bf16(av[im], bv[in], oa[im][in], 0, 0, 0);
  }
#pragma unroll
  for (int im = 0; im < 2; ++im)
#pragma unroll
    for (int j = 0; j < 4; ++j) {
      const int qi = wid * 32 + im * 16 + lg * 4 + j;
      const float inv = 1.f / (psum[0][qi] + psum[1][qi]);
#pragma unroll
      for (int in = 0; in < 4; ++in)
        o[((size_t)n * 128 + qi) * 512 + h * 64 + in * 16 + lr] = f2bf(oa[im][in][j] * inv);
    }
}

// ---------------------------------------------------------------------------
extern "C" void kernel_launch(void* const* d_in, const int* in_sizes, int n_in,
                              void* d_out, int out_size, void* d_ws, size_t ws_size,
                              hipStream_t stream) {
  const float* source = (const float*)d_in[0];
  const float* qlat   = (const float*)d_in[1];
  const float* ca_ln  = (const float*)d_in[2];
  const float* ca_wq  = (const float*)d_in[3];
  const float* ca_wk  = (const float*)d_in[4];
  const float* ca_bk  = (const float*)d_in[5];
  const float* ca_wv  = (const float*)d_in[6];
  const float* ca_wo  = (const float*)d_in[7];
  const float* ca_w1  = (const float*)d_in[8];
  const float* ca_w2  = (const float*)d_in[9];
  const float* ta_ln  = (const float*)d_in[10];
  const float* ta_wq  = (const float*)d_in[11];
  const float* ta_wk  = (const float*)d_in[12];
  const float* ta_bk  = (const float*)d_in[13];
  const float* ta_wv  = (const float*)d_in[14];
  const float* ta_wo  = (const float*)d_in[15];
  const float* ta_w1  = (const float*)d_in[16];
  const float* ta_w2  = (const float*)d_in[17];
  float* lat = (float*)d_out;  // residual stream lives in d_out
  char* ws = (char*)d_ws;
  (void)in_sizes; (void)n_in; (void)out_size;

  if (ws_size < 251674624ull) return;  // known-good guard from R2

  const size_t WQ = 512 * 512, W1SZ = (size_t)512 * 4096, W2SZ = (size_t)2048 * 512;
  const size_t O_CA_WQ = 0,
               O_CA_KV = 4 * WQ,
               O_CA_WO = 12 * WQ,
               O_CA_W1 = 16 * WQ,
               O_CA_W2 = O_CA_W1 + 4 * W1SZ,
               O_TA_WQ = O_CA_W2 + 4 * W2SZ,
               O_TA_KV = O_TA_WQ + 4 * WQ,
               O_TA_WO = O_TA_KV + 8 * WQ,
               O_TA_W1 = O_TA_WO + 4 * WQ,
               O_TA_W2 = O_TA_W1 + 4 * W1SZ;  // ends at 128*WQ = 67,108,864 B

  u16*   W    = (u16*)ws;                    // [0, 67,108,864)  weights (exact)
  u16*   xn   = (u16*)(ws + 67108864);       // 32 MiB
  u16*   shat = (u16*)(ws + 100663296);      // 64 MiB (CA s_n; TA fused KV; h2 head)
  u16*   qb   = (u16*)(ws + 167772160);      // 32 MiB (q / attn out)
  u16*   kvb  = (u16*)(ws + 201326592);      // 48 MiB (CA fused K|V chunk)
  u16*   h2   = shat;                        // MLP hidden 128 MiB
  u16*   takv = shat;                        // TA fused KV 64 MiB
  float* cosT = (float*)(ws + 251658240);    // 8 KiB  (tail gap, within guard)
  float* sinT = (float*)(ws + 251666432);    // 8 KiB

  transpose_cast<<<dim3(16, 16, 4), 256, 0, stream>>>(ca_wq, W + O_CA_WQ, 512, 512, WQ);
  transpose_cast<<<dim3(16, 16, 4), 256, 0, stream>>>(ca_wk, W + O_CA_KV, 512, 512, 2 * WQ);
  transpose_cast<<<dim3(16, 16, 4), 256, 0, stream>>>(ca_wv, W + O_CA_KV + WQ, 512, 512, 2 * WQ);
  transpose_cast<<<dim3(16, 16, 4), 256, 0, stream>>>(ca_wo, W + O_CA_WO, 512, 512, WQ);
  transpose_w1 <<<dim3(128, 16, 4), 256, 0, stream>>>(ca_w1, W + O_CA_W1);
  transpose_cast<<<dim3(16, 64, 4), 256, 0, stream>>>(ca_w2, W + O_CA_W2, 2048, 512, W2SZ);
  transpose_cast<<<dim3(16, 16, 4), 256, 0, stream>>>(ta_wq, W + O_TA_WQ, 512, 512, WQ);
  transpose_cast<<<dim3(16, 16, 4), 256, 0, stream>>>(ta_wk, W + O_TA_KV, 512, 512, 2 * WQ);
  transpose_cast<<<dim3(16, 16, 4), 256, 0, stream>>>(ta_wv, W + O_TA_KV + WQ, 512, 512, 2 * WQ);
  transpose_cast<<<dim3(16, 16, 4), 256, 0, stream>>>(ta_wo, W + O_TA_WO, 512, 512, WQ);
  transpose_w1 <<<dim3(128, 16, 4), 256, 0, stream>>>(ta_w1, W + O_TA_W1);
  transpose_cast<<<dim3(16, 64, 4), 256, 0, stream>>>(ta_w2, W + O_TA_W2, 2048, 512, W2SZ);
  rope_init<<<8, 256, 0, stream>>>(cosT, sinT);
  init_lat<<<16384, 256, 0, stream>>>(qlat, lat);

  for (int b = 0; b < 4; ++b) {
    const u16* wqt   = W + O_CA_WQ + (size_t)b * WQ;
    const u16* wkvt  = W + O_CA_KV + (size_t)b * 2 * WQ;
    const u16* wot   = W + O_CA_WO + (size_t)b * WQ;
    const u16* w1t   = W + O_CA_W1 + (size_t)b * W1SZ;
    const u16* w2t   = W + O_CA_W2 + (size_t)b * W2SZ;
    const u16* twqt  = W + O_TA_WQ + (size_t)b * WQ;
    const u16* twkvt = W + O_TA_KV + (size_t)b * 2 * WQ;
    const u16* twot  = W + O_TA_WO + (size_t)b * WQ;
    const u16* tw1t  = W + O_TA_W1 + (size_t)b * W1SZ;
    const u16* tw2t  = W + O_TA_W2 + (size_t)b * W2SZ;

    // ---- cross attention ----
    rms_rows<0><<<8192, 256, 0, stream>>>(lat, ca_ln + b * 1536, xn);              // l_n
    rms_rows<0><<<16384, 256, 0, stream>>>(source, ca_ln + b * 1536 + 512, shat);  // s_n
    gemm256<0, 0, 0><<<dim3(2, 128), 512, 0, stream>>>(xn, nullptr, wqt, qb, nullptr, nullptr, 32768, 512, 512, 0);
    for (int c = 0; c < 4; ++c) {  // fused K|V + attention per 256-batch chunk
      gemm256<1, 0, 1><<<dim3(4, 96), 512, 0, stream>>>(shat, xn, wkvt, kvb, nullptr, ca_bk + b * 512, 24576, 1024, 512, c * 256);
      attn_ca<<<dim3(256, 8), 256, 0, stream>>>(qb, kvb, qb, c * 256);
    }
    gemm256<2, 0, 0><<<dim3(2, 128), 512, 0, stream>>>(qb, nullptr, wot, nullptr, lat, nullptr, 32768, 512, 512, 0);
    rms_rows<0><<<8192, 256, 0, stream>>>(lat, ca_ln + b * 1536 + 1024, xn);
    gemm256<3, 0, 0><<<dim3(16, 128), 512, 0, stream>>>(xn, nullptr, w1t, h2, nullptr, nullptr, 32768, 4096, 512, 0);
    gemm256<2, 0, 0><<<dim3(2, 128), 512, 0, stream>>>(h2, nullptr, w2t, nullptr, lat, nullptr, 32768, 512, 2048, 0);

    // ---- temporal attention ----
    rms_rows<1><<<8192, 256, 0, stream>>>(lat, ta_ln + b * 1024, xn);
    gemm256<0, 0, 0><<<dim3(2, 128), 512, 0, stream>>>(xn, nullptr, twqt, qb, nullptr, nullptr, 32768, 512, 512, 0);
    gemm256<1, 0, 0><<<dim3(4, 128), 512, 0, stream>>>(xn, nullptr, twkvt, takv, nullptr, ta_bk + b * 512, 32768, 1024, 512, 0);
    attn_ta<<<dim3(256, 8), 256, 0, stream>>>(qb, takv, cosT, sinT, qb);
    gemm256<2, 1, 0><<<dim3(2, 128), 512, 0, stream>>>(qb, nullptr, twot, nullptr, lat, nullptr, 32768, 512, 512, 0);
    rms_rows<1><<<8192, 256, 0, stream>>>(lat, ta_ln + b * 1024 + 512, xn);
    gemm256<3, 0, 0><<<dim3(16, 128), 512, 0, stream>>>(xn, nullptr, tw1t, h2, nullptr, nullptr, 32768, 4096, 512, 0);
    gemm256<2, 1, 0><<<dim3(2, 128), 512, 0, stream>>>(h2, nullptr, tw2t, nullptr, lat, nullptr, 32768, 512, 2048, 0);
  }
}

// Round 8
// 4909.673 us; speedup vs baseline: 1.3045x; 1.0276x over previous
//
#include <hip/hip_runtime.h>
#include <stdint.h>

// ---------------------------------------------------------------------------
// SpatioTemporalPerceiverResampler  (D=512, H=8, DH=64, NB=4, DMLP=2048,
// L=32, T=128, B=8, BT=1024, ROPE_DIM=32)
// R8: gemm256 frag-pipelining (ds_read one phase ahead, ping-pong reg sets;
// next-tile B/p0 frags read post-gate). G-loads spread 2/phase. Gate vmcnt(4).
// Attention (R6) and all else unchanged.
// ---------------------------------------------------------------------------

typedef short    bf16x8 __attribute__((ext_vector_type(8)));
typedef float    f32x4  __attribute__((ext_vector_type(4)));
typedef uint16_t u16;

__device__ __forceinline__ float bf2f(uint32_t u) {
  union { uint32_t i; float f; } x; x.i = u << 16; return x.f;
}
__device__ __forceinline__ u16 f2bf(float f) {
  union { float f; uint32_t i; } x; x.f = f;
  return (u16)((x.i + 0x7fffu + ((x.i >> 16) & 1u)) >> 16);  // RNE
}
__device__ __forceinline__ float gelu_t(float x) {  // jax.nn.gelu approximate=True
  float u = 0.7978845608028654f * (x + 0.044715f * x * x * x);
  float t = 1.f - 2.f / (__expf(2.f * u) + 1.f);
  return 0.5f * x * (1.f + t);
}
// r_x = (b*L + l)*T + t  ->  lat row (b*T + t)*L + l     (L=32, T=128)
template<int RMAP>
__device__ __forceinline__ int maprow(int r) {
  if (RMAP == 0) return r;
  int b = r >> 12, rem = r & 4095;
  return ((b << 7) + (rem & 127)) * 32 + (rem >> 7);
}
__device__ __forceinline__ void glds16(const u16* g, u16* l) {
  __builtin_amdgcn_global_load_lds((const __attribute__((address_space(1))) uint32_t*)(g),
                                   (__attribute__((address_space(3))) uint32_t*)(l),
                                   16, 0, 0);
}

// ---------------------------------------------------------------------------
__global__ __launch_bounds__(256) void transpose_cast(const float* __restrict__ src,
                                                      u16* __restrict__ dst,
                                                      int R, int C, size_t zsD) {
  src += (size_t)blockIdx.z * R * C;
  dst += (size_t)blockIdx.z * zsD;
  __shared__ float t[32][33];
  int c0 = blockIdx.x * 32, r0 = blockIdx.y * 32;
  int tx = threadIdx.x & 31, ty = threadIdx.x >> 5;
#pragma unroll
  for (int i = 0; i < 32; i += 8) t[ty + i][tx] = src[(size_t)(r0 + ty + i) * C + c0 + tx];
  __syncthreads();
#pragma unroll
  for (int i = 0; i < 32; i += 8)
    dst[(size_t)(c0 + ty + i) * R + r0 + tx] = f2bf(t[tx][ty + i]);
}

// w1 (512 x 4096) -> w1t (4096 x 512), GEGLU interleave for the 256-tile GEMM:
// dst row c: src col (c>>8)*128 + ((c>>6)&3)*32 + (c&31) + (c&32 ? 2048 : 0)
__global__ __launch_bounds__(256) void transpose_w1(const float* __restrict__ src,
                                                    u16* __restrict__ dst) {
  src += (size_t)blockIdx.z * 512 * 4096;
  dst += (size_t)blockIdx.z * 512 * 4096;
  __shared__ float t[32][33];
  int c0 = blockIdx.x * 32, r0 = blockIdx.y * 32;
  int m0 = (c0 >> 8) * 128 + ((c0 >> 6) & 3) * 32 + ((c0 & 32) ? 2048 : 0);
  int tx = threadIdx.x & 31, ty = threadIdx.x >> 5;
#pragma unroll
  for (int i = 0; i < 32; i += 8) t[ty + i][tx] = src[(size_t)(r0 + ty + i) * 4096 + m0 + tx];
  __syncthreads();
#pragma unroll
  for (int i = 0; i < 32; i += 8)
    dst[(size_t)(c0 + ty + i) * 512 + r0 + tx] = f2bf(t[tx][ty + i]);
}

// ---------------------------------------------------------------------------
__global__ void rope_init(float* cosT, float* sinT) {
  int idx = blockIdx.x * 256 + threadIdx.x;
  if (idx < 128 * 16) {
    int t = idx >> 4, j = idx & 15;
    float inv = __expf(-logf(10000.f) * (float)j / 16.f);
    float a = (float)t * inv;
    cosT[idx] = cosf(a);
    sinT[idx] = sinf(a);
  }
}

__global__ __launch_bounds__(256) void init_lat(const float* __restrict__ ql,
                                                float* __restrict__ lat) {
  size_t i = (size_t)blockIdx.x * 256 + threadIdx.x;  // float4 index
  int r = (int)(i >> 7), cw = (int)(i & 127);
  int l = r & 31;
  ((float4*)lat)[i] = ((const float4*)ql)[l * 128 + cw];
}

// ---------------------------------------------------------------------------
template<int RMAP>
__global__ __launch_bounds__(256) void rms_rows(const float* __restrict__ src,
                                                const float* __restrict__ g,
                                                u16* __restrict__ out) {
  const int wid = threadIdx.x >> 6, lane = threadIdx.x & 63;
  const int row = (blockIdx.x << 2) + wid;
  const int srow = maprow<RMAP>(row);
  const float4* p = (const float4*)(src + (size_t)srow * 512);
  float4 v0 = p[lane * 2], v1 = p[lane * 2 + 1];
  float ss = v0.x * v0.x + v0.y * v0.y + v0.z * v0.z + v0.w * v0.w +
             v1.x * v1.x + v1.y * v1.y + v1.z * v1.z + v1.w * v1.w;
#pragma unroll
  for (int m = 1; m < 64; m <<= 1) ss += __shfl_xor(ss, m);
  const float rs = rsqrtf(ss * (1.f / 512.f) + 1e-6f);
  const float4* gp = (const float4*)g;
  float4 g0 = gp[lane * 2], g1 = gp[lane * 2 + 1];
  u16 rb[8];
  rb[0] = f2bf(v0.x * rs * g0.x); rb[1] = f2bf(v0.y * rs * g0.y);
  rb[2] = f2bf(v0.z * rs * g0.z); rb[3] = f2bf(v0.w * rs * g0.w);
  rb[4] = f2bf(v1.x * rs * g1.x); rb[5] = f2bf(v1.y * rs * g1.y);
  rb[6] = f2bf(v1.z * rs * g1.z); rb[7] = f2bf(v1.w * rs * g1.w);
  *(int4*)(out + (size_t)row * 512 + lane * 8) = *(int4*)rb;
}

// ---------------------------------------------------------------------------
// gemm256 R8: 256x256 tile, BK=64, 8 waves (2M x 4N), per-wave C 128x64.
// Frag-pipelined 4-phase K-loop: phase p issues ds_read of phase p+1's A-frags
// before its MFMA (ping-pong reg sets); next-tile B-frags + p0-frags read
// post-gate at p3. A triple-buffered LDS, B double-buffered; G-loads spread
// 2/phase (B(kt+1)@p0-p1, A(kt+2)@p2-p3); gate = vmcnt(4). XOR-swizzle, T1.
// ---------------------------------------------------------------------------
template<int EPI, int RMAP, int AMAP>
__global__ __launch_bounds__(512, 2) void gemm256(const u16* __restrict__ A,
                                                  const u16* __restrict__ A2,
                                                  const u16* __restrict__ Bt,
                                                  u16* __restrict__ outH,
                                                  float* __restrict__ latF,
                                                  const float* __restrict__ bias,
                                                  int M, int N, int K, int nb) {
  __shared__ __align__(16) u16 Ab[3][256 * 64];   // 96 KiB
  __shared__ __align__(16) u16 Bb[2][256 * 64];   // 64 KiB
  const int tid = threadIdx.x;
  // T1: XCD-aware block swizzle (all grids have nwg % 8 == 0 -> bijective)
  const int nwg = gridDim.x * gridDim.y;
  int bid = blockIdx.y * gridDim.x + blockIdx.x;
  bid = (bid & 7) * (nwg >> 3) + (bid >> 3);
  const int m0 = (bid / gridDim.x) << 8;
  const int n0 = (bid % gridDim.x) << 8;
  const int wid = tid >> 6, lane = tid & 63;
  const int wm = wid >> 2, wn = wid & 3;
  const int lr = lane & 15, lg = lane >> 4;
  const int rx = (lr & 7) << 3;  // read-side col XOR (elems)

  // stage half h (2 glds16/thread) of a 256x64 K-tile into LDS slot.
  auto stageA = [&](int slot, int kt, int h) {
#pragma unroll
    for (int i = 0; i < 2; ++i) {
      const int e = ((h * 2 + i) * 512 + tid) * 8;
      const int r = e >> 6;
      const int cs = (e & 63) ^ ((r & 7) << 3);
      const u16* src;
      if constexpr (AMAP == 0) {
        src = A + (size_t)(m0 + r) * K + kt * 64 + cs;
      } else {
        const int R = m0 + r;
        const int n_ = R / 96;
        const int j = R - n_ * 96;
        src = (j < 64) ? A  + ((size_t)((nb + n_) * 64 + j)) * 512 + kt * 64 + cs
                       : A2 + ((size_t)((nb + n_) * 32 + (j - 64))) * 512 + kt * 64 + cs;
      }
      glds16(src, &Ab[slot][e]);
    }
  };
  auto stageB = [&](int slot, int kt, int h) {
#pragma unroll
    for (int i = 0; i < 2; ++i) {
      const int e = ((h * 2 + i) * 512 + tid) * 8;
      const int r = e >> 6;
      const int cs = (e & 63) ^ ((r & 7) << 3);
      glds16(Bt + (size_t)(n0 + r) * K + kt * 64 + cs, &Bb[slot][e]);
    }
  };

  bf16x8 bfr[2][4];                    // B-frags, whole K-tile
  bf16x8 afrA[2][2], afrB_[2][2];      // A-frag ping-pong (even/odd phase)
  auto readAfr = [&](bf16x8 (&dst)[2][2], const u16* Abase, int p) {
#pragma unroll
    for (int d = 0; d < 2; ++d)
#pragma unroll
      for (int ks = 0; ks < 2; ++ks) {
        const int rw = wm * 128 + (p * 2 + d) * 16 + lr;
        dst[d][ks] = *(const bf16x8*)&Abase[rw * 64 + ((ks * 32 + lg * 8) ^ rx)];
      }
  };
  auto readBfr = [&](const u16* Bbase) {
#pragma unroll
    for (int ks = 0; ks < 2; ++ks)
#pragma unroll
      for (int in = 0; in < 4; ++in) {
        const int rw = wn * 64 + in * 16 + lr;
        bfr[ks][in] = *(const bf16x8*)&Bbase[rw * 64 + ((ks * 32 + lg * 8) ^ rx)];
      }
  };

  f32x4 acc[8][4];
#pragma unroll
  for (int i = 0; i < 8; ++i)
#pragma unroll
    for (int j = 0; j < 4; ++j) acc[i][j] = (f32x4){0.f, 0.f, 0.f, 0.f};

  // prologue: A0, B0, A1 issued (12 loads); wait A0+B0 (A1 stays in flight);
  // pre-read tile0's B-frags and p0 A-frags.
  stageA(0, 0, 0); stageA(0, 0, 1);
  stageB(0, 0, 0); stageB(0, 0, 1);
  stageA(1, 1, 0); stageA(1, 1, 1);
  asm volatile("s_waitcnt vmcnt(4)" ::: "memory");
  __builtin_amdgcn_s_barrier();
  asm volatile("" ::: "memory");
  readBfr(&Bb[0][0]);
  readAfr(afrA, &Ab[0][0], 0);

  const int nkt = K >> 6;
  int sl0 = 0;  // LDS A-slot of tile kt
  int sl2 = 2;  // LDS A-slot of tile kt+2
  for (int kt = 0; kt < nkt; ++kt) {
    const u16* Abase = &Ab[sl0][0];
#pragma unroll
    for (int p = 0; p < 4; ++p) {
      // G-issue schedule: B(kt+1) halves at p0/p1; A(kt+2) halves at p2/p3.
      if (p <= 1 && kt + 1 < nkt) stageB((kt + 1) & 1, kt + 1, p);
      if (p >= 2 && kt + 2 < nkt) stageA(sl2, kt + 2, p - 2);
      // prefetch next phase's A-frags (within tile) into the other reg set
      if (p < 3) {
        if ((p & 1) == 0) readAfr(afrB_, Abase, p + 1);
        else              readAfr(afrA,  Abase, p + 1);
      }
      __builtin_amdgcn_s_setprio(1);
      if ((p & 1) == 0) {
#pragma unroll
        for (int d = 0; d < 2; ++d)
#pragma unroll
          for (int in = 0; in < 4; ++in)
#pragma unroll
            for (int ks = 0; ks < 2; ++ks)
              acc[p * 2 + d][in] = __builtin_amdgcn_mfma_f32_16x16x32_bf16(
                  afrA[d][ks], bfr[ks][in], acc[p * 2 + d][in], 0, 0, 0);
      } else {
#pragma unroll
        for (int d = 0; d < 2; ++d)
#pragma unroll
          for (int in = 0; in < 4; ++in)
#pragma unroll
            for (int ks = 0; ks < 2; ++ks)
              acc[p * 2 + d][in] = __builtin_amdgcn_mfma_f32_16x16x32_bf16(
                  afrB_[d][ks], bfr[ks][in], acc[p * 2 + d][in], 0, 0, 0);
      }
      __builtin_amdgcn_s_setprio(0);
      if (p < 3) {
        __builtin_amdgcn_s_barrier();
      } else if (kt + 1 < nkt) {
        // gate into tile kt+1: counted wait (A(kt+2) stays in flight), then
        // pre-read next tile's B-frags + p0 A-frags under the new buffers.
        if (kt + 2 < nkt) asm volatile("s_waitcnt vmcnt(4)" ::: "memory");
        else              asm volatile("s_waitcnt vmcnt(0)" ::: "memory");
        __builtin_amdgcn_s_barrier();
        asm volatile("" ::: "memory");
        const int sln = (sl0 == 2) ? 0 : sl0 + 1;
        readBfr(&Bb[(kt + 1) & 1][0]);
        readAfr(afrA, &Ab[sln][0], 0);
      }
    }
    sl0 = (sl0 == 2) ? 0 : sl0 + 1;
    sl2 = (sl2 == 2) ? 0 : sl2 + 1;
  }

  // ---- epilogues (direct stores) ----
  if constexpr (EPI == 3) {
    const int t128 = n0 >> 1;
#pragma unroll
    for (int im = 0; im < 8; ++im)
#pragma unroll
      for (int in = 0; in < 2; ++in)
#pragma unroll
        for (int j = 0; j < 4; ++j) {
          const int row = m0 + wm * 128 + im * 16 + lg * 4 + j;
          const int hcol = t128 + wn * 32 + in * 16 + lr;
          outH[(size_t)row * 2048 + hcol] = f2bf(acc[im][in][j] * gelu_t(acc[im][in + 2][j]));
        }
  } else if constexpr (EPI == 2) {
#pragma unroll
    for (int im = 0; im < 8; ++im)
#pragma unroll
      for (int in = 0; in < 4; ++in) {
        const int col = n0 + wn * 64 + in * 16 + lr;
#pragma unroll
        for (int j = 0; j < 4; ++j) {
          const int row = m0 + wm * 128 + im * 16 + lg * 4 + j;
          const size_t rr = (size_t)maprow<RMAP>(row) * 512 + col;
          latF[rr] += acc[im][in][j];
        }
      }
  } else {
    float bv4[4];
    if constexpr (EPI == 1) {
#pragma unroll
      for (int in = 0; in < 4; ++in)
        bv4[in] = (n0 < 512) ? bias[n0 + wn * 64 + in * 16 + lr] : 0.f;
    }
#pragma unroll
    for (int im = 0; im < 8; ++im)
#pragma unroll
      for (int in = 0; in < 4; ++in) {
        const int col = n0 + wn * 64 + in * 16 + lr;
#pragma unroll
        for (int j = 0; j < 4; ++j) {
          const int row = m0 + wm * 128 + im * 16 + lg * 4 + j;
          float v = acc[im][in][j];
          if constexpr (EPI == 1) v += bv4[in];
          outH[(size_t)row * N + col] = f2bf(v);
        }
      }
  }
}

// ---------------------------------------------------------------------------
// Cross-attention R6: block per (n_local,h), n = nb + n_local. Lq=32, Lk=96.
// ---------------------------------------------------------------------------
__global__ __launch_bounds__(256) void attn_ca(const u16* q,
                                               const u16* __restrict__ kv,
                                               u16* o, int nb) {
  union __align__(16) SM {
    struct { u16 Qs[32][72]; u16 Ks[96][72]; } qk;
    u16 Pb[32][104];
  };
  __shared__ SM sm;
  __shared__ __align__(16) u16 Vt[64][104];
  __shared__ float pmax[2][32];
  __shared__ float psum[2][32];
  const int nl = blockIdx.x, n = nb + nl, h = blockIdx.y, tid = threadIdx.x;

  {
    int r = tid >> 3, c = (tid & 7) * 8;
    *(int4*)&sm.qk.Qs[r][c] = *(const int4*)&q[((size_t)n * 32 + r) * 512 + h * 64 + c];
  }
#pragma unroll
  for (int i = 0; i < 3; ++i) {
    int idx = i * 256 + tid;
    int r = idx >> 3, c = (idx & 7) * 8;
    *(int4*)&sm.qk.Ks[r][c] = *(const int4*)&kv[((size_t)nl * 96 + r) * 1024 + h * 64 + c];
  }
#pragma unroll
  for (int i = 0; i < 3; ++i) {
    int idx = i * 256 + tid;
    int dg = idx / 96, t = idx - dg * 96;
    int4 pv = *(const int4*)&kv[((size_t)nl * 96 + t) * 1024 + 512 + h * 64 + dg * 8];
    const u16* pu = (const u16*)&pv;
#pragma unroll
    for (int e = 0; e < 8; ++e) Vt[dg * 8 + e][t] = pu[e];
  }
  __syncthreads();

  const int wid = tid >> 6, lane = tid & 63, lr = lane & 15, lg = lane >> 4;
  const int m0 = (wid & 1) * 16, wnq = wid >> 1, nbc = wnq * 48;

  f32x4 sa[3];
#pragma unroll
  for (int f = 0; f < 3; ++f) sa[f] = (f32x4){0.f, 0.f, 0.f, 0.f};
#pragma unroll
  for (int ks = 0; ks < 2; ++ks) {
    bf16x8 a = *(const bf16x8*)&sm.qk.Qs[m0 + lr][ks * 32 + lg * 8];
#pragma unroll
    for (int f = 0; f < 3; ++f) {
      bf16x8 bb = *(const bf16x8*)&sm.qk.Ks[nbc + f * 16 + lr][ks * 32 + lg * 8];
      sa[f] = __builtin_amdgcn_mfma_f32_16x16x32_bf16(a, bb, sa[f], 0, 0, 0);
    }
  }

#pragma unroll
  for (int j = 0; j < 4; ++j) {
    float m = fmaxf(fmaxf(sa[0][j], sa[1][j]), sa[2][j]);
    m = fmaxf(m, __shfl_xor(m, 1));
    m = fmaxf(m, __shfl_xor(m, 2));
    m = fmaxf(m, __shfl_xor(m, 4));
    m = fmaxf(m, __shfl_xor(m, 8));
    if (lr == 0) pmax[wnq][m0 + lg * 4 + j] = m;
  }
  __syncthreads();
#pragma unroll
  for (int j = 0; j < 4; ++j) {
    const int row = m0 + lg * 4 + j;
    const float m = fmaxf(pmax[0][row], pmax[1][row]);
    float s = 0.f;
#pragma unroll
    for (int f = 0; f < 3; ++f) {
      float p = __expf(0.125f * (sa[f][j] - m));
      sa[f][j] = p;
      s += p;
    }
    s += __shfl_xor(s, 1); s += __shfl_xor(s, 2); s += __shfl_xor(s, 4); s += __shfl_xor(s, 8);
    if (lr == 0) psum[wnq][row] = s;
  }
#pragma unroll
  for (int f = 0; f < 3; ++f)
#pragma unroll
    for (int j = 0; j < 4; ++j)
      sm.Pb[m0 + lg * 4 + j][nbc + f * 16 + lr] = f2bf(sa[f][j]);
  __syncthreads();

  const int n0d = wnq * 32;
  f32x4 oa[2];
#pragma unroll
  for (int f = 0; f < 2; ++f) oa[f] = (f32x4){0.f, 0.f, 0.f, 0.f};
#pragma unroll
  for (int ks = 0; ks < 3; ++ks) {
    bf16x8 a = *(const bf16x8*)&sm.Pb[m0 + lr][ks * 32 + lg * 8];
#pragma unroll
    for (int f = 0; f < 2; ++f) {
      bf16x8 bb = *(const bf16x8*)&Vt[n0d + f * 16 + lr][ks * 32 + lg * 8];
      oa[f] = __builtin_amdgcn_mfma_f32_16x16x32_bf16(a, bb, oa[f], 0, 0, 0);
    }
  }
#pragma unroll
  for (int j = 0; j < 4; ++j) {
    const int row = m0 + lg * 4 + j;
    const float inv = 1.f / (psum[0][row] + psum[1][row]);
#pragma unroll
    for (int f = 0; f < 2; ++f)
      o[((size_t)n * 32 + row) * 512 + h * 64 + n0d + f * 16 + lr] = f2bf(oa[f][j] * inv);
  }
}

// ---------------------------------------------------------------------------
// Temporal attention R6 with RoPE: block per (n,h), n in [0,256). T=128.
// ---------------------------------------------------------------------------
__global__ __launch_bounds__(256) void attn_ta(const u16* q,
                                               const u16* __restrict__ kv,
                                               const float* __restrict__ cosT,
                                               const float* __restrict__ sinT,
                                               u16* o) {
  union __align__(16) SM {
    struct { u16 Qs[128][72]; u16 Ks[128][72]; } qk;
    u16 Pb[128][136];
  };
  __shared__ SM sm;
  __shared__ __align__(16) u16 Vt[64][136];
  __shared__ float pmax[2][128];
  __shared__ float psum[2][128];
  const int n = blockIdx.x, h = blockIdx.y, tid = threadIdx.x;

#pragma unroll
  for (int i = 0; i < 16; ++i) {
    int idx = i * 256 + tid;
    int t = idx >> 5, pr = idx & 31;
    uint32_t uq = *(const uint32_t*)&q[((size_t)n * 128 + t) * 512 + h * 64 + pr * 2];
    uint32_t uk = *(const uint32_t*)&kv[((size_t)n * 128 + t) * 1024 + h * 64 + pr * 2];
    float q1 = bf2f(uq & 0xffff), q2 = bf2f(uq >> 16);
    float k1 = bf2f(uk & 0xffff), k2 = bf2f(uk >> 16);
    if (pr < 16) {
      float c = cosT[t * 16 + pr], s = sinT[t * 16 + pr];
      float a;
      a = q1 * c - q2 * s; q2 = q1 * s + q2 * c; q1 = a;
      a = k1 * c - k2 * s; k2 = k1 * s + k2 * c; k1 = a;
    }
    sm.qk.Qs[t][pr * 2] = f2bf(q1); sm.qk.Qs[t][pr * 2 + 1] = f2bf(q2);
    sm.qk.Ks[t][pr * 2] = f2bf(k1); sm.qk.Ks[t][pr * 2 + 1] = f2bf(k2);
  }
#pragma unroll
  for (int i = 0; i < 4; ++i) {
    int idx = i * 256 + tid;
    int t = idx & 127, d0 = (idx >> 7) * 8;
    int4 pv = *(const int4*)&kv[((size_t)n * 128 + t) * 1024 + 512 + h * 64 + d0];
    const u16* pu = (const u16*)&pv;
#pragma unroll
    for (int e = 0; e < 8; ++e) Vt[d0 + e][t] = pu[e];
  }
  __syncthreads();

  const int wid = tid >> 6, lane = tid & 63, lr = lane & 15, lg = lane >> 4;
  const int wm = wid >> 1, wn = wid & 1;
  const int rbase = wm * 64;

  f32x4 sa[4][4];
#pragma unroll
  for (int i = 0; i < 4; ++i)
#pragma unroll
    for (int j = 0; j < 4; ++j) sa[i][j] = (f32x4){0.f, 0.f, 0.f, 0.f};
#pragma unroll
  for (int ks = 0; ks < 2; ++ks) {
    bf16x8 av[4], bv[4];
#pragma unroll
    for (int im = 0; im < 4; ++im)
      av[im] = *(const bf16x8*)&sm.qk.Qs[rbase + im * 16 + lr][ks * 32 + lg * 8];
#pragma unroll
    for (int in = 0; in < 4; ++in)
      bv[in] = *(const bf16x8*)&sm.qk.Ks[wn * 64 + in * 16 + lr][ks * 32 + lg * 8];
#pragma unroll
    for (int im = 0; im < 4; ++im)
#pragma unroll
      for (int in = 0; in < 4; ++in)
        sa[im][in] = __builtin_amdgcn_mfma_f32_16x16x32_bf16(av[im], bv[in], sa[im][in], 0, 0, 0);
  }

#pragma unroll
  for (int im = 0; im < 4; ++im)
#pragma unroll
    for (int j = 0; j < 4; ++j) {
      float m = fmaxf(fmaxf(sa[im][0][j], sa[im][1][j]), fmaxf(sa[im][2][j], sa[im][3][j]));
      m = fmaxf(m, __shfl_xor(m, 1));
      m = fmaxf(m, __shfl_xor(m, 2));
      m = fmaxf(m, __shfl_xor(m, 4));
      m = fmaxf(m, __shfl_xor(m, 8));
      if (lr == 0) pmax[wn][rbase + im * 16 + lg * 4 + j] = m;
    }
  __syncthreads();
#pragma unroll
  for (int im = 0; im < 4; ++im)
#pragma unroll
    for (int j = 0; j < 4; ++j) {
      const int row = rbase + im * 16 + lg * 4 + j;
      const float m = fmaxf(pmax[0][row], pmax[1][row]);
      float s = 0.f;
#pragma unroll
      for (int in = 0; in < 4; ++in) {
        float p = __expf(0.125f * (sa[im][in][j] - m));
        sa[im][in][j] = p;
        s += p;
      }
      s += __shfl_xor(s, 1); s += __shfl_xor(s, 2); s += __shfl_xor(s, 4); s += __shfl_xor(s, 8);
      if (lr == 0) psum[wn][row] = s;
    }
#pragma unroll
  for (int im = 0; im < 4; ++im)
#pragma unroll
    for (int in = 0; in < 4; ++in)
#pragma unroll
      for (int j = 0; j < 4; ++j)
        sm.Pb[rbase + im * 16 + lg * 4 + j][wn * 64 + in * 16 + lr] = f2bf(sa[im][in][j]);
  __syncthreads();

  f32x4 oa[2][4];
#pragma unroll
  for (int i = 0; i < 2; ++i)
#pragma unroll
    for (int j = 0; j < 4; ++j) oa[i][j] = (f32x4){0.f, 0.f, 0.f, 0.f};
#pragma unroll
  for (int ks = 0; ks < 4; ++ks) {
    bf16x8 av[2], bv[4];
#pragma unroll
    for (int im = 0; im < 2; ++im)
      av[im] = *(const bf16x8*)&sm.Pb[wid * 32 + im * 16 + lr][ks * 32 + lg * 8];
#pragma unroll
    for (int in = 0; in < 4; ++in)
      bv[in] = *(const bf16x8*)&Vt[in * 16 + lr][ks * 32 + lg * 8];
#pragma unroll
    for (int im = 0; im < 2; ++im)
#pragma unroll
      for (int in = 0; in < 4; ++in)
        oa[im][in] = __builtin_amdgcn_mfma_f32_16x16x32_bf16(av[im], bv[in], oa[im][in], 0, 0, 0);
  }
#pragma unroll
  for (int im = 0; im < 2; ++im)
#pragma unroll
    for (int j = 0; j < 4; ++j) {
      const int qi = wid * 32 + im * 16 + lg * 4 + j;
      const float inv = 1.f / (psum[0][qi] + psum[1][qi]);
#pragma unroll
      for (int in = 0; in < 4; ++in)
        o[((size_t)n * 128 + qi) * 512 + h * 64 + in * 16 + lr] = f2bf(oa[im][in][j] * inv);
    }
}

// ---------------------------------------------------------------------------
extern "C" void kernel_launch(void* const* d_in, const int* in_sizes, int n_in,
                              void* d_out, int out_size, void* d_ws, size_t ws_size,
                              hipStream_t stream) {
  const float* source = (const float*)d_in[0];
  const float* qlat   = (const float*)d_in[1];
  const float* ca_ln  = (const float*)d_in[2];
  const float* ca_wq  = (const float*)d_in[3];
  const float* ca_wk  = (const float*)d_in[4];
  const float* ca_bk  = (const float*)d_in[5];
  const float* ca_wv  = (const float*)d_in[6];
  const float* ca_wo  = (const float*)d_in[7];
  const float* ca_w1  = (const float*)d_in[8];
  const float* ca_w2  = (const float*)d_in[9];
  const float* ta_ln  = (const float*)d_in[10];
  const float* ta_wq  = (const float*)d_in[11];
  const float* ta_wk  = (const float*)d_in[12];
  const float* ta_bk  = (const float*)d_in[13];
  const float* ta_wv  = (const float*)d_in[14];
  const float* ta_wo  = (const float*)d_in[15];
  const float* ta_w1  = (const float*)d_in[16];
  const float* ta_w2  = (const float*)d_in[17];
  float* lat = (float*)d_out;  // residual stream lives in d_out
  char* ws = (char*)d_ws;
  (void)in_sizes; (void)n_in; (void)out_size;

  if (ws_size < 251674624ull) return;  // known-good guard from R2

  const size_t WQ = 512 * 512, W1SZ = (size_t)512 * 4096, W2SZ = (size_t)2048 * 512;
  const size_t O_CA_WQ = 0,
               O_CA_KV = 4 * WQ,
               O_CA_WO = 12 * WQ,
               O_CA_W1 = 16 * WQ,
               O_CA_W2 = O_CA_W1 + 4 * W1SZ,
               O_TA_WQ = O_CA_W2 + 4 * W2SZ,
               O_TA_KV = O_TA_WQ + 4 * WQ,
               O_TA_WO = O_TA_KV + 8 * WQ,
               O_TA_W1 = O_TA_WO + 4 * WQ,
               O_TA_W2 = O_TA_W1 + 4 * W1SZ;  // ends at 128*WQ = 67,108,864 B

  u16*   W    = (u16*)ws;                    // [0, 67,108,864)  weights (exact)
  u16*   xn   = (u16*)(ws + 67108864);       // 32 MiB
  u16*   shat = (u16*)(ws + 100663296);      // 64 MiB (CA s_n; TA fused KV; h2 head)
  u16*   qb   = (u16*)(ws + 167772160);      // 32 MiB (q / attn out)
  u16*   kvb  = (u16*)(ws + 201326592);      // 48 MiB (CA fused K|V chunk)
  u16*   h2   = shat;                        // MLP hidden 128 MiB
  u16*   takv = shat;                        // TA fused KV 64 MiB
  float* cosT = (float*)(ws + 251658240);    // 8 KiB  (tail gap, within guard)
  float* sinT = (float*)(ws + 251666432);    // 8 KiB

  transpose_cast<<<dim3(16, 16, 4), 256, 0, stream>>>(ca_wq, W + O_CA_WQ, 512, 512, WQ);
  transpose_cast<<<dim3(16, 16, 4), 256, 0, stream>>>(ca_wk, W + O_CA_KV, 512, 512, 2 * WQ);
  transpose_cast<<<dim3(16, 16, 4), 256, 0, stream>>>(ca_wv, W + O_CA_KV + WQ, 512, 512, 2 * WQ);
  transpose_cast<<<dim3(16, 16, 4), 256, 0, stream>>>(ca_wo, W + O_CA_WO, 512, 512, WQ);
  transpose_w1 <<<dim3(128, 16, 4), 256, 0, stream>>>(ca_w1, W + O_CA_W1);
  transpose_cast<<<dim3(16, 64, 4), 256, 0, stream>>>(ca_w2, W + O_CA_W2, 2048, 512, W2SZ);
  transpose_cast<<<dim3(16, 16, 4), 256, 0, stream>>>(ta_wq, W + O_TA_WQ, 512, 512, WQ);
  transpose_cast<<<dim3(16, 16, 4), 256, 0, stream>>>(ta_wk, W + O_TA_KV, 512, 512, 2 * WQ);
  transpose_cast<<<dim3(16, 16, 4), 256, 0, stream>>>(ta_wv, W + O_TA_KV + WQ, 512, 512, 2 * WQ);
  transpose_cast<<<dim3(16, 16, 4), 256, 0, stream>>>(ta_wo, W + O_TA_WO, 512, 512, WQ);
  transpose_w1 <<<dim3(128, 16, 4), 256, 0, stream>>>(ta_w1, W + O_TA_W1);
  transpose_cast<<<dim3(16, 64, 4), 256, 0, stream>>>(ta_w2, W + O_TA_W2, 2048, 512, W2SZ);
  rope_init<<<8, 256, 0, stream>>>(cosT, sinT);
  init_lat<<<16384, 256, 0, stream>>>(qlat, lat);

  for (int b = 0; b < 4; ++b) {
    const u16* wqt   = W + O_CA_WQ + (size_t)b * WQ;
    const u16* wkvt  = W + O_CA_KV + (size_t)b * 2 * WQ;
    const u16* wot   = W + O_CA_WO + (size_t)b * WQ;
    const u16* w1t   = W + O_CA_W1 + (size_t)b * W1SZ;
    const u16* w2t   = W + O_CA_W2 + (size_t)b * W2SZ;
    const u16* twqt  = W + O_TA_WQ + (size_t)b * WQ;
    const u16* twkvt = W + O_TA_KV + (size_t)b * 2 * WQ;
    const u16* twot  = W + O_TA_WO + (size_t)b * WQ;
    const u16* tw1t  = W + O_TA_W1 + (size_t)b * W1SZ;
    const u16* tw2t  = W + O_TA_W2 + (size_t)b * W2SZ;

    // ---- cross attention ----
    rms_rows<0><<<8192, 256, 0, stream>>>(lat, ca_ln + b * 1536, xn);              // l_n
    rms_rows<0><<<16384, 256, 0, stream>>>(source, ca_ln + b * 1536 + 512, shat);  // s_n
    gemm256<0, 0, 0><<<dim3(2, 128), 512, 0, stream>>>(xn, nullptr, wqt, qb, nullptr, nullptr, 32768, 512, 512, 0);
    for (int c = 0; c < 4; ++c) {  // fused K|V + attention per 256-batch chunk
      gemm256<1, 0, 1><<<dim3(4, 96), 512, 0, stream>>>(shat, xn, wkvt, kvb, nullptr, ca_bk + b * 512, 24576, 1024, 512, c * 256);
      attn_ca<<<dim3(256, 8), 256, 0, stream>>>(qb, kvb, qb, c * 256);
    }
    gemm256<2, 0, 0><<<dim3(2, 128), 512, 0, stream>>>(qb, nullptr, wot, nullptr, lat, nullptr, 32768, 512, 512, 0);
    rms_rows<0><<<8192, 256, 0, stream>>>(lat, ca_ln + b * 1536 + 1024, xn);
    gemm256<3, 0, 0><<<dim3(16, 128), 512, 0, stream>>>(xn, nullptr, w1t, h2, nullptr, nullptr, 32768, 4096, 512, 0);
    gemm256<2, 0, 0><<<dim3(2, 128), 512, 0, stream>>>(h2, nullptr, w2t, nullptr, lat, nullptr, 32768, 512, 2048, 0);

    // ---- temporal attention ----
    rms_rows<1><<<8192, 256, 0, stream>>>(lat, ta_ln + b * 1024, xn);
    gemm256<0, 0, 0><<<dim3(2, 128), 512, 0, stream>>>(xn, nullptr, twqt, qb, nullptr, nullptr, 32768, 512, 512, 0);
    gemm256<1, 0, 0><<<dim3(4, 128), 512, 0, stream>>>(xn, nullptr, twkvt, takv, nullptr, ta_bk + b * 512, 32768, 1024, 512, 0);
    attn_ta<<<dim3(256, 8), 256, 0, stream>>>(qb, takv, cosT, sinT, qb);
    gemm256<2, 1, 0><<<dim3(2, 128), 512, 0, stream>>>(qb, nullptr, twot, nullptr, lat, nullptr, 32768, 512, 512, 0);
    rms_rows<1><<<8192, 256, 0, stream>>>(lat, ta_ln + b * 1024 + 512, xn);
    gemm256<3, 0, 0><<<dim3(16, 128), 512, 0, stream>>>(xn, nullptr, tw1t, h2, nullptr, nullptr, 32768, 4096, 512, 0);
    gemm256<2, 1, 0><<<dim3(2, 128), 512, 0, stream>>>(h2, nullptr, tw2t, nullptr, lat, nullptr, 32768, 512, 2048, 0);
  }
}